// Round 1
// baseline (1426.240 us; speedup 1.0000x reference)
//
#include <hip/hip_runtime.h>
#include <math.h>

#define NB 10
#define KNN_K 11

// ---------------- Threefry-2x32-20 (JAX) ----------------
__device__ __forceinline__ void tf2x32(unsigned k0, unsigned k1, unsigned& x0, unsigned& x1) {
  unsigned ks0 = k0, ks1 = k1, ks2 = k0 ^ k1 ^ 0x1BD11BDAu;
  x0 += ks0; x1 += ks1;
#define TF_R(r) { x0 += x1; x1 = (x1 << (r)) | (x1 >> (32 - (r))); x1 ^= x0; }
  TF_R(13) TF_R(15) TF_R(26) TF_R(6)  x0 += ks1; x1 += ks2 + 1u;
  TF_R(17) TF_R(29) TF_R(16) TF_R(24) x0 += ks2; x1 += ks0 + 2u;
  TF_R(13) TF_R(15) TF_R(26) TF_R(6)  x0 += ks0; x1 += ks1 + 3u;
  TF_R(17) TF_R(29) TF_R(16) TF_R(24) x0 += ks1; x1 += ks2 + 4u;
  TF_R(13) TF_R(15) TF_R(26) TF_R(6)  x0 += ks2; x1 += ks0 + 5u;
#undef TF_R
}

// Replicates jax.random.permutation(key(seed), n)[:m].
// mode 0: threefry_partitionable=True (modern default); mode 1: legacy.
__global__ __launch_bounds__(1024) void perm_kernel(int n, int m, unsigned key0, unsigned key1,
                                                    int rounds, int mode, int* __restrict__ out) {
  __shared__ unsigned long long skey[2048];
  __shared__ unsigned sval[2048];
  int tid = threadIdx.x;
  for (int i = tid; i < n; i += blockDim.x) sval[i] = (unsigned)i;
  unsigned k0 = key0, k1 = key1;
  for (int r = 0; r < rounds; ++r) {
    unsigned a0, a1, s0, s1;
    if (mode == 0) {
      a0 = 0u; a1 = 0u; tf2x32(k0, k1, a0, a1);
      s0 = 0u; s1 = 1u; tf2x32(k0, k1, s0, s1);
    } else {
      unsigned A0 = 0u, A1 = 2u; tf2x32(k0, k1, A0, A1);
      unsigned B0 = 1u, B1 = 3u; tf2x32(k0, k1, B0, B1);
      a0 = A0; a1 = B0; s0 = A1; s1 = B1;
    }
    __syncthreads();
    if (mode == 0) {
      for (int i = tid; i < n; i += blockDim.x) {
        unsigned y0 = 0u, y1 = (unsigned)i;
        tf2x32(s0, s1, y0, y1);
        skey[i] = ((unsigned long long)(y0 ^ y1) << 32) | (unsigned)i;
      }
    } else {
      int h = n >> 1;
      for (int i = tid; i < h; i += blockDim.x) {
        unsigned y0 = (unsigned)i, y1 = (unsigned)(i + h);
        tf2x32(s0, s1, y0, y1);
        skey[i]     = ((unsigned long long)y0 << 32) | (unsigned)i;
        skey[i + h] = ((unsigned long long)y1 << 32) | (unsigned)(i + h);
      }
    }
    __syncthreads();
    for (int kk = 2; kk <= n; kk <<= 1) {
      for (int j = kk >> 1; j > 0; j >>= 1) {
        for (int i = tid; i < n; i += blockDim.x) {
          int ixj = i ^ j;
          if (ixj > i) {
            bool up = ((i & kk) == 0);
            unsigned long long ki = skey[i], kj = skey[ixj];
            if ((ki > kj) == up) {
              skey[i] = kj; skey[ixj] = ki;
              unsigned t = sval[i]; sval[i] = sval[ixj]; sval[ixj] = t;
            }
          }
        }
        __syncthreads();
      }
    }
    k0 = a0; k1 = a1;
  }
  for (int i = tid; i < m; i += blockDim.x) out[i] = (int)sval[i];
}

// ---------------- kNN: top-10 (drop self as the nearest of 11) ----------------
__global__ void knn_kernel(const float* __restrict__ v, int N, int* __restrict__ out) {
  __shared__ float4 pts[2048];
  int b = blockIdx.y;
  const float* vb = v + (size_t)b * N * 3;
  for (int i = threadIdx.x; i < N; i += blockDim.x) {
    float x = vb[i * 3], y = vb[i * 3 + 1], z = vb[i * 3 + 2];
    pts[i] = make_float4(x, y, z, x * x + y * y + z * z);
  }
  __syncthreads();
  int i = blockIdx.x * blockDim.x + threadIdx.x;
  if (i >= N) return;
  float4 p = pts[i];
  float bd[KNN_K]; int bi[KNN_K];
#pragma unroll
  for (int t = 0; t < KNN_K; ++t) { bd[t] = 3.4e38f; bi[t] = -1; }
  for (int j = 0; j < N; ++j) {
    float4 q = pts[j];
    float dot = p.x * q.x + p.y * q.y + p.z * q.z;
    float d = p.w + q.w - 2.0f * dot;
    if (d < bd[KNN_K - 1]) {
      float cd = d; int ci = j;
#pragma unroll
      for (int t = 0; t < KNN_K; ++t) {
        bool sw = cd < bd[t];
        float td = bd[t]; int ti = bi[t];
        bd[t] = sw ? cd : td; bi[t] = sw ? ci : ti;
        cd = sw ? td : cd;   ci = sw ? ti : ci;
      }
    }
  }
  int* o = out + ((size_t)b * N + i) * NB;
#pragma unroll
  for (int t = 1; t < KNN_K; ++t) o[t - 1] = bi[t];
}

// ---------------- conv_surface (writes fm0 channels 0..63, fused outer relu) ----------------
__global__ void conv_surface_kernel(const float* __restrict__ v, const int* __restrict__ idx,
                                    const float* __restrict__ dir0, float* __restrict__ fm0) {
  __shared__ float dn[4][NB][3];
  int b = blockIdx.y;
  int n0 = blockIdx.x * 4;
  int tid = threadIdx.x;
  if (tid < 4 * NB) {
    int p = tid / NB, k = tid % NB;
    size_t row = (size_t)b * 2048 + (n0 + p);
    const float* c = v + row * 3;
    int nb = idx[row * NB + k];
    const float* q = v + ((size_t)b * 2048 + nb) * 3;
    float dx = q[0] - c[0], dy = q[1] - c[1], dz = q[2] - c[2];
    float nr = fmaxf(sqrtf(dx * dx + dy * dy + dz * dz), 1e-12f);
    dn[p][k][0] = dx / nr; dn[p][k][1] = dy / nr; dn[p][k][2] = dz / nr;
  }
  __syncthreads();
  int p = tid >> 6, c = tid & 63;
  int n = n0 + p;
  float acc = 0.f;
  for (int s = 0; s < 7; ++s) {
    int e = s * 64 + c;
    float d0 = dir0[e], d1 = dir0[448 + e], d2 = dir0[896 + e];
    float nr = fmaxf(sqrtf(d0 * d0 + d1 * d1 + d2 * d2), 1e-12f);
    d0 /= nr; d1 /= nr; d2 /= nr;
    float mx = 0.f; // theta = relu(..) >= 0 so max over k >= 0
    for (int k = 0; k < NB; ++k) {
      float t = dn[p][k][0] * d0 + dn[p][k][1] * d1 + dn[p][k][2] * d2;
      t = fmaxf(t, 0.f);
      mx = fmaxf(mx, t);
    }
    acc += mx;
  }
  fm0[((size_t)b * 2048 + n) * 128 + c] = fmaxf(acc, 0.f);
}

// ---------------- rgb branch (writes fm0 channels 64..127) ----------------
__global__ void rgb_kernel(const float* __restrict__ rgb_f, const float* __restrict__ w,
                           const float* __restrict__ bias, const float* __restrict__ g,
                           const float* __restrict__ bb, const float* __restrict__ mm,
                           const float* __restrict__ vv, float* __restrict__ fm0) {
  int b = blockIdx.y;
  int tid = threadIdx.x;
  int p = tid >> 6, o = tid & 63;
  int n = blockIdx.x * 4 + p;
  const float* f = rgb_f + (size_t)b * 32 * 2048;
  float acc = bias[o];
  for (int c = 0; c < 32; ++c) acc += w[o * 32 + c] * f[c * 2048 + n];
  acc = fmaxf(acc, 0.f);
  acc = (acc - mm[o]) / sqrtf(vv[o] + 1e-5f) * g[o] + bb[o];
  fm0[((size_t)b * 2048 + n) * 128 + 64 + o] = acc;
}

// ---------------- fp32 tiled matmul: C[MxN] = A[MxK] @ W[KxN] + bias ----------------
__global__ __launch_bounds__(256) void matmul_bias_kernel(const float* __restrict__ A,
                                                          const float* __restrict__ W,
                                                          const float* __restrict__ bias,
                                                          float* __restrict__ C,
                                                          int M, int K, int N) {
  __shared__ float As[16][65];
  __shared__ float Bs[16][65];
  int tx = threadIdx.x, ty = threadIdx.y;
  int tid = ty * 16 + tx;
  int m0 = blockIdx.y * 64, n0 = blockIdx.x * 64;
  float acc[4][4] = {};
  for (int kt = 0; kt < K; kt += 16) {
    for (int l = tid; l < 1024; l += 256) {
      int r = l >> 4, c = l & 15;
      As[c][r] = A[(size_t)(m0 + r) * K + kt + c];
    }
    for (int l = tid; l < 1024; l += 256) {
      int r = l >> 6, c = l & 63;
      Bs[r][c] = W[(size_t)(kt + r) * N + n0 + c];
    }
    __syncthreads();
#pragma unroll
    for (int kk = 0; kk < 16; ++kk) {
      float a[4], bv[4];
#pragma unroll
      for (int r = 0; r < 4; ++r) a[r] = As[kk][ty * 4 + r];
#pragma unroll
      for (int c = 0; c < 4; ++c) bv[c] = Bs[kk][tx * 4 + c];
#pragma unroll
      for (int r = 0; r < 4; ++r)
#pragma unroll
        for (int c = 0; c < 4; ++c) acc[r][c] += a[r] * bv[c];
    }
    __syncthreads();
  }
#pragma unroll
  for (int r = 0; r < 4; ++r) {
    int m = m0 + ty * 4 + r;
#pragma unroll
    for (int c = 0; c < 4; ++c) {
      int n = n0 + tx * 4 + c;
      C[(size_t)m * N + n] = acc[r][c] + bias[n];
    }
  }
}

// ---------------- conv_layer combine: center + sum_s max_k theta*supp, optional bn+relu ----------------
__global__ void conv_combine_kernel(const int* __restrict__ idx, const float* __restrict__ v,
                                    const float* __restrict__ fout, const float* __restrict__ dirs,
                                    const float* __restrict__ g, const float* __restrict__ bb,
                                    const float* __restrict__ mm, const float* __restrict__ vv,
                                    int use_bn_relu, float* __restrict__ outf, int Np, int Cout) {
  __shared__ float dn[NB][3];
  __shared__ int nbrow[NB];
  int b = blockIdx.y, n = blockIdx.x;
  int tid = threadIdx.x;
  size_t row = (size_t)b * Np + n;
  if (tid < NB) {
    int nb = idx[row * NB + tid];
    const float* c = v + row * 3;
    const float* q = v + ((size_t)b * Np + nb) * 3;
    float dx = q[0] - c[0], dy = q[1] - c[1], dz = q[2] - c[2];
    float nr = fmaxf(sqrtf(dx * dx + dy * dy + dz * dz), 1e-12f);
    dn[tid][0] = dx / nr; dn[tid][1] = dy / nr; dn[tid][2] = dz / nr;
    nbrow[tid] = b * Np + nb;
  }
  __syncthreads();
  int c = tid;
  int F = 8 * Cout;
  int W7 = 7 * Cout;
  float acc = fout[row * (size_t)F + c];  // center
  for (int s = 0; s < 7; ++s) {
    int e = s * Cout + c;
    float d0 = dirs[e], d1 = dirs[W7 + e], d2 = dirs[2 * W7 + e];
    float nr = fmaxf(sqrtf(d0 * d0 + d1 * d1 + d2 * d2), 1e-12f);
    d0 /= nr; d1 /= nr; d2 /= nr;
    float mx = -3.4e38f;
#pragma unroll
    for (int k = 0; k < NB; ++k) {
      float t = fmaxf(dn[k][0] * d0 + dn[k][1] * d1 + dn[k][2] * d2, 0.f);
      float sv = fout[(size_t)nbrow[k] * F + Cout + e];
      mx = fmaxf(mx, t * sv);
    }
    acc += mx;
  }
  if (use_bn_relu) {
    acc = (acc - mm[c]) / sqrtf(vv[c] + 1e-5f) * g[c] + bb[c];
    acc = fmaxf(acc, 0.f);
  }
  outf[row * (size_t)Cout + c] = acc;
}

// ---------------- pool: max over first-4 neighbors at sampled rows ----------------
__global__ void pool_kernel(const float* __restrict__ v, const float* __restrict__ fm,
                            const int* __restrict__ idx10, const int* __restrict__ samp,
                            float* __restrict__ v_out, float* __restrict__ f_out,
                            int Nin, int C) {
  int b = blockIdx.y, mi = blockIdx.x, c = threadIdx.x;
  int n = samp[mi];
  size_t row = (size_t)b * Nin + n;
  float mx = -3.4e38f;
#pragma unroll
  for (int j = 0; j < 4; ++j) {
    int nb = idx10[row * NB + j];
    mx = fmaxf(mx, fm[((size_t)b * Nin + nb) * C + c]);
  }
  int Mout = gridDim.x;
  f_out[((size_t)b * Mout + mi) * C + c] = mx;
  if (c < 3) v_out[((size_t)b * Mout + mi) * 3 + c] = v[row * 3 + c];
}

// ---------------- global max over points of fm4 ----------------
__global__ void global_max_kernel(const float* __restrict__ fm4, float* __restrict__ fg) {
  int b = blockIdx.x, c = threadIdx.x;
  float mx = -3.4e38f;
  for (int p = 0; p < 128; ++p) mx = fmaxf(mx, fm4[((size_t)b * 128 + p) * 512 + c]);
  fg[b * 512 + c] = mx;
}

// ---------------- nearest source index for each target point ----------------
__global__ void nearest_kernel(const float* __restrict__ tgt, const float* __restrict__ src,
                               int S, int* __restrict__ out) {
  __shared__ float4 sp[512];
  int b = blockIdx.y;
  for (int i = threadIdx.x; i < S; i += blockDim.x) {
    const float* q = src + ((size_t)b * S + i) * 3;
    float x = q[0], y = q[1], z = q[2];
    sp[i] = make_float4(x, y, z, x * x + y * y + z * z);
  }
  __syncthreads();
  int n = blockIdx.x * blockDim.x + threadIdx.x;
  const float* t = tgt + ((size_t)b * 2048 + n) * 3;
  float x = t[0], y = t[1], z = t[2];
  float sqt = x * x + y * y + z * z;
  float best = 3.4e38f; int bi = 0;
  for (int s = 0; s < S; ++s) {
    float4 q = sp[s];
    float d = q.w + sqt - 2.f * (x * q.x + y * q.y + z * q.z);
    if (d < best) { best = d; bi = s; }
  }
  out[(size_t)b * 2048 + n] = bi;
}

// ---------------- final transpose/concat into feat + fuse outputs ----------------
__global__ void output_kernel(const float* __restrict__ fm0, const float* __restrict__ fm1,
                              const float* __restrict__ fm2, const float* __restrict__ fm3,
                              const float* __restrict__ fm4, const float* __restrict__ fg,
                              const int* __restrict__ ni1, const int* __restrict__ ni2,
                              float* __restrict__ out) {
  int b = blockIdx.z, cc = blockIdx.y;
  int n = blockIdx.x * blockDim.x + threadIdx.x;
  size_t row = (size_t)b * 2048 + n;
  float val;
  if (cc < 128)       val = fm0[row * 128 + cc];
  else if (cc < 256)  val = fm1[row * 128 + (cc - 128)];
  else if (cc < 512)  val = fm2[((size_t)b * 512 + ni1[row]) * 256 + (cc - 256)];
  else if (cc < 768)  val = fm3[((size_t)b * 512 + ni1[row]) * 256 + (cc - 512)];
  else if (cc < 1280) val = fm4[((size_t)b * 128 + ni2[row]) * 512 + (cc - 768)];
  else                val = fg[b * 512 + (cc - 1280)];
  float* out0 = out;                              // (4,1280,2048)
  float* out1 = out + (size_t)4 * 1280 * 2048;    // (4,1792,2048)
  if (cc < 1280) out0[((size_t)b * 1280 + cc) * 2048 + n] = val;
  out1[((size_t)b * 1792 + cc) * 2048 + n] = val;
}

extern "C" void kernel_launch(void* const* d_in, const int* in_sizes, int n_in,
                              void* d_out, int out_size, void* d_ws, size_t ws_size,
                              hipStream_t stream) {
  (void)in_sizes; (void)n_in; (void)out_size; (void)ws_size;
  const float* vertices = (const float*)d_in[0];
  const float* rgb_f    = (const float*)d_in[1];
  const float* dir0     = (const float*)d_in[2];
  const float* w1 = (const float*)d_in[3],  *b1 = (const float*)d_in[4],  *d1 = (const float*)d_in[5];
  const float* w2 = (const float*)d_in[6],  *b2 = (const float*)d_in[7],  *d2 = (const float*)d_in[8];
  const float* w3 = (const float*)d_in[9],  *b3 = (const float*)d_in[10], *d3 = (const float*)d_in[11];
  const float* w4 = (const float*)d_in[12], *b4 = (const float*)d_in[13], *d4 = (const float*)d_in[14];
  const float* rgb_w = (const float*)d_in[15], *rgb_b = (const float*)d_in[16];
  const float* rbn_g = (const float*)d_in[17], *rbn_b = (const float*)d_in[18];
  const float* rbn_m = (const float*)d_in[19], *rbn_v = (const float*)d_in[20];
  const float* bn1_g = (const float*)d_in[21], *bn1_b = (const float*)d_in[22];
  const float* bn1_m = (const float*)d_in[23], *bn1_v = (const float*)d_in[24];
  const float* bn2_g = (const float*)d_in[25], *bn2_b = (const float*)d_in[26];
  const float* bn2_m = (const float*)d_in[27], *bn2_v = (const float*)d_in[28];
  const float* bn3_g = (const float*)d_in[29], *bn3_b = (const float*)d_in[30];
  const float* bn3_m = (const float*)d_in[31], *bn3_v = (const float*)d_in[32];
  float* out = (float*)d_out;

  char* ws = (char*)d_ws;
  size_t off = 0;
  auto alloc = [&](size_t bytes) -> void* {
    void* p = ws + off;
    off += (bytes + 255) & ~(size_t)255;
    return p;
  };
  int*   samp1 = (int*)alloc(512 * 4);
  int*   samp2 = (int*)alloc(128 * 4);
  int*   idx0  = (int*)alloc((size_t)4 * 2048 * NB * 4);
  int*   idx1  = (int*)alloc((size_t)4 * 512 * NB * 4);
  int*   idx2  = (int*)alloc((size_t)4 * 128 * NB * 4);
  float* fm0   = (float*)alloc((size_t)4 * 2048 * 128 * 4);
  float* fm1   = (float*)alloc((size_t)4 * 2048 * 128 * 4);
  float* fout  = (float*)alloc((size_t)4 * 2048 * 1024 * 4);  // reused by all 4 layers
  float* v1    = (float*)alloc((size_t)4 * 512 * 3 * 4);
  float* fp1   = (float*)alloc((size_t)4 * 512 * 128 * 4);
  float* fm2   = (float*)alloc((size_t)4 * 512 * 256 * 4);
  float* fm3   = (float*)alloc((size_t)4 * 512 * 256 * 4);
  float* v2    = (float*)alloc((size_t)4 * 128 * 3 * 4);
  float* fp2   = (float*)alloc((size_t)4 * 128 * 256 * 4);
  float* fm4   = (float*)alloc((size_t)4 * 128 * 512 * 4);
  float* fg    = (float*)alloc((size_t)4 * 512 * 4);
  int*   ni1   = (int*)alloc((size_t)4 * 2048 * 4);
  int*   ni2   = (int*)alloc((size_t)4 * 2048 * 4);

  const int PART_MODE = 0;  // 0 = jax_threefry_partitionable (modern default); 1 = legacy

  // permutations: seed 1 (n=2048 -> 2 rounds), seed 2 (n=512 -> 1 round)
  perm_kernel<<<1, 1024, 0, stream>>>(2048, 512, 0u, 1u, 2, PART_MODE, samp1);
  perm_kernel<<<1, 1024, 0, stream>>>(512, 128, 0u, 2u, 1, PART_MODE, samp2);

  // level-0 kNN
  knn_kernel<<<dim3(8, 4), 256, 0, stream>>>(vertices, 2048, idx0);

  // fm0 = [conv_surface(64ch) | bn(relu(rgb))(64ch)]
  conv_surface_kernel<<<dim3(512, 4), 256, 0, stream>>>(vertices, idx0, dir0, fm0);
  rgb_kernel<<<dim3(512, 4), 256, 0, stream>>>(rgb_f, rgb_w, rgb_b, rbn_g, rbn_b, rbn_m, rbn_v, fm0);

  // layer 1: fout = fm0 @ w1 + b1 ; fm1 = relu(bn1(combine))
  matmul_bias_kernel<<<dim3(1024 / 64, 8192 / 64), dim3(16, 16), 0, stream>>>(fm0, w1, b1, fout, 8192, 128, 1024);
  conv_combine_kernel<<<dim3(2048, 4), 128, 0, stream>>>(idx0, vertices, fout, d1,
                                                         bn1_g, bn1_b, bn1_m, bn1_v, 1, fm1, 2048, 128);

  // pool 1 -> v1, fp1 ; level-1 kNN
  pool_kernel<<<dim3(512, 4), 128, 0, stream>>>(vertices, fm1, idx0, samp1, v1, fp1, 2048, 128);
  knn_kernel<<<dim3(2, 4), 256, 0, stream>>>(v1, 512, idx1);

  // layer 2
  matmul_bias_kernel<<<dim3(2048 / 64, 2048 / 64), dim3(16, 16), 0, stream>>>(fp1, w2, b2, fout, 2048, 128, 2048);
  conv_combine_kernel<<<dim3(512, 4), 256, 0, stream>>>(idx1, v1, fout, d2,
                                                        bn2_g, bn2_b, bn2_m, bn2_v, 1, fm2, 512, 256);
  // layer 3
  matmul_bias_kernel<<<dim3(2048 / 64, 2048 / 64), dim3(16, 16), 0, stream>>>(fm2, w3, b3, fout, 2048, 256, 2048);
  conv_combine_kernel<<<dim3(512, 4), 256, 0, stream>>>(idx1, v1, fout, d3,
                                                        bn3_g, bn3_b, bn3_m, bn3_v, 1, fm3, 512, 256);

  // pool 2 -> v2, fp2 ; level-2 kNN
  pool_kernel<<<dim3(128, 4), 256, 0, stream>>>(v1, fm3, idx1, samp2, v2, fp2, 512, 256);
  knn_kernel<<<dim3(1, 4), 256, 0, stream>>>(v2, 128, idx2);

  // layer 4 (no bn, no relu)
  matmul_bias_kernel<<<dim3(4096 / 64, 512 / 64), dim3(16, 16), 0, stream>>>(fp2, w4, b4, fout, 512, 256, 4096);
  conv_combine_kernel<<<dim3(128, 4), 512, 0, stream>>>(idx2, v2, fout, d4,
                                                        nullptr, nullptr, nullptr, nullptr, 0, fm4, 128, 512);

  // global max + upsample indices
  global_max_kernel<<<4, 512, 0, stream>>>(fm4, fg);
  nearest_kernel<<<dim3(8, 4), 256, 0, stream>>>(vertices, v1, 512, ni1);
  nearest_kernel<<<dim3(8, 4), 256, 0, stream>>>(vertices, v2, 128, ni2);

  // outputs
  output_kernel<<<dim3(8, 1792, 4), 256, 0, stream>>>(fm0, fm1, fm2, fm3, fm4, fg, ni1, ni2, out);
}

// Round 2
// 550.382 us; speedup vs baseline: 2.5914x; 2.5914x over previous
//
#include <hip/hip_runtime.h>
#include <math.h>

#define NB 10
#define KNN_K 11

// ---------------- Threefry-2x32-20 (JAX) ----------------
__device__ __forceinline__ void tf2x32(unsigned k0, unsigned k1, unsigned& x0, unsigned& x1) {
  unsigned ks0 = k0, ks1 = k1, ks2 = k0 ^ k1 ^ 0x1BD11BDAu;
  x0 += ks0; x1 += ks1;
#define TF_R(r) { x0 += x1; x1 = (x1 << (r)) | (x1 >> (32 - (r))); x1 ^= x0; }
  TF_R(13) TF_R(15) TF_R(26) TF_R(6)  x0 += ks1; x1 += ks2 + 1u;
  TF_R(17) TF_R(29) TF_R(16) TF_R(24) x0 += ks2; x1 += ks0 + 2u;
  TF_R(13) TF_R(15) TF_R(26) TF_R(6)  x0 += ks0; x1 += ks1 + 3u;
  TF_R(17) TF_R(29) TF_R(16) TF_R(24) x0 += ks1; x1 += ks2 + 4u;
  TF_R(13) TF_R(15) TF_R(26) TF_R(6)  x0 += ks2; x1 += ks0 + 5u;
#undef TF_R
}

// Replicates jax.random.permutation(key(seed), n)[:m].
// mode 0: threefry_partitionable=True (modern default); mode 1: legacy.
__global__ __launch_bounds__(1024) void perm_kernel(int n, int m, unsigned key0, unsigned key1,
                                                    int rounds, int mode, int* __restrict__ out) {
  __shared__ unsigned long long skey[2048];
  __shared__ unsigned sval[2048];
  int tid = threadIdx.x;
  for (int i = tid; i < n; i += blockDim.x) sval[i] = (unsigned)i;
  unsigned k0 = key0, k1 = key1;
  for (int r = 0; r < rounds; ++r) {
    unsigned a0, a1, s0, s1;
    if (mode == 0) {
      a0 = 0u; a1 = 0u; tf2x32(k0, k1, a0, a1);
      s0 = 0u; s1 = 1u; tf2x32(k0, k1, s0, s1);
    } else {
      unsigned A0 = 0u, A1 = 2u; tf2x32(k0, k1, A0, A1);
      unsigned B0 = 1u, B1 = 3u; tf2x32(k0, k1, B0, B1);
      a0 = A0; a1 = B0; s0 = A1; s1 = B1;
    }
    __syncthreads();
    if (mode == 0) {
      for (int i = tid; i < n; i += blockDim.x) {
        unsigned y0 = 0u, y1 = (unsigned)i;
        tf2x32(s0, s1, y0, y1);
        skey[i] = ((unsigned long long)(y0 ^ y1) << 32) | (unsigned)i;
      }
    } else {
      int h = n >> 1;
      for (int i = tid; i < h; i += blockDim.x) {
        unsigned y0 = (unsigned)i, y1 = (unsigned)(i + h);
        tf2x32(s0, s1, y0, y1);
        skey[i]     = ((unsigned long long)y0 << 32) | (unsigned)i;
        skey[i + h] = ((unsigned long long)y1 << 32) | (unsigned)(i + h);
      }
    }
    __syncthreads();
    for (int kk = 2; kk <= n; kk <<= 1) {
      for (int j = kk >> 1; j > 0; j >>= 1) {
        for (int i = tid; i < n; i += blockDim.x) {
          int ixj = i ^ j;
          if (ixj > i) {
            bool up = ((i & kk) == 0);
            unsigned long long ki = skey[i], kj = skey[ixj];
            if ((ki > kj) == up) {
              skey[i] = kj; skey[ixj] = ki;
              unsigned t = sval[i]; sval[i] = sval[ixj]; sval[ixj] = t;
            }
          }
        }
        __syncthreads();
      }
    }
    k0 = a0; k1 = a1;
  }
  for (int i = tid; i < m; i += blockDim.x) out[i] = (int)sval[i];
}

// ---------------- kNN: wave-per-query top-11, drop slot 0 ----------------
// Each 64-lane wave owns one query point. Lanes scan candidates j = lane+64*s,
// keep a private sorted top-11 (strict < insertion => stable by index within a
// lane since j increases), then 11 rounds of lexicographic (d, idx) butterfly
// min-reduce merge across lanes — matches jax.lax.top_k tie-by-lowest-index.
__global__ __launch_bounds__(256) void knn_wave_kernel(const float* __restrict__ v, int N,
                                                       int* __restrict__ out) {
  __shared__ float4 pts[2048];
  int b = blockIdx.y;
  const float* vb = v + (size_t)b * N * 3;
  for (int i = threadIdx.x; i < N; i += blockDim.x) {
    float x = vb[i * 3], y = vb[i * 3 + 1], z = vb[i * 3 + 2];
    pts[i] = make_float4(x, y, z, x * x + y * y + z * z);
  }
  __syncthreads();
  int wave = threadIdx.x >> 6;
  int lane = threadIdx.x & 63;
  int qi = blockIdx.x * 4 + wave;  // grid sized so qi < N always
  float4 p = pts[qi];
  float bd[KNN_K]; int bi[KNN_K];
#pragma unroll
  for (int t = 0; t < KNN_K; ++t) { bd[t] = 3.4e38f; bi[t] = 0x7fffffff; }
  for (int j = lane; j < N; j += 64) {
    float4 q = pts[j];
    float dot = p.x * q.x + p.y * q.y + p.z * q.z;
    float d = p.w + q.w - 2.0f * dot;
    if (d < bd[KNN_K - 1]) {
      float cd = d; int ci = j;
#pragma unroll
      for (int t = 0; t < KNN_K; ++t) {
        bool sw = cd < bd[t];
        float td = bd[t]; int ti = bi[t];
        bd[t] = sw ? cd : td; bi[t] = sw ? ci : ti;
        cd = sw ? td : cd;   ci = sw ? ti : ci;
      }
    }
  }
  // merge: 11 rounds of (d, idx) lexicographic wave-min; winner advances.
  int ptr = 0;
  int* o = out + ((size_t)b * N + qi) * NB;
#pragma unroll 1
  for (int t = 0; t < KNN_K; ++t) {
    float d = (ptr < KNN_K) ? bd[ptr] : 3.4e38f;
    int idx = (ptr < KNN_K) ? bi[ptr] : 0x7fffffff;
    float rd = d; int ridx = idx;
#pragma unroll
    for (int s = 32; s > 0; s >>= 1) {
      float od = __shfl_xor(rd, s);
      int oi = __shfl_xor(ridx, s);
      if (od < rd || (od == rd && oi < ridx)) { rd = od; ridx = oi; }
    }
    if (d == rd && idx == ridx) ptr++;  // candidate indices unique -> exactly one winner
    if (t >= 1 && lane == 0) o[t - 1] = ridx;
  }
}

// ---------------- conv_surface (writes fm0 channels 0..63, fused outer relu) ----------------
__global__ void conv_surface_kernel(const float* __restrict__ v, const int* __restrict__ idx,
                                    const float* __restrict__ dir0, float* __restrict__ fm0) {
  __shared__ float dn[4][NB][3];
  int b = blockIdx.y;
  int n0 = blockIdx.x * 4;
  int tid = threadIdx.x;
  if (tid < 4 * NB) {
    int p = tid / NB, k = tid % NB;
    size_t row = (size_t)b * 2048 + (n0 + p);
    const float* c = v + row * 3;
    int nb = idx[row * NB + k];
    const float* q = v + ((size_t)b * 2048 + nb) * 3;
    float dx = q[0] - c[0], dy = q[1] - c[1], dz = q[2] - c[2];
    float nr = fmaxf(sqrtf(dx * dx + dy * dy + dz * dz), 1e-12f);
    dn[p][k][0] = dx / nr; dn[p][k][1] = dy / nr; dn[p][k][2] = dz / nr;
  }
  __syncthreads();
  int p = tid >> 6, c = tid & 63;
  int n = n0 + p;
  float acc = 0.f;
  for (int s = 0; s < 7; ++s) {
    int e = s * 64 + c;
    float d0 = dir0[e], d1 = dir0[448 + e], d2 = dir0[896 + e];
    float nr = fmaxf(sqrtf(d0 * d0 + d1 * d1 + d2 * d2), 1e-12f);
    d0 /= nr; d1 /= nr; d2 /= nr;
    float mx = 0.f; // theta = relu(..) >= 0 so max over k >= 0
    for (int k = 0; k < NB; ++k) {
      float t = dn[p][k][0] * d0 + dn[p][k][1] * d1 + dn[p][k][2] * d2;
      t = fmaxf(t, 0.f);
      mx = fmaxf(mx, t);
    }
    acc += mx;
  }
  fm0[((size_t)b * 2048 + n) * 128 + c] = fmaxf(acc, 0.f);
}

// ---------------- rgb branch (writes fm0 channels 64..127) ----------------
__global__ void rgb_kernel(const float* __restrict__ rgb_f, const float* __restrict__ w,
                           const float* __restrict__ bias, const float* __restrict__ g,
                           const float* __restrict__ bb, const float* __restrict__ mm,
                           const float* __restrict__ vv, float* __restrict__ fm0) {
  int b = blockIdx.y;
  int tid = threadIdx.x;
  int p = tid >> 6, o = tid & 63;
  int n = blockIdx.x * 4 + p;
  const float* f = rgb_f + (size_t)b * 32 * 2048;
  float acc = bias[o];
  for (int c = 0; c < 32; ++c) acc += w[o * 32 + c] * f[c * 2048 + n];
  acc = fmaxf(acc, 0.f);
  acc = (acc - mm[o]) / sqrtf(vv[o] + 1e-5f) * g[o] + bb[o];
  fm0[((size_t)b * 2048 + n) * 128 + 64 + o] = acc;
}

// ---------------- fp32 tiled matmul: C[MxN] = A[MxK] @ W[KxN] + bias ----------------
__global__ __launch_bounds__(256) void matmul_bias_kernel(const float* __restrict__ A,
                                                          const float* __restrict__ W,
                                                          const float* __restrict__ bias,
                                                          float* __restrict__ C,
                                                          int M, int K, int N) {
  __shared__ float As[16][65];
  __shared__ float Bs[16][65];
  int tx = threadIdx.x, ty = threadIdx.y;
  int tid = ty * 16 + tx;
  int m0 = blockIdx.y * 64, n0 = blockIdx.x * 64;
  float acc[4][4] = {};
  for (int kt = 0; kt < K; kt += 16) {
    for (int l = tid; l < 1024; l += 256) {
      int r = l >> 4, c = l & 15;
      As[c][r] = A[(size_t)(m0 + r) * K + kt + c];
    }
    for (int l = tid; l < 1024; l += 256) {
      int r = l >> 6, c = l & 63;
      Bs[r][c] = W[(size_t)(kt + r) * N + n0 + c];
    }
    __syncthreads();
#pragma unroll
    for (int kk = 0; kk < 16; ++kk) {
      float a[4], bv[4];
#pragma unroll
      for (int r = 0; r < 4; ++r) a[r] = As[kk][ty * 4 + r];
#pragma unroll
      for (int c = 0; c < 4; ++c) bv[c] = Bs[kk][tx * 4 + c];
#pragma unroll
      for (int r = 0; r < 4; ++r)
#pragma unroll
        for (int c = 0; c < 4; ++c) acc[r][c] += a[r] * bv[c];
    }
    __syncthreads();
  }
#pragma unroll
  for (int r = 0; r < 4; ++r) {
    int m = m0 + ty * 4 + r;
#pragma unroll
    for (int c = 0; c < 4; ++c) {
      int n = n0 + tx * 4 + c;
      C[(size_t)m * N + n] = acc[r][c] + bias[n];
    }
  }
}

// ---------------- conv_layer combine: center + sum_s max_k theta*supp, optional bn+relu ----------------
__global__ void conv_combine_kernel(const int* __restrict__ idx, const float* __restrict__ v,
                                    const float* __restrict__ fout, const float* __restrict__ dirs,
                                    const float* __restrict__ g, const float* __restrict__ bb,
                                    const float* __restrict__ mm, const float* __restrict__ vv,
                                    int use_bn_relu, float* __restrict__ outf, int Np, int Cout) {
  __shared__ float dn[NB][3];
  __shared__ int nbrow[NB];
  int b = blockIdx.y, n = blockIdx.x;
  int tid = threadIdx.x;
  size_t row = (size_t)b * Np + n;
  if (tid < NB) {
    int nb = idx[row * NB + tid];
    const float* c = v + row * 3;
    const float* q = v + ((size_t)b * Np + nb) * 3;
    float dx = q[0] - c[0], dy = q[1] - c[1], dz = q[2] - c[2];
    float nr = fmaxf(sqrtf(dx * dx + dy * dy + dz * dz), 1e-12f);
    dn[tid][0] = dx / nr; dn[tid][1] = dy / nr; dn[tid][2] = dz / nr;
    nbrow[tid] = b * Np + nb;
  }
  __syncthreads();
  int c = tid;
  int F = 8 * Cout;
  int W7 = 7 * Cout;
  float acc = fout[row * (size_t)F + c];  // center
  for (int s = 0; s < 7; ++s) {
    int e = s * Cout + c;
    float d0 = dirs[e], d1 = dirs[W7 + e], d2 = dirs[2 * W7 + e];
    float nr = fmaxf(sqrtf(d0 * d0 + d1 * d1 + d2 * d2), 1e-12f);
    d0 /= nr; d1 /= nr; d2 /= nr;
    float mx = -3.4e38f;
#pragma unroll
    for (int k = 0; k < NB; ++k) {
      float t = fmaxf(dn[k][0] * d0 + dn[k][1] * d1 + dn[k][2] * d2, 0.f);
      float sv = fout[(size_t)nbrow[k] * F + Cout + e];
      mx = fmaxf(mx, t * sv);
    }
    acc += mx;
  }
  if (use_bn_relu) {
    acc = (acc - mm[c]) / sqrtf(vv[c] + 1e-5f) * g[c] + bb[c];
    acc = fmaxf(acc, 0.f);
  }
  outf[row * (size_t)Cout + c] = acc;
}

// ---------------- pool: max over first-4 neighbors at sampled rows ----------------
__global__ void pool_kernel(const float* __restrict__ v, const float* __restrict__ fm,
                            const int* __restrict__ idx10, const int* __restrict__ samp,
                            float* __restrict__ v_out, float* __restrict__ f_out,
                            int Nin, int C) {
  int b = blockIdx.y, mi = blockIdx.x, c = threadIdx.x;
  int n = samp[mi];
  size_t row = (size_t)b * Nin + n;
  float mx = -3.4e38f;
#pragma unroll
  for (int j = 0; j < 4; ++j) {
    int nb = idx10[row * NB + j];
    mx = fmaxf(mx, fm[((size_t)b * Nin + nb) * C + c]);
  }
  int Mout = gridDim.x;
  f_out[((size_t)b * Mout + mi) * C + c] = mx;
  if (c < 3) v_out[((size_t)b * Mout + mi) * 3 + c] = v[row * 3 + c];
}

// ---------------- global max over points of fm4 ----------------
__global__ void global_max_kernel(const float* __restrict__ fm4, float* __restrict__ fg) {
  int b = blockIdx.x, c = threadIdx.x;
  float mx = -3.4e38f;
  for (int p = 0; p < 128; ++p) mx = fmaxf(mx, fm4[((size_t)b * 128 + p) * 512 + c]);
  fg[b * 512 + c] = mx;
}

// ---------------- nearest source index for each target point ----------------
__global__ void nearest_kernel(const float* __restrict__ tgt, const float* __restrict__ src,
                               int S, int* __restrict__ out) {
  __shared__ float4 sp[512];
  int b = blockIdx.y;
  for (int i = threadIdx.x; i < S; i += blockDim.x) {
    const float* q = src + ((size_t)b * S + i) * 3;
    float x = q[0], y = q[1], z = q[2];
    sp[i] = make_float4(x, y, z, x * x + y * y + z * z);
  }
  __syncthreads();
  int n = blockIdx.x * blockDim.x + threadIdx.x;
  const float* t = tgt + ((size_t)b * 2048 + n) * 3;
  float x = t[0], y = t[1], z = t[2];
  float sqt = x * x + y * y + z * z;
  float best = 3.4e38f; int bi = 0;
  for (int s = 0; s < S; ++s) {
    float4 q = sp[s];
    float d = q.w + sqt - 2.f * (x * q.x + y * q.y + z * q.z);
    if (d < best) { best = d; bi = s; }
  }
  out[(size_t)b * 2048 + n] = bi;
}

// ---------------- final transpose/concat into feat + fuse outputs ----------------
__global__ void output_kernel(const float* __restrict__ fm0, const float* __restrict__ fm1,
                              const float* __restrict__ fm2, const float* __restrict__ fm3,
                              const float* __restrict__ fm4, const float* __restrict__ fg,
                              const int* __restrict__ ni1, const int* __restrict__ ni2,
                              float* __restrict__ out) {
  int b = blockIdx.z, cc = blockIdx.y;
  int n = blockIdx.x * blockDim.x + threadIdx.x;
  size_t row = (size_t)b * 2048 + n;
  float val;
  if (cc < 128)       val = fm0[row * 128 + cc];
  else if (cc < 256)  val = fm1[row * 128 + (cc - 128)];
  else if (cc < 512)  val = fm2[((size_t)b * 512 + ni1[row]) * 256 + (cc - 256)];
  else if (cc < 768)  val = fm3[((size_t)b * 512 + ni1[row]) * 256 + (cc - 512)];
  else if (cc < 1280) val = fm4[((size_t)b * 128 + ni2[row]) * 512 + (cc - 768)];
  else                val = fg[b * 512 + (cc - 1280)];
  float* out0 = out;                              // (4,1280,2048)
  float* out1 = out + (size_t)4 * 1280 * 2048;    // (4,1792,2048)
  if (cc < 1280) out0[((size_t)b * 1280 + cc) * 2048 + n] = val;
  out1[((size_t)b * 1792 + cc) * 2048 + n] = val;
}

extern "C" void kernel_launch(void* const* d_in, const int* in_sizes, int n_in,
                              void* d_out, int out_size, void* d_ws, size_t ws_size,
                              hipStream_t stream) {
  (void)in_sizes; (void)n_in; (void)out_size; (void)ws_size;
  const float* vertices = (const float*)d_in[0];
  const float* rgb_f    = (const float*)d_in[1];
  const float* dir0     = (const float*)d_in[2];
  const float* w1 = (const float*)d_in[3],  *b1 = (const float*)d_in[4],  *d1 = (const float*)d_in[5];
  const float* w2 = (const float*)d_in[6],  *b2 = (const float*)d_in[7],  *d2 = (const float*)d_in[8];
  const float* w3 = (const float*)d_in[9],  *b3 = (const float*)d_in[10], *d3 = (const float*)d_in[11];
  const float* w4 = (const float*)d_in[12], *b4 = (const float*)d_in[13], *d4 = (const float*)d_in[14];
  const float* rgb_w = (const float*)d_in[15], *rgb_b = (const float*)d_in[16];
  const float* rbn_g = (const float*)d_in[17], *rbn_b = (const float*)d_in[18];
  const float* rbn_m = (const float*)d_in[19], *rbn_v = (const float*)d_in[20];
  const float* bn1_g = (const float*)d_in[21], *bn1_b = (const float*)d_in[22];
  const float* bn1_m = (const float*)d_in[23], *bn1_v = (const float*)d_in[24];
  const float* bn2_g = (const float*)d_in[25], *bn2_b = (const float*)d_in[26];
  const float* bn2_m = (const float*)d_in[27], *bn2_v = (const float*)d_in[28];
  const float* bn3_g = (const float*)d_in[29], *bn3_b = (const float*)d_in[30];
  const float* bn3_m = (const float*)d_in[31], *bn3_v = (const float*)d_in[32];
  float* out = (float*)d_out;

  char* ws = (char*)d_ws;
  size_t off = 0;
  auto alloc = [&](size_t bytes) -> void* {
    void* p = ws + off;
    off += (bytes + 255) & ~(size_t)255;
    return p;
  };
  int*   samp1 = (int*)alloc(512 * 4);
  int*   samp2 = (int*)alloc(128 * 4);
  int*   idx0  = (int*)alloc((size_t)4 * 2048 * NB * 4);
  int*   idx1  = (int*)alloc((size_t)4 * 512 * NB * 4);
  int*   idx2  = (int*)alloc((size_t)4 * 128 * NB * 4);
  float* fm0   = (float*)alloc((size_t)4 * 2048 * 128 * 4);
  float* fm1   = (float*)alloc((size_t)4 * 2048 * 128 * 4);
  float* fout  = (float*)alloc((size_t)4 * 2048 * 1024 * 4);  // reused by all 4 layers
  float* v1    = (float*)alloc((size_t)4 * 512 * 3 * 4);
  float* fp1   = (float*)alloc((size_t)4 * 512 * 128 * 4);
  float* fm2   = (float*)alloc((size_t)4 * 512 * 256 * 4);
  float* fm3   = (float*)alloc((size_t)4 * 512 * 256 * 4);
  float* v2    = (float*)alloc((size_t)4 * 128 * 3 * 4);
  float* fp2   = (float*)alloc((size_t)4 * 128 * 256 * 4);
  float* fm4   = (float*)alloc((size_t)4 * 128 * 512 * 4);
  float* fg    = (float*)alloc((size_t)4 * 512 * 4);
  int*   ni1   = (int*)alloc((size_t)4 * 2048 * 4);
  int*   ni2   = (int*)alloc((size_t)4 * 2048 * 4);

  const int PART_MODE = 0;  // 0 = jax_threefry_partitionable (modern default); 1 = legacy

  // permutations: seed 1 (n=2048 -> 2 rounds), seed 2 (n=512 -> 1 round)
  perm_kernel<<<1, 1024, 0, stream>>>(2048, 512, 0u, 1u, 2, PART_MODE, samp1);
  perm_kernel<<<1, 1024, 0, stream>>>(512, 128, 0u, 2u, 1, PART_MODE, samp2);

  // level-0 kNN (wave-per-query: 4 queries per 256-thread block)
  knn_wave_kernel<<<dim3(2048 / 4, 4), 256, 0, stream>>>(vertices, 2048, idx0);

  // fm0 = [conv_surface(64ch) | bn(relu(rgb))(64ch)]
  conv_surface_kernel<<<dim3(512, 4), 256, 0, stream>>>(vertices, idx0, dir0, fm0);
  rgb_kernel<<<dim3(512, 4), 256, 0, stream>>>(rgb_f, rgb_w, rgb_b, rbn_g, rbn_b, rbn_m, rbn_v, fm0);

  // layer 1: fout = fm0 @ w1 + b1 ; fm1 = relu(bn1(combine))
  matmul_bias_kernel<<<dim3(1024 / 64, 8192 / 64), dim3(16, 16), 0, stream>>>(fm0, w1, b1, fout, 8192, 128, 1024);
  conv_combine_kernel<<<dim3(2048, 4), 128, 0, stream>>>(idx0, vertices, fout, d1,
                                                         bn1_g, bn1_b, bn1_m, bn1_v, 1, fm1, 2048, 128);

  // pool 1 -> v1, fp1 ; level-1 kNN
  pool_kernel<<<dim3(512, 4), 128, 0, stream>>>(vertices, fm1, idx0, samp1, v1, fp1, 2048, 128);
  knn_wave_kernel<<<dim3(512 / 4, 4), 256, 0, stream>>>(v1, 512, idx1);

  // layer 2
  matmul_bias_kernel<<<dim3(2048 / 64, 2048 / 64), dim3(16, 16), 0, stream>>>(fp1, w2, b2, fout, 2048, 128, 2048);
  conv_combine_kernel<<<dim3(512, 4), 256, 0, stream>>>(idx1, v1, fout, d2,
                                                        bn2_g, bn2_b, bn2_m, bn2_v, 1, fm2, 512, 256);
  // layer 3
  matmul_bias_kernel<<<dim3(2048 / 64, 2048 / 64), dim3(16, 16), 0, stream>>>(fm2, w3, b3, fout, 2048, 256, 2048);
  conv_combine_kernel<<<dim3(512, 4), 256, 0, stream>>>(idx1, v1, fout, d3,
                                                        bn3_g, bn3_b, bn3_m, bn3_v, 1, fm3, 512, 256);

  // pool 2 -> v2, fp2 ; level-2 kNN
  pool_kernel<<<dim3(128, 4), 256, 0, stream>>>(v1, fm3, idx1, samp2, v2, fp2, 512, 256);
  knn_wave_kernel<<<dim3(128 / 4, 4), 256, 0, stream>>>(v2, 128, idx2);

  // layer 4 (no bn, no relu)
  matmul_bias_kernel<<<dim3(4096 / 64, 512 / 64), dim3(16, 16), 0, stream>>>(fp2, w4, b4, fout, 512, 256, 4096);
  conv_combine_kernel<<<dim3(128, 4), 512, 0, stream>>>(idx2, v2, fout, d4,
                                                        nullptr, nullptr, nullptr, nullptr, 0, fm4, 128, 512);

  // global max + upsample indices
  global_max_kernel<<<4, 512, 0, stream>>>(fm4, fg);
  nearest_kernel<<<dim3(8, 4), 256, 0, stream>>>(vertices, v1, 512, ni1);
  nearest_kernel<<<dim3(8, 4), 256, 0, stream>>>(vertices, v2, 128, ni2);

  // outputs
  output_kernel<<<dim3(8, 1792, 4), 256, 0, stream>>>(fm0, fm1, fm2, fm3, fm4, fg, ni1, ni2, out);
}

// Round 3
// 497.154 us; speedup vs baseline: 2.8688x; 1.1071x over previous
//
#include <hip/hip_runtime.h>
#include <math.h>

#define NB 10
#define KNN_K 11

// ---------------- Threefry-2x32-20 (JAX) ----------------
__device__ __forceinline__ void tf2x32(unsigned k0, unsigned k1, unsigned& x0, unsigned& x1) {
  unsigned ks0 = k0, ks1 = k1, ks2 = k0 ^ k1 ^ 0x1BD11BDAu;
  x0 += ks0; x1 += ks1;
#define TF_R(r) { x0 += x1; x1 = (x1 << (r)) | (x1 >> (32 - (r))); x1 ^= x0; }
  TF_R(13) TF_R(15) TF_R(26) TF_R(6)  x0 += ks1; x1 += ks2 + 1u;
  TF_R(17) TF_R(29) TF_R(16) TF_R(24) x0 += ks2; x1 += ks0 + 2u;
  TF_R(13) TF_R(15) TF_R(26) TF_R(6)  x0 += ks0; x1 += ks1 + 3u;
  TF_R(17) TF_R(29) TF_R(16) TF_R(24) x0 += ks1; x1 += ks2 + 4u;
  TF_R(13) TF_R(15) TF_R(26) TF_R(6)  x0 += ks2; x1 += ks0 + 5u;
#undef TF_R
}

__device__ __forceinline__ unsigned long long shfl_xor_u64(unsigned long long v, int m) {
  unsigned lo = (unsigned)v, hi = (unsigned)(v >> 32);
  lo = (unsigned)__shfl_xor((int)lo, m);
  hi = (unsigned)__shfl_xor((int)hi, m);
  return ((unsigned long long)hi << 32) | lo;
}

// Both jax.random.permutation replications in one kernel, one block each.
// Register-resident bitonic: thread t owns wires t and t+n/2. Composite key
// (bits<<32)|pos, ascending, up=((wire&kk)==0) — identical network and keys
// to the verified LDS version, so bit-identical results.
// block 0: n=2048, m=512, key(0,1), 2 rounds -> samp1
// block 1: n=512,  m=128, key(0,2), 1 round  -> samp2
__global__ __launch_bounds__(1024) void perm2_kernel(int* __restrict__ samp1,
                                                     int* __restrict__ samp2) {
  __shared__ unsigned long long buf[2][2048];
  __shared__ unsigned perm[2][2048];
  int which = blockIdx.x;
  int n = (which == 0) ? 2048 : 512;
  int m = (which == 0) ? 512 : 128;
  int R = (which == 0) ? 2 : 1;
  unsigned k0 = 0u, k1 = (which == 0) ? 1u : 2u;
  int* out = (which == 0) ? samp1 : samp2;
  int T = n >> 1;
  int t = threadIdx.x;
  bool act = (t < T);  // T is a multiple of 64 -> wave-uniform
  int pb = 0;
  unsigned valA = 0, valB = 0;
  int lb = 0;
  for (int r = 0; r < R; ++r) {
    unsigned a0 = 0u, a1 = 0u, s0 = 0u, s1 = 1u;
    tf2x32(k0, k1, a0, a1);  // next-round key
    tf2x32(k0, k1, s0, s1);  // subkey for bits
    unsigned long long kA = 0, kB = 0;
    if (act) {
      unsigned y0 = 0u, y1 = (unsigned)t;
      tf2x32(s0, s1, y0, y1);
      kA = ((unsigned long long)(y0 ^ y1) << 32) | (unsigned)t;
      y0 = 0u; y1 = (unsigned)(t + T);
      tf2x32(s0, s1, y0, y1);
      kB = ((unsigned long long)(y0 ^ y1) << 32) | (unsigned)(t + T);
    }
    for (int kk = 2; kk <= n; kk <<= 1) {
      for (int j = kk >> 1; j > 0; j >>= 1) {
        if (j == T) {
          // only at kk==n, up=true for all wires: ensure kA<=kB
          if (act) {
            unsigned long long lo = (kA < kB) ? kA : kB;
            unsigned long long hi = (kA < kB) ? kB : kA;
            kA = lo; kB = hi;
          }
        } else if (j >= 64) {
          if (act) { buf[lb][t] = kA; buf[lb][t + T] = kB; }
          __syncthreads();
          if (act) {
            unsigned long long okA = buf[lb][t ^ j];
            unsigned long long okB = buf[lb][(t ^ j) + T];
            bool lower = ((t & j) == 0);
            bool upA = ((t & kk) == 0);
            bool upB = (((t + T) & kk) == 0);
            kA = (upA == lower) ? (kA < okA ? kA : okA) : (kA < okA ? okA : kA);
            kB = (upB == lower) ? (kB < okB ? kB : okB) : (kB < okB ? okB : kB);
          }
          lb ^= 1;  // double-buffer: next LDS phase writes the other buffer
        } else {
          unsigned long long okA = shfl_xor_u64(kA, j);
          unsigned long long okB = shfl_xor_u64(kB, j);
          if (act) {
            bool lower = ((t & j) == 0);
            bool upA = ((t & kk) == 0);
            bool upB = (((t + T) & kk) == 0);
            kA = (upA == lower) ? (kA < okA ? kA : okA) : (kA < okA ? okA : kA);
            kB = (upB == lower) ? (kB < okB ? kB : okB) : (kB < okB ? okB : kB);
          }
        }
      }
    }
    // map sorted keys -> permutation values (low 32 bits = keygen position)
    if (act) {
      unsigned posA = (unsigned)(kA & 0xffffffffu);
      unsigned posB = (unsigned)(kB & 0xffffffffu);
      if (r == 0) { valA = posA; valB = posB; }
      else        { valA = perm[pb][posA]; valB = perm[pb][posB]; }
    }
    if (r + 1 < R) {
      __syncthreads();  // perm[pb] reads done before anyone proceeds
      if (act) { perm[pb ^ 1][t] = valA; perm[pb ^ 1][t + T] = valB; }
      pb ^= 1;
      __syncthreads();
    }
    k0 = a0; k1 = a1;
  }
  if (t < m) out[t] = (int)valA;
}

// ---------------- kNN: wave-per-query top-11, drop slot 0 ----------------
__global__ __launch_bounds__(256) void knn_wave_kernel(const float* __restrict__ v, int N,
                                                       int* __restrict__ out) {
  __shared__ float4 pts[2048];
  int b = blockIdx.y;
  const float* vb = v + (size_t)b * N * 3;
  for (int i = threadIdx.x; i < N; i += blockDim.x) {
    float x = vb[i * 3], y = vb[i * 3 + 1], z = vb[i * 3 + 2];
    pts[i] = make_float4(x, y, z, x * x + y * y + z * z);
  }
  __syncthreads();
  int wave = threadIdx.x >> 6;
  int lane = threadIdx.x & 63;
  int qi = blockIdx.x * 4 + wave;  // grid sized so qi < N always
  float4 p = pts[qi];
  float bd[KNN_K]; int bi[KNN_K];
#pragma unroll
  for (int t = 0; t < KNN_K; ++t) { bd[t] = 3.4e38f; bi[t] = 0x7fffffff; }
  for (int j = lane; j < N; j += 64) {
    float4 q = pts[j];
    float dot = p.x * q.x + p.y * q.y + p.z * q.z;
    float d = p.w + q.w - 2.0f * dot;
    if (d < bd[KNN_K - 1]) {
      float cd = d; int ci = j;
#pragma unroll
      for (int t = 0; t < KNN_K; ++t) {
        bool sw = cd < bd[t];
        float td = bd[t]; int ti = bi[t];
        bd[t] = sw ? cd : td; bi[t] = sw ? ci : ti;
        cd = sw ? td : cd;   ci = sw ? ti : ci;
      }
    }
  }
  int ptr = 0;
  int* o = out + ((size_t)b * N + qi) * NB;
#pragma unroll 1
  for (int t = 0; t < KNN_K; ++t) {
    float d = (ptr < KNN_K) ? bd[ptr] : 3.4e38f;
    int idx = (ptr < KNN_K) ? bi[ptr] : 0x7fffffff;
    float rd = d; int ridx = idx;
#pragma unroll
    for (int s = 32; s > 0; s >>= 1) {
      float od = __shfl_xor(rd, s);
      int oi = __shfl_xor(ridx, s);
      if (od < rd || (od == rd && oi < ridx)) { rd = od; ridx = oi; }
    }
    if (d == rd && idx == ridx) ptr++;
    if (t >= 1 && lane == 0) o[t - 1] = ridx;
  }
}

// ---------------- conv_surface (writes fm0 channels 0..63, fused outer relu) ----------------
__global__ void conv_surface_kernel(const float* __restrict__ v, const int* __restrict__ idx,
                                    const float* __restrict__ dir0, float* __restrict__ fm0) {
  __shared__ float dn[4][NB][3];
  int b = blockIdx.y;
  int n0 = blockIdx.x * 4;
  int tid = threadIdx.x;
  if (tid < 4 * NB) {
    int p = tid / NB, k = tid % NB;
    size_t row = (size_t)b * 2048 + (n0 + p);
    const float* c = v + row * 3;
    int nb = idx[row * NB + k];
    const float* q = v + ((size_t)b * 2048 + nb) * 3;
    float dx = q[0] - c[0], dy = q[1] - c[1], dz = q[2] - c[2];
    float nr = fmaxf(sqrtf(dx * dx + dy * dy + dz * dz), 1e-12f);
    dn[p][k][0] = dx / nr; dn[p][k][1] = dy / nr; dn[p][k][2] = dz / nr;
  }
  __syncthreads();
  int p = tid >> 6, c = tid & 63;
  int n = n0 + p;
  float acc = 0.f;
  for (int s = 0; s < 7; ++s) {
    int e = s * 64 + c;
    float d0 = dir0[e], d1 = dir0[448 + e], d2 = dir0[896 + e];
    float nr = fmaxf(sqrtf(d0 * d0 + d1 * d1 + d2 * d2), 1e-12f);
    d0 /= nr; d1 /= nr; d2 /= nr;
    float mx = 0.f;
    for (int k = 0; k < NB; ++k) {
      float t = dn[p][k][0] * d0 + dn[p][k][1] * d1 + dn[p][k][2] * d2;
      t = fmaxf(t, 0.f);
      mx = fmaxf(mx, t);
    }
    acc += mx;
  }
  fm0[((size_t)b * 2048 + n) * 128 + c] = fmaxf(acc, 0.f);
}

// ---------------- rgb branch (writes fm0 channels 64..127) ----------------
__global__ void rgb_kernel(const float* __restrict__ rgb_f, const float* __restrict__ w,
                           const float* __restrict__ bias, const float* __restrict__ g,
                           const float* __restrict__ bb, const float* __restrict__ mm,
                           const float* __restrict__ vv, float* __restrict__ fm0) {
  int b = blockIdx.y;
  int tid = threadIdx.x;
  int p = tid >> 6, o = tid & 63;
  int n = blockIdx.x * 4 + p;
  const float* f = rgb_f + (size_t)b * 32 * 2048;
  float acc = bias[o];
  for (int c = 0; c < 32; ++c) acc += w[o * 32 + c] * f[c * 2048 + n];
  acc = fmaxf(acc, 0.f);
  acc = (acc - mm[o]) / sqrtf(vv[o] + 1e-5f) * g[o] + bb[o];
  fm0[((size_t)b * 2048 + n) * 128 + 64 + o] = acc;
}

// ---------------- fp32 tiled matmul: C[MxN] = A[MxK] @ W[KxN] + bias ----------------
__global__ __launch_bounds__(256) void matmul_bias_kernel(const float* __restrict__ A,
                                                          const float* __restrict__ W,
                                                          const float* __restrict__ bias,
                                                          float* __restrict__ C,
                                                          int M, int K, int N) {
  __shared__ float As[16][65];
  __shared__ float Bs[16][65];
  int tx = threadIdx.x, ty = threadIdx.y;
  int tid = ty * 16 + tx;
  int m0 = blockIdx.y * 64, n0 = blockIdx.x * 64;
  float acc[4][4] = {};
  for (int kt = 0; kt < K; kt += 16) {
    for (int l = tid; l < 1024; l += 256) {
      int r = l >> 4, c = l & 15;
      As[c][r] = A[(size_t)(m0 + r) * K + kt + c];
    }
    for (int l = tid; l < 1024; l += 256) {
      int r = l >> 6, c = l & 63;
      Bs[r][c] = W[(size_t)(kt + r) * N + n0 + c];
    }
    __syncthreads();
#pragma unroll
    for (int kk = 0; kk < 16; ++kk) {
      float a[4], bv[4];
#pragma unroll
      for (int r = 0; r < 4; ++r) a[r] = As[kk][ty * 4 + r];
#pragma unroll
      for (int c = 0; c < 4; ++c) bv[c] = Bs[kk][tx * 4 + c];
#pragma unroll
      for (int r = 0; r < 4; ++r)
#pragma unroll
        for (int c = 0; c < 4; ++c) acc[r][c] += a[r] * bv[c];
    }
    __syncthreads();
  }
#pragma unroll
  for (int r = 0; r < 4; ++r) {
    int m = m0 + ty * 4 + r;
#pragma unroll
    for (int c = 0; c < 4; ++c) {
      int n = n0 + tx * 4 + c;
      C[(size_t)m * N + n] = acc[r][c] + bias[n];
    }
  }
}

// ---------------- conv_layer combine: center + sum_s max_k theta*supp, optional bn+relu ----------------
__global__ void conv_combine_kernel(const int* __restrict__ idx, const float* __restrict__ v,
                                    const float* __restrict__ fout, const float* __restrict__ dirs,
                                    const float* __restrict__ g, const float* __restrict__ bb,
                                    const float* __restrict__ mm, const float* __restrict__ vv,
                                    int use_bn_relu, float* __restrict__ outf, int Np, int Cout) {
  __shared__ float dn[NB][3];
  __shared__ int nbrow[NB];
  int b = blockIdx.y, n = blockIdx.x;
  int tid = threadIdx.x;
  size_t row = (size_t)b * Np + n;
  if (tid < NB) {
    int nb = idx[row * NB + tid];
    const float* c = v + row * 3;
    const float* q = v + ((size_t)b * Np + nb) * 3;
    float dx = q[0] - c[0], dy = q[1] - c[1], dz = q[2] - c[2];
    float nr = fmaxf(sqrtf(dx * dx + dy * dy + dz * dz), 1e-12f);
    dn[tid][0] = dx / nr; dn[tid][1] = dy / nr; dn[tid][2] = dz / nr;
    nbrow[tid] = b * Np + nb;
  }
  __syncthreads();
  int c = tid;
  int F = 8 * Cout;
  int W7 = 7 * Cout;
  float acc = fout[row * (size_t)F + c];  // center
  for (int s = 0; s < 7; ++s) {
    int e = s * Cout + c;
    float d0 = dirs[e], d1 = dirs[W7 + e], d2 = dirs[2 * W7 + e];
    float nr = fmaxf(sqrtf(d0 * d0 + d1 * d1 + d2 * d2), 1e-12f);
    d0 /= nr; d1 /= nr; d2 /= nr;
    float mx = -3.4e38f;
#pragma unroll
    for (int k = 0; k < NB; ++k) {
      float t = fmaxf(dn[k][0] * d0 + dn[k][1] * d1 + dn[k][2] * d2, 0.f);
      float sv = fout[(size_t)nbrow[k] * F + Cout + e];
      mx = fmaxf(mx, t * sv);
    }
    acc += mx;
  }
  if (use_bn_relu) {
    acc = (acc - mm[c]) / sqrtf(vv[c] + 1e-5f) * g[c] + bb[c];
    acc = fmaxf(acc, 0.f);
  }
  outf[row * (size_t)Cout + c] = acc;
}

// ---------------- pool: max over first-4 neighbors at sampled rows ----------------
__global__ void pool_kernel(const float* __restrict__ v, const float* __restrict__ fm,
                            const int* __restrict__ idx10, const int* __restrict__ samp,
                            float* __restrict__ v_out, float* __restrict__ f_out,
                            int Nin, int C) {
  int b = blockIdx.y, mi = blockIdx.x, c = threadIdx.x;
  int n = samp[mi];
  size_t row = (size_t)b * Nin + n;
  float mx = -3.4e38f;
#pragma unroll
  for (int j = 0; j < 4; ++j) {
    int nb = idx10[row * NB + j];
    mx = fmaxf(mx, fm[((size_t)b * Nin + nb) * C + c]);
  }
  int Mout = gridDim.x;
  f_out[((size_t)b * Mout + mi) * C + c] = mx;
  if (c < 3) v_out[((size_t)b * Mout + mi) * 3 + c] = v[row * 3 + c];
}

// ---------------- global max over points of fm4 ----------------
__global__ void global_max_kernel(const float* __restrict__ fm4, float* __restrict__ fg) {
  int b = blockIdx.x, c = threadIdx.x;
  float mx = -3.4e38f;
  for (int p = 0; p < 128; ++p) mx = fmaxf(mx, fm4[((size_t)b * 128 + p) * 512 + c]);
  fg[b * 512 + c] = mx;
}

// ---------------- nearest source index for each target point ----------------
__global__ void nearest_kernel(const float* __restrict__ tgt, const float* __restrict__ src,
                               int S, int* __restrict__ out) {
  __shared__ float4 sp[512];
  int b = blockIdx.y;
  for (int i = threadIdx.x; i < S; i += blockDim.x) {
    const float* q = src + ((size_t)b * S + i) * 3;
    float x = q[0], y = q[1], z = q[2];
    sp[i] = make_float4(x, y, z, x * x + y * y + z * z);
  }
  __syncthreads();
  int n = blockIdx.x * blockDim.x + threadIdx.x;
  const float* t = tgt + ((size_t)b * 2048 + n) * 3;
  float x = t[0], y = t[1], z = t[2];
  float sqt = x * x + y * y + z * z;
  float best = 3.4e38f; int bi = 0;
  for (int s = 0; s < S; ++s) {
    float4 q = sp[s];
    float d = q.w + sqt - 2.f * (x * q.x + y * q.y + z * q.z);
    if (d < best) { best = d; bi = s; }
  }
  out[(size_t)b * 2048 + n] = bi;
}

// ---------------- final transpose/concat into feat + fuse outputs ----------------
__global__ void output_kernel(const float* __restrict__ fm0, const float* __restrict__ fm1,
                              const float* __restrict__ fm2, const float* __restrict__ fm3,
                              const float* __restrict__ fm4, const float* __restrict__ fg,
                              const int* __restrict__ ni1, const int* __restrict__ ni2,
                              float* __restrict__ out) {
  int b = blockIdx.z, cc = blockIdx.y;
  int n = blockIdx.x * blockDim.x + threadIdx.x;
  size_t row = (size_t)b * 2048 + n;
  float val;
  if (cc < 128)       val = fm0[row * 128 + cc];
  else if (cc < 256)  val = fm1[row * 128 + (cc - 128)];
  else if (cc < 512)  val = fm2[((size_t)b * 512 + ni1[row]) * 256 + (cc - 256)];
  else if (cc < 768)  val = fm3[((size_t)b * 512 + ni1[row]) * 256 + (cc - 512)];
  else if (cc < 1280) val = fm4[((size_t)b * 128 + ni2[row]) * 512 + (cc - 768)];
  else                val = fg[b * 512 + (cc - 1280)];
  float* out0 = out;                              // (4,1280,2048)
  float* out1 = out + (size_t)4 * 1280 * 2048;    // (4,1792,2048)
  if (cc < 1280) out0[((size_t)b * 1280 + cc) * 2048 + n] = val;
  out1[((size_t)b * 1792 + cc) * 2048 + n] = val;
}

extern "C" void kernel_launch(void* const* d_in, const int* in_sizes, int n_in,
                              void* d_out, int out_size, void* d_ws, size_t ws_size,
                              hipStream_t stream) {
  (void)in_sizes; (void)n_in; (void)out_size; (void)ws_size;
  const float* vertices = (const float*)d_in[0];
  const float* rgb_f    = (const float*)d_in[1];
  const float* dir0     = (const float*)d_in[2];
  const float* w1 = (const float*)d_in[3],  *b1 = (const float*)d_in[4],  *d1 = (const float*)d_in[5];
  const float* w2 = (const float*)d_in[6],  *b2 = (const float*)d_in[7],  *d2 = (const float*)d_in[8];
  const float* w3 = (const float*)d_in[9],  *b3 = (const float*)d_in[10], *d3 = (const float*)d_in[11];
  const float* w4 = (const float*)d_in[12], *b4 = (const float*)d_in[13], *d4 = (const float*)d_in[14];
  const float* rgb_w = (const float*)d_in[15], *rgb_b = (const float*)d_in[16];
  const float* rbn_g = (const float*)d_in[17], *rbn_b = (const float*)d_in[18];
  const float* rbn_m = (const float*)d_in[19], *rbn_v = (const float*)d_in[20];
  const float* bn1_g = (const float*)d_in[21], *bn1_b = (const float*)d_in[22];
  const float* bn1_m = (const float*)d_in[23], *bn1_v = (const float*)d_in[24];
  const float* bn2_g = (const float*)d_in[25], *bn2_b = (const float*)d_in[26];
  const float* bn2_m = (const float*)d_in[27], *bn2_v = (const float*)d_in[28];
  const float* bn3_g = (const float*)d_in[29], *bn3_b = (const float*)d_in[30];
  const float* bn3_m = (const float*)d_in[31], *bn3_v = (const float*)d_in[32];
  float* out = (float*)d_out;

  char* ws = (char*)d_ws;
  size_t off = 0;
  auto alloc = [&](size_t bytes) -> void* {
    void* p = ws + off;
    off += (bytes + 255) & ~(size_t)255;
    return p;
  };
  int*   samp1 = (int*)alloc(512 * 4);
  int*   samp2 = (int*)alloc(128 * 4);
  int*   idx0  = (int*)alloc((size_t)4 * 2048 * NB * 4);
  int*   idx1  = (int*)alloc((size_t)4 * 512 * NB * 4);
  int*   idx2  = (int*)alloc((size_t)4 * 128 * NB * 4);
  float* fm0   = (float*)alloc((size_t)4 * 2048 * 128 * 4);
  float* fm1   = (float*)alloc((size_t)4 * 2048 * 128 * 4);
  float* fout  = (float*)alloc((size_t)4 * 2048 * 1024 * 4);  // reused by all 4 layers
  float* v1    = (float*)alloc((size_t)4 * 512 * 3 * 4);
  float* fp1   = (float*)alloc((size_t)4 * 512 * 128 * 4);
  float* fm2   = (float*)alloc((size_t)4 * 512 * 256 * 4);
  float* fm3   = (float*)alloc((size_t)4 * 512 * 256 * 4);
  float* v2    = (float*)alloc((size_t)4 * 128 * 3 * 4);
  float* fp2   = (float*)alloc((size_t)4 * 128 * 256 * 4);
  float* fm4   = (float*)alloc((size_t)4 * 128 * 512 * 4);
  float* fg    = (float*)alloc((size_t)4 * 512 * 4);
  int*   ni1   = (int*)alloc((size_t)4 * 2048 * 4);
  int*   ni2   = (int*)alloc((size_t)4 * 2048 * 4);

  // both permutations (block 0: n=2048 seed1; block 1: n=512 seed2)
  perm2_kernel<<<2, 1024, 0, stream>>>(samp1, samp2);

  // level-0 kNN (wave-per-query: 4 queries per 256-thread block)
  knn_wave_kernel<<<dim3(2048 / 4, 4), 256, 0, stream>>>(vertices, 2048, idx0);

  // fm0 = [conv_surface(64ch) | bn(relu(rgb))(64ch)]
  conv_surface_kernel<<<dim3(512, 4), 256, 0, stream>>>(vertices, idx0, dir0, fm0);
  rgb_kernel<<<dim3(512, 4), 256, 0, stream>>>(rgb_f, rgb_w, rgb_b, rbn_g, rbn_b, rbn_m, rbn_v, fm0);

  // layer 1: fout = fm0 @ w1 + b1 ; fm1 = relu(bn1(combine))
  matmul_bias_kernel<<<dim3(1024 / 64, 8192 / 64), dim3(16, 16), 0, stream>>>(fm0, w1, b1, fout, 8192, 128, 1024);
  conv_combine_kernel<<<dim3(2048, 4), 128, 0, stream>>>(idx0, vertices, fout, d1,
                                                         bn1_g, bn1_b, bn1_m, bn1_v, 1, fm1, 2048, 128);

  // pool 1 -> v1, fp1 ; level-1 kNN
  pool_kernel<<<dim3(512, 4), 128, 0, stream>>>(vertices, fm1, idx0, samp1, v1, fp1, 2048, 128);
  knn_wave_kernel<<<dim3(512 / 4, 4), 256, 0, stream>>>(v1, 512, idx1);

  // layer 2
  matmul_bias_kernel<<<dim3(2048 / 64, 2048 / 64), dim3(16, 16), 0, stream>>>(fp1, w2, b2, fout, 2048, 128, 2048);
  conv_combine_kernel<<<dim3(512, 4), 256, 0, stream>>>(idx1, v1, fout, d2,
                                                        bn2_g, bn2_b, bn2_m, bn2_v, 1, fm2, 512, 256);
  // layer 3
  matmul_bias_kernel<<<dim3(2048 / 64, 2048 / 64), dim3(16, 16), 0, stream>>>(fm2, w3, b3, fout, 2048, 256, 2048);
  conv_combine_kernel<<<dim3(512, 4), 256, 0, stream>>>(idx1, v1, fout, d3,
                                                        bn3_g, bn3_b, bn3_m, bn3_v, 1, fm3, 512, 256);

  // pool 2 -> v2, fp2 ; level-2 kNN
  pool_kernel<<<dim3(128, 4), 256, 0, stream>>>(v1, fm3, idx1, samp2, v2, fp2, 512, 256);
  knn_wave_kernel<<<dim3(128 / 4, 4), 256, 0, stream>>>(v2, 128, idx2);

  // layer 4 (no bn, no relu)
  matmul_bias_kernel<<<dim3(4096 / 64, 512 / 64), dim3(16, 16), 0, stream>>>(fp2, w4, b4, fout, 512, 256, 4096);
  conv_combine_kernel<<<dim3(128, 4), 512, 0, stream>>>(idx2, v2, fout, d4,
                                                        nullptr, nullptr, nullptr, nullptr, 0, fm4, 128, 512);

  // global max + upsample indices
  global_max_kernel<<<4, 512, 0, stream>>>(fm4, fg);
  nearest_kernel<<<dim3(8, 4), 256, 0, stream>>>(vertices, v1, 512, ni1);
  nearest_kernel<<<dim3(8, 4), 256, 0, stream>>>(vertices, v2, 128, ni2);

  // outputs
  output_kernel<<<dim3(8, 1792, 4), 256, 0, stream>>>(fm0, fm1, fm2, fm3, fm4, fg, ni1, ni2, out);
}

// Round 4
// 362.531 us; speedup vs baseline: 3.9341x; 1.3713x over previous
//
#include <hip/hip_runtime.h>
#include <hip/hip_bf16.h>
#include <math.h>

#define NB 10
#define KNN_K 11

typedef __attribute__((ext_vector_type(8))) short bf16x8;
typedef __attribute__((ext_vector_type(4))) float f32x4;

// ---------------- Threefry-2x32-20 (JAX) ----------------
__device__ __forceinline__ void tf2x32(unsigned k0, unsigned k1, unsigned& x0, unsigned& x1) {
  unsigned ks0 = k0, ks1 = k1, ks2 = k0 ^ k1 ^ 0x1BD11BDAu;
  x0 += ks0; x1 += ks1;
#define TF_R(r) { x0 += x1; x1 = (x1 << (r)) | (x1 >> (32 - (r))); x1 ^= x0; }
  TF_R(13) TF_R(15) TF_R(26) TF_R(6)  x0 += ks1; x1 += ks2 + 1u;
  TF_R(17) TF_R(29) TF_R(16) TF_R(24) x0 += ks2; x1 += ks0 + 2u;
  TF_R(13) TF_R(15) TF_R(26) TF_R(6)  x0 += ks0; x1 += ks1 + 3u;
  TF_R(17) TF_R(29) TF_R(16) TF_R(24) x0 += ks1; x1 += ks2 + 4u;
  TF_R(13) TF_R(15) TF_R(26) TF_R(6)  x0 += ks2; x1 += ks0 + 5u;
#undef TF_R
}

__device__ __forceinline__ unsigned long long shfl_xor_u64(unsigned long long v, int m) {
  unsigned lo = (unsigned)v, hi = (unsigned)(v >> 32);
  lo = (unsigned)__shfl_xor((int)lo, m);
  hi = (unsigned)__shfl_xor((int)hi, m);
  return ((unsigned long long)hi << 32) | lo;
}

// Both jax.random.permutation replications in one kernel, one block each.
__global__ __launch_bounds__(1024) void perm2_kernel(int* __restrict__ samp1,
                                                     int* __restrict__ samp2) {
  __shared__ unsigned long long buf[2][2048];
  __shared__ unsigned perm[2][2048];
  int which = blockIdx.x;
  int n = (which == 0) ? 2048 : 512;
  int m = (which == 0) ? 512 : 128;
  int R = (which == 0) ? 2 : 1;
  unsigned k0 = 0u, k1 = (which == 0) ? 1u : 2u;
  int* out = (which == 0) ? samp1 : samp2;
  int T = n >> 1;
  int t = threadIdx.x;
  bool act = (t < T);  // T is a multiple of 64 -> wave-uniform
  int pb = 0;
  unsigned valA = 0, valB = 0;
  int lb = 0;
  for (int r = 0; r < R; ++r) {
    unsigned a0 = 0u, a1 = 0u, s0 = 0u, s1 = 1u;
    tf2x32(k0, k1, a0, a1);
    tf2x32(k0, k1, s0, s1);
    unsigned long long kA = 0, kB = 0;
    if (act) {
      unsigned y0 = 0u, y1 = (unsigned)t;
      tf2x32(s0, s1, y0, y1);
      kA = ((unsigned long long)(y0 ^ y1) << 32) | (unsigned)t;
      y0 = 0u; y1 = (unsigned)(t + T);
      tf2x32(s0, s1, y0, y1);
      kB = ((unsigned long long)(y0 ^ y1) << 32) | (unsigned)(t + T);
    }
    for (int kk = 2; kk <= n; kk <<= 1) {
      for (int j = kk >> 1; j > 0; j >>= 1) {
        if (j == T) {
          if (act) {
            unsigned long long lo = (kA < kB) ? kA : kB;
            unsigned long long hi = (kA < kB) ? kB : kA;
            kA = lo; kB = hi;
          }
        } else if (j >= 64) {
          if (act) { buf[lb][t] = kA; buf[lb][t + T] = kB; }
          __syncthreads();
          if (act) {
            unsigned long long okA = buf[lb][t ^ j];
            unsigned long long okB = buf[lb][(t ^ j) + T];
            bool lower = ((t & j) == 0);
            bool upA = ((t & kk) == 0);
            bool upB = (((t + T) & kk) == 0);
            kA = (upA == lower) ? (kA < okA ? kA : okA) : (kA < okA ? okA : kA);
            kB = (upB == lower) ? (kB < okB ? kB : okB) : (kB < okB ? okB : kB);
          }
          lb ^= 1;
        } else {
          unsigned long long okA = shfl_xor_u64(kA, j);
          unsigned long long okB = shfl_xor_u64(kB, j);
          if (act) {
            bool lower = ((t & j) == 0);
            bool upA = ((t & kk) == 0);
            bool upB = (((t + T) & kk) == 0);
            kA = (upA == lower) ? (kA < okA ? kA : okA) : (kA < okA ? okA : kA);
            kB = (upB == lower) ? (kB < okB ? kB : okB) : (kB < okB ? okB : kB);
          }
        }
      }
    }
    if (act) {
      unsigned posA = (unsigned)(kA & 0xffffffffu);
      unsigned posB = (unsigned)(kB & 0xffffffffu);
      if (r == 0) { valA = posA; valB = posB; }
      else        { valA = perm[pb][posA]; valB = perm[pb][posB]; }
    }
    if (r + 1 < R) {
      __syncthreads();
      if (act) { perm[pb ^ 1][t] = valA; perm[pb ^ 1][t + T] = valB; }
      pb ^= 1;
      __syncthreads();
    }
    k0 = a0; k1 = a1;
  }
  if (t < m) out[t] = (int)valA;
}

// ---------------- kNN: wave-per-query top-11, drop slot 0 ----------------
__global__ __launch_bounds__(256) void knn_wave_kernel(const float* __restrict__ v, int N,
                                                       int* __restrict__ out) {
  __shared__ float4 pts[2048];
  int b = blockIdx.y;
  const float* vb = v + (size_t)b * N * 3;
  for (int i = threadIdx.x; i < N; i += blockDim.x) {
    float x = vb[i * 3], y = vb[i * 3 + 1], z = vb[i * 3 + 2];
    pts[i] = make_float4(x, y, z, x * x + y * y + z * z);
  }
  __syncthreads();
  int wave = threadIdx.x >> 6;
  int lane = threadIdx.x & 63;
  int qi = blockIdx.x * 4 + wave;
  float4 p = pts[qi];
  float bd[KNN_K]; int bi[KNN_K];
#pragma unroll
  for (int t = 0; t < KNN_K; ++t) { bd[t] = 3.4e38f; bi[t] = 0x7fffffff; }
  for (int j = lane; j < N; j += 64) {
    float4 q = pts[j];
    float dot = p.x * q.x + p.y * q.y + p.z * q.z;
    float d = p.w + q.w - 2.0f * dot;
    if (d < bd[KNN_K - 1]) {
      float cd = d; int ci = j;
#pragma unroll
      for (int t = 0; t < KNN_K; ++t) {
        bool sw = cd < bd[t];
        float td = bd[t]; int ti = bi[t];
        bd[t] = sw ? cd : td; bi[t] = sw ? ci : ti;
        cd = sw ? td : cd;   ci = sw ? ti : ci;
      }
    }
  }
  int ptr = 0;
  int* o = out + ((size_t)b * N + qi) * NB;
#pragma unroll 1
  for (int t = 0; t < KNN_K; ++t) {
    float d = (ptr < KNN_K) ? bd[ptr] : 3.4e38f;
    int idx = (ptr < KNN_K) ? bi[ptr] : 0x7fffffff;
    float rd = d; int ridx = idx;
#pragma unroll
    for (int s = 32; s > 0; s >>= 1) {
      float od = __shfl_xor(rd, s);
      int oi = __shfl_xor(ridx, s);
      if (od < rd || (od == rd && oi < ridx)) { rd = od; ridx = oi; }
    }
    if (d == rd && idx == ridx) ptr++;
    if (t >= 1 && lane == 0) o[t - 1] = ridx;
  }
}

// ---------------- conv_surface (fm0 ch 0..63, fp32 + bf16 copies) ----------------
__global__ void conv_surface_kernel(const float* __restrict__ v, const int* __restrict__ idx,
                                    const float* __restrict__ dir0, float* __restrict__ fm0,
                                    __hip_bfloat16* __restrict__ fm0b) {
  __shared__ float dn[4][NB][3];
  int b = blockIdx.y;
  int n0 = blockIdx.x * 4;
  int tid = threadIdx.x;
  if (tid < 4 * NB) {
    int p = tid / NB, k = tid % NB;
    size_t row = (size_t)b * 2048 + (n0 + p);
    const float* c = v + row * 3;
    int nb = idx[row * NB + k];
    const float* q = v + ((size_t)b * 2048 + nb) * 3;
    float dx = q[0] - c[0], dy = q[1] - c[1], dz = q[2] - c[2];
    float nr = fmaxf(sqrtf(dx * dx + dy * dy + dz * dz), 1e-12f);
    dn[p][k][0] = dx / nr; dn[p][k][1] = dy / nr; dn[p][k][2] = dz / nr;
  }
  __syncthreads();
  int p = tid >> 6, c = tid & 63;
  int n = n0 + p;
  float acc = 0.f;
  for (int s = 0; s < 7; ++s) {
    int e = s * 64 + c;
    float d0 = dir0[e], d1 = dir0[448 + e], d2 = dir0[896 + e];
    float nr = fmaxf(sqrtf(d0 * d0 + d1 * d1 + d2 * d2), 1e-12f);
    d0 /= nr; d1 /= nr; d2 /= nr;
    float mx = 0.f;
    for (int k = 0; k < NB; ++k) {
      float t = dn[p][k][0] * d0 + dn[p][k][1] * d1 + dn[p][k][2] * d2;
      t = fmaxf(t, 0.f);
      mx = fmaxf(mx, t);
    }
    acc += mx;
  }
  acc = fmaxf(acc, 0.f);
  size_t o = ((size_t)b * 2048 + n) * 128 + c;
  fm0[o] = acc;
  fm0b[o] = __float2bfloat16(acc);
}

// ---------------- rgb branch (fm0 ch 64..127) ----------------
__global__ void rgb_kernel(const float* __restrict__ rgb_f, const float* __restrict__ w,
                           const float* __restrict__ bias, const float* __restrict__ g,
                           const float* __restrict__ bb, const float* __restrict__ mm,
                           const float* __restrict__ vv, float* __restrict__ fm0,
                           __hip_bfloat16* __restrict__ fm0b) {
  int b = blockIdx.y;
  int tid = threadIdx.x;
  int p = tid >> 6, o = tid & 63;
  int n = blockIdx.x * 4 + p;
  const float* f = rgb_f + (size_t)b * 32 * 2048;
  float acc = bias[o];
  for (int c = 0; c < 32; ++c) acc += w[o * 32 + c] * f[c * 2048 + n];
  acc = fmaxf(acc, 0.f);
  acc = (acc - mm[o]) / sqrtf(vv[o] + 1e-5f) * g[o] + bb[o];
  size_t oo = ((size_t)b * 2048 + n) * 128 + 64 + o;
  fm0[oo] = acc;
  fm0b[oo] = __float2bfloat16(acc);
}

// ---------------- weight transpose+convert: W[K][N] fp32 -> WT[N][K] bf16 ----------------
__global__ __launch_bounds__(256) void wt_kernel(const float* __restrict__ w1, __hip_bfloat16* __restrict__ o1,
                                                 const float* __restrict__ w2, __hip_bfloat16* __restrict__ o2,
                                                 const float* __restrict__ w3, __hip_bfloat16* __restrict__ o3,
                                                 const float* __restrict__ w4, __hip_bfloat16* __restrict__ o4) {
  __shared__ float tbuf[32][33];
  int bid = blockIdx.x;
  const float* W; __hip_bfloat16* O; int K, N;
  if (bid < 128)      { W = w1; O = o1; K = 128; N = 1024; }
  else if (bid < 384) { bid -= 128; W = w2; O = o2; K = 128; N = 2048; }
  else if (bid < 896) { bid -= 384; W = w3; O = o3; K = 256; N = 2048; }
  else                { bid -= 896; W = w4; O = o4; K = 256; N = 4096; }
  int tpr = N / 32;
  int tk = bid / tpr, tn = bid % tpr;
  int tx = threadIdx.x & 31, ty = threadIdx.x >> 5;  // (32, 8)
#pragma unroll
  for (int i = 0; i < 4; ++i)
    tbuf[ty + 8 * i][tx] = W[(size_t)(tk * 32 + ty + 8 * i) * N + tn * 32 + tx];
  __syncthreads();
#pragma unroll
  for (int i = 0; i < 4; ++i)
    O[(size_t)(tn * 32 + ty + 8 * i) * K + tk * 32 + tx] = __float2bfloat16(tbuf[tx][ty + 8 * i]);
}

// ---------------- bf16 MFMA GEMM: C[M][N] = A[M][K] @ BT[N][K]^T + bias ----------------
// 128x128 tile, BK=32, 4 waves (2x2), 4x4 16x16 fragments per wave.
// Fragment layouts (guide-verified): A: row=lane&15, k=(lane>>4)*8+i;
// C/D: col=lane&15, row=(lane>>4)*4+reg.
__global__ __launch_bounds__(256) void mfma_gemm_kernel(const __hip_bfloat16* __restrict__ A,
                                                        const __hip_bfloat16* __restrict__ BT,
                                                        const float* __restrict__ bias,
                                                        float* __restrict__ C,
                                                        int M, int K, int N) {
  __shared__ __hip_bfloat16 Al[128 * 32];
  __shared__ __hip_bfloat16 Bl[128 * 32];
  int t = threadIdx.x;
  int l = t & 63;
  int w = t >> 6;
  int wm = w >> 1, wn = w & 1;
  int m0 = blockIdx.y * 128, n0 = blockIdx.x * 128;
  f32x4 zero = {0.f, 0.f, 0.f, 0.f};
  f32x4 acc[4][4];
#pragma unroll
  for (int i = 0; i < 4; ++i)
#pragma unroll
    for (int j = 0; j < 4; ++j) acc[i][j] = zero;

  for (int kt = 0; kt < K; kt += 32) {
    // stage 128x32 bf16 tiles (16B per thread per tile half)
#pragma unroll
    for (int j = 0; j < 2; ++j) {
      int c = t + 256 * j;
      int r = c >> 2, o = c & 3;
      *(uint4*)&Al[r * 32 + o * 8] = *(const uint4*)&A[(size_t)(m0 + r) * K + kt + o * 8];
      *(uint4*)&Bl[r * 32 + o * 8] = *(const uint4*)&BT[(size_t)(n0 + r) * K + kt + o * 8];
    }
    __syncthreads();
    bf16x8 af[4], bfv[4];
#pragma unroll
    for (int f = 0; f < 4; ++f) {
      af[f]  = *(const bf16x8*)&Al[(wm * 64 + f * 16 + (l & 15)) * 32 + (l >> 4) * 8];
      bfv[f] = *(const bf16x8*)&Bl[(wn * 64 + f * 16 + (l & 15)) * 32 + (l >> 4) * 8];
    }
#pragma unroll
    for (int i = 0; i < 4; ++i)
#pragma unroll
      for (int j = 0; j < 4; ++j)
        acc[i][j] = __builtin_amdgcn_mfma_f32_16x16x32_bf16(af[i], bfv[j], acc[i][j], 0, 0, 0);
    __syncthreads();
  }
  int col_l = l & 15, rbase = (l >> 4) * 4;
#pragma unroll
  for (int i = 0; i < 4; ++i) {
#pragma unroll
    for (int j = 0; j < 4; ++j) {
      int col = n0 + wn * 64 + j * 16 + col_l;
      float bv = bias[col];
#pragma unroll
      for (int r = 0; r < 4; ++r) {
        int m = m0 + wm * 64 + i * 16 + rbase + r;
        C[(size_t)m * N + col] = acc[i][j][r] + bv;
      }
    }
  }
}

// ---------------- conv_layer combine ----------------
__global__ void conv_combine_kernel(const int* __restrict__ idx, const float* __restrict__ v,
                                    const float* __restrict__ fout, const float* __restrict__ dirs,
                                    const float* __restrict__ g, const float* __restrict__ bb,
                                    const float* __restrict__ mm, const float* __restrict__ vv,
                                    int use_bn_relu, float* __restrict__ outf,
                                    __hip_bfloat16* __restrict__ outb, int Np, int Cout) {
  __shared__ float dn[NB][3];
  __shared__ int nbrow[NB];
  int b = blockIdx.y, n = blockIdx.x;
  int tid = threadIdx.x;
  size_t row = (size_t)b * Np + n;
  if (tid < NB) {
    int nb = idx[row * NB + tid];
    const float* c = v + row * 3;
    const float* q = v + ((size_t)b * Np + nb) * 3;
    float dx = q[0] - c[0], dy = q[1] - c[1], dz = q[2] - c[2];
    float nr = fmaxf(sqrtf(dx * dx + dy * dy + dz * dz), 1e-12f);
    dn[tid][0] = dx / nr; dn[tid][1] = dy / nr; dn[tid][2] = dz / nr;
    nbrow[tid] = b * Np + nb;
  }
  __syncthreads();
  int c = tid;
  int F = 8 * Cout;
  int W7 = 7 * Cout;
  float acc = fout[row * (size_t)F + c];  // center
  for (int s = 0; s < 7; ++s) {
    int e = s * Cout + c;
    float d0 = dirs[e], d1 = dirs[W7 + e], d2 = dirs[2 * W7 + e];
    float nr = fmaxf(sqrtf(d0 * d0 + d1 * d1 + d2 * d2), 1e-12f);
    d0 /= nr; d1 /= nr; d2 /= nr;
    float mx = -3.4e38f;
#pragma unroll
    for (int k = 0; k < NB; ++k) {
      float t = fmaxf(dn[k][0] * d0 + dn[k][1] * d1 + dn[k][2] * d2, 0.f);
      float sv = fout[(size_t)nbrow[k] * F + Cout + e];
      mx = fmaxf(mx, t * sv);
    }
    acc += mx;
  }
  if (use_bn_relu) {
    acc = (acc - mm[c]) / sqrtf(vv[c] + 1e-5f) * g[c] + bb[c];
    acc = fmaxf(acc, 0.f);
  }
  outf[row * (size_t)Cout + c] = acc;
  if (outb) outb[row * (size_t)Cout + c] = __float2bfloat16(acc);
}

// ---------------- pool: max over first-4 neighbors at sampled rows ----------------
__global__ void pool_kernel(const float* __restrict__ v, const float* __restrict__ fm,
                            const int* __restrict__ idx10, const int* __restrict__ samp,
                            float* __restrict__ v_out, float* __restrict__ f_out,
                            __hip_bfloat16* __restrict__ f_out_b, int Nin, int C) {
  int b = blockIdx.y, mi = blockIdx.x, c = threadIdx.x;
  int n = samp[mi];
  size_t row = (size_t)b * Nin + n;
  float mx = -3.4e38f;
#pragma unroll
  for (int j = 0; j < 4; ++j) {
    int nb = idx10[row * NB + j];
    mx = fmaxf(mx, fm[((size_t)b * Nin + nb) * C + c]);
  }
  int Mout = gridDim.x;
  f_out[((size_t)b * Mout + mi) * C + c] = mx;
  f_out_b[((size_t)b * Mout + mi) * C + c] = __float2bfloat16(mx);
  if (c < 3) v_out[((size_t)b * Mout + mi) * 3 + c] = v[row * 3 + c];
}

// ---------------- global max over points of fm4 ----------------
__global__ void global_max_kernel(const float* __restrict__ fm4, float* __restrict__ fg) {
  int b = blockIdx.x, c = threadIdx.x;
  float mx = -3.4e38f;
  for (int p = 0; p < 128; ++p) mx = fmaxf(mx, fm4[((size_t)b * 128 + p) * 512 + c]);
  fg[b * 512 + c] = mx;
}

// ---------------- nearest source index for each target point ----------------
__global__ void nearest_kernel(const float* __restrict__ tgt, const float* __restrict__ src,
                               int S, int* __restrict__ out) {
  __shared__ float4 sp[512];
  int b = blockIdx.y;
  for (int i = threadIdx.x; i < S; i += blockDim.x) {
    const float* q = src + ((size_t)b * S + i) * 3;
    float x = q[0], y = q[1], z = q[2];
    sp[i] = make_float4(x, y, z, x * x + y * y + z * z);
  }
  __syncthreads();
  int n = blockIdx.x * blockDim.x + threadIdx.x;
  const float* t = tgt + ((size_t)b * 2048 + n) * 3;
  float x = t[0], y = t[1], z = t[2];
  float sqt = x * x + y * y + z * z;
  float best = 3.4e38f; int bi = 0;
  for (int s = 0; s < S; ++s) {
    float4 q = sp[s];
    float d = q.w + sqt - 2.f * (x * q.x + y * q.y + z * q.z);
    if (d < best) { best = d; bi = s; }
  }
  out[(size_t)b * 2048 + n] = bi;
}

// ---------------- final transpose/concat into feat + fuse outputs ----------------
__global__ void output_kernel(const float* __restrict__ fm0, const float* __restrict__ fm1,
                              const float* __restrict__ fm2, const float* __restrict__ fm3,
                              const float* __restrict__ fm4, const float* __restrict__ fg,
                              const int* __restrict__ ni1, const int* __restrict__ ni2,
                              float* __restrict__ out) {
  int b = blockIdx.z, cc = blockIdx.y;
  int n = blockIdx.x * blockDim.x + threadIdx.x;
  size_t row = (size_t)b * 2048 + n;
  float val;
  if (cc < 128)       val = fm0[row * 128 + cc];
  else if (cc < 256)  val = fm1[row * 128 + (cc - 128)];
  else if (cc < 512)  val = fm2[((size_t)b * 512 + ni1[row]) * 256 + (cc - 256)];
  else if (cc < 768)  val = fm3[((size_t)b * 512 + ni1[row]) * 256 + (cc - 512)];
  else if (cc < 1280) val = fm4[((size_t)b * 128 + ni2[row]) * 512 + (cc - 768)];
  else                val = fg[b * 512 + (cc - 1280)];
  float* out0 = out;                              // (4,1280,2048)
  float* out1 = out + (size_t)4 * 1280 * 2048;    // (4,1792,2048)
  if (cc < 1280) out0[((size_t)b * 1280 + cc) * 2048 + n] = val;
  out1[((size_t)b * 1792 + cc) * 2048 + n] = val;
}

extern "C" void kernel_launch(void* const* d_in, const int* in_sizes, int n_in,
                              void* d_out, int out_size, void* d_ws, size_t ws_size,
                              hipStream_t stream) {
  (void)in_sizes; (void)n_in; (void)out_size; (void)ws_size;
  const float* vertices = (const float*)d_in[0];
  const float* rgb_f    = (const float*)d_in[1];
  const float* dir0     = (const float*)d_in[2];
  const float* w1 = (const float*)d_in[3],  *b1 = (const float*)d_in[4],  *d1 = (const float*)d_in[5];
  const float* w2 = (const float*)d_in[6],  *b2 = (const float*)d_in[7],  *d2 = (const float*)d_in[8];
  const float* w3 = (const float*)d_in[9],  *b3 = (const float*)d_in[10], *d3 = (const float*)d_in[11];
  const float* w4 = (const float*)d_in[12], *b4 = (const float*)d_in[13], *d4 = (const float*)d_in[14];
  const float* rgb_w = (const float*)d_in[15], *rgb_b = (const float*)d_in[16];
  const float* rbn_g = (const float*)d_in[17], *rbn_b = (const float*)d_in[18];
  const float* rbn_m = (const float*)d_in[19], *rbn_v = (const float*)d_in[20];
  const float* bn1_g = (const float*)d_in[21], *bn1_b = (const float*)d_in[22];
  const float* bn1_m = (const float*)d_in[23], *bn1_v = (const float*)d_in[24];
  const float* bn2_g = (const float*)d_in[25], *bn2_b = (const float*)d_in[26];
  const float* bn2_m = (const float*)d_in[27], *bn2_v = (const float*)d_in[28];
  const float* bn3_g = (const float*)d_in[29], *bn3_b = (const float*)d_in[30];
  const float* bn3_m = (const float*)d_in[31], *bn3_v = (const float*)d_in[32];
  float* out = (float*)d_out;

  char* ws = (char*)d_ws;
  size_t off = 0;
  auto alloc = [&](size_t bytes) -> void* {
    void* p = ws + off;
    off += (bytes + 255) & ~(size_t)255;
    return p;
  };
  int*   samp1 = (int*)alloc(512 * 4);
  int*   samp2 = (int*)alloc(128 * 4);
  int*   idx0  = (int*)alloc((size_t)4 * 2048 * NB * 4);
  int*   idx1  = (int*)alloc((size_t)4 * 512 * NB * 4);
  int*   idx2  = (int*)alloc((size_t)4 * 128 * NB * 4);
  float* fm0   = (float*)alloc((size_t)4 * 2048 * 128 * 4);
  float* fm1   = (float*)alloc((size_t)4 * 2048 * 128 * 4);
  float* fout  = (float*)alloc((size_t)4 * 2048 * 1024 * 4);  // reused by all 4 layers
  float* v1    = (float*)alloc((size_t)4 * 512 * 3 * 4);
  float* fp1   = (float*)alloc((size_t)4 * 512 * 128 * 4);
  float* fm2   = (float*)alloc((size_t)4 * 512 * 256 * 4);
  float* fm3   = (float*)alloc((size_t)4 * 512 * 256 * 4);
  float* v2    = (float*)alloc((size_t)4 * 128 * 3 * 4);
  float* fp2   = (float*)alloc((size_t)4 * 128 * 256 * 4);
  float* fm4   = (float*)alloc((size_t)4 * 128 * 512 * 4);
  float* fg    = (float*)alloc((size_t)4 * 512 * 4);
  int*   ni1   = (int*)alloc((size_t)4 * 2048 * 4);
  int*   ni2   = (int*)alloc((size_t)4 * 2048 * 4);
  // bf16 matmul operands
  __hip_bfloat16* fm0b = (__hip_bfloat16*)alloc((size_t)4 * 2048 * 128 * 2);
  __hip_bfloat16* fp1b = (__hip_bfloat16*)alloc((size_t)4 * 512 * 128 * 2);
  __hip_bfloat16* fm2b = (__hip_bfloat16*)alloc((size_t)4 * 512 * 256 * 2);
  __hip_bfloat16* fp2b = (__hip_bfloat16*)alloc((size_t)4 * 128 * 256 * 2);
  __hip_bfloat16* wt1  = (__hip_bfloat16*)alloc((size_t)1024 * 128 * 2);
  __hip_bfloat16* wt2  = (__hip_bfloat16*)alloc((size_t)2048 * 128 * 2);
  __hip_bfloat16* wt3  = (__hip_bfloat16*)alloc((size_t)2048 * 256 * 2);
  __hip_bfloat16* wt4  = (__hip_bfloat16*)alloc((size_t)4096 * 256 * 2);

  // weight transpose+convert (all 4 weights, one launch)
  wt_kernel<<<1920, 256, 0, stream>>>(w1, wt1, w2, wt2, w3, wt3, w4, wt4);

  // both permutations (block 0: n=2048 seed1; block 1: n=512 seed2)
  perm2_kernel<<<2, 1024, 0, stream>>>(samp1, samp2);

  // level-0 kNN (wave-per-query)
  knn_wave_kernel<<<dim3(2048 / 4, 4), 256, 0, stream>>>(vertices, 2048, idx0);

  // fm0 = [conv_surface(64ch) | bn(relu(rgb))(64ch)]
  conv_surface_kernel<<<dim3(512, 4), 256, 0, stream>>>(vertices, idx0, dir0, fm0, fm0b);
  rgb_kernel<<<dim3(512, 4), 256, 0, stream>>>(rgb_f, rgb_w, rgb_b, rbn_g, rbn_b, rbn_m, rbn_v, fm0, fm0b);

  // layer 1
  mfma_gemm_kernel<<<dim3(1024 / 128, 8192 / 128), 256, 0, stream>>>(fm0b, wt1, b1, fout, 8192, 128, 1024);
  conv_combine_kernel<<<dim3(2048, 4), 128, 0, stream>>>(idx0, vertices, fout, d1,
                                                         bn1_g, bn1_b, bn1_m, bn1_v, 1, fm1, nullptr, 2048, 128);

  // pool 1 -> v1, fp1(+bf16) ; level-1 kNN
  pool_kernel<<<dim3(512, 4), 128, 0, stream>>>(vertices, fm1, idx0, samp1, v1, fp1, fp1b, 2048, 128);
  knn_wave_kernel<<<dim3(512 / 4, 4), 256, 0, stream>>>(v1, 512, idx1);

  // layer 2 (emit fm2 bf16 for layer-3 A)
  mfma_gemm_kernel<<<dim3(2048 / 128, 2048 / 128), 256, 0, stream>>>(fp1b, wt2, b2, fout, 2048, 128, 2048);
  conv_combine_kernel<<<dim3(512, 4), 256, 0, stream>>>(idx1, v1, fout, d2,
                                                        bn2_g, bn2_b, bn2_m, bn2_v, 1, fm2, fm2b, 512, 256);
  // layer 3
  mfma_gemm_kernel<<<dim3(2048 / 128, 2048 / 128), 256, 0, stream>>>(fm2b, wt3, b3, fout, 2048, 256, 2048);
  conv_combine_kernel<<<dim3(512, 4), 256, 0, stream>>>(idx1, v1, fout, d3,
                                                        bn3_g, bn3_b, bn3_m, bn3_v, 1, fm3, nullptr, 512, 256);

  // pool 2 -> v2, fp2(+bf16) ; level-2 kNN
  pool_kernel<<<dim3(128, 4), 256, 0, stream>>>(v1, fm3, idx1, samp2, v2, fp2, fp2b, 512, 256);
  knn_wave_kernel<<<dim3(128 / 4, 4), 256, 0, stream>>>(v2, 128, idx2);

  // layer 4 (no bn, no relu)
  mfma_gemm_kernel<<<dim3(4096 / 128, 512 / 128), 256, 0, stream>>>(fp2b, wt4, b4, fout, 512, 256, 4096);
  conv_combine_kernel<<<dim3(128, 4), 512, 0, stream>>>(idx2, v2, fout, d4,
                                                        nullptr, nullptr, nullptr, nullptr, 0, fm4, nullptr, 128, 512);

  // global max + upsample indices
  global_max_kernel<<<4, 512, 0, stream>>>(fm4, fg);
  nearest_kernel<<<dim3(8, 4), 256, 0, stream>>>(vertices, v1, 512, ni1);
  nearest_kernel<<<dim3(8, 4), 256, 0, stream>>>(vertices, v2, 128, ni2);

  // outputs
  output_kernel<<<dim3(8, 1792, 4), 256, 0, stream>>>(fm0, fm1, fm2, fm3, fm4, fg, ni1, ni2, out);
}

// Round 6
// 340.523 us; speedup vs baseline: 4.1884x; 1.0646x over previous
//
#include <hip/hip_runtime.h>
#include <hip/hip_bf16.h>
#include <math.h>

#define NB 10
#define KNN_K 11

typedef __attribute__((ext_vector_type(8))) short bf16x8;
typedef __attribute__((ext_vector_type(4))) float f32x4;

// ---------------- Threefry-2x32-20 (JAX) ----------------
__device__ __forceinline__ void tf2x32(unsigned k0, unsigned k1, unsigned& x0, unsigned& x1) {
  unsigned ks0 = k0, ks1 = k1, ks2 = k0 ^ k1 ^ 0x1BD11BDAu;
  x0 += ks0; x1 += ks1;
#define TF_R(r) { x0 += x1; x1 = (x1 << (r)) | (x1 >> (32 - (r))); x1 ^= x0; }
  TF_R(13) TF_R(15) TF_R(26) TF_R(6)  x0 += ks1; x1 += ks2 + 1u;
  TF_R(17) TF_R(29) TF_R(16) TF_R(24) x0 += ks2; x1 += ks0 + 2u;
  TF_R(13) TF_R(15) TF_R(26) TF_R(6)  x0 += ks0; x1 += ks1 + 3u;
  TF_R(17) TF_R(29) TF_R(16) TF_R(24) x0 += ks1; x1 += ks2 + 4u;
  TF_R(13) TF_R(15) TF_R(26) TF_R(6)  x0 += ks2; x1 += ks0 + 5u;
#undef TF_R
}

__device__ __forceinline__ unsigned long long shfl_xor_u64(unsigned long long v, int m) {
  unsigned lo = (unsigned)v, hi = (unsigned)(v >> 32);
  lo = (unsigned)__shfl_xor((int)lo, m);
  hi = (unsigned)__shfl_xor((int)hi, m);
  return ((unsigned long long)hi << 32) | lo;
}

// Both jax.random.permutation replications in one kernel, one block each.
__global__ __launch_bounds__(1024) void perm2_kernel(int* __restrict__ samp1,
                                                     int* __restrict__ samp2) {
  __shared__ unsigned long long buf[2][2048];
  __shared__ unsigned perm[2][2048];
  int which = blockIdx.x;
  int n = (which == 0) ? 2048 : 512;
  int m = (which == 0) ? 512 : 128;
  int R = (which == 0) ? 2 : 1;
  unsigned k0 = 0u, k1 = (which == 0) ? 1u : 2u;
  int* out = (which == 0) ? samp1 : samp2;
  int T = n >> 1;
  int t = threadIdx.x;
  bool act = (t < T);  // T is a multiple of 64 -> wave-uniform
  int pb = 0;
  unsigned valA = 0, valB = 0;
  int lb = 0;
  for (int r = 0; r < R; ++r) {
    unsigned a0 = 0u, a1 = 0u, s0 = 0u, s1 = 1u;
    tf2x32(k0, k1, a0, a1);
    tf2x32(k0, k1, s0, s1);
    unsigned long long kA = 0, kB = 0;
    if (act) {
      unsigned y0 = 0u, y1 = (unsigned)t;
      tf2x32(s0, s1, y0, y1);
      kA = ((unsigned long long)(y0 ^ y1) << 32) | (unsigned)t;
      y0 = 0u; y1 = (unsigned)(t + T);
      tf2x32(s0, s1, y0, y1);
      kB = ((unsigned long long)(y0 ^ y1) << 32) | (unsigned)(t + T);
    }
    for (int kk = 2; kk <= n; kk <<= 1) {
      for (int j = kk >> 1; j > 0; j >>= 1) {
        if (j == T) {
          if (act) {
            unsigned long long lo = (kA < kB) ? kA : kB;
            unsigned long long hi = (kA < kB) ? kB : kA;
            kA = lo; kB = hi;
          }
        } else if (j >= 64) {
          if (act) { buf[lb][t] = kA; buf[lb][t + T] = kB; }
          __syncthreads();
          if (act) {
            unsigned long long okA = buf[lb][t ^ j];
            unsigned long long okB = buf[lb][(t ^ j) + T];
            bool lower = ((t & j) == 0);
            bool upA = ((t & kk) == 0);
            bool upB = (((t + T) & kk) == 0);
            kA = (upA == lower) ? (kA < okA ? kA : okA) : (kA < okA ? okA : kA);
            kB = (upB == lower) ? (kB < okB ? kB : okB) : (kB < okB ? okB : kB);
          }
          lb ^= 1;
        } else {
          unsigned long long okA = shfl_xor_u64(kA, j);
          unsigned long long okB = shfl_xor_u64(kB, j);
          if (act) {
            bool lower = ((t & j) == 0);
            bool upA = ((t & kk) == 0);
            bool upB = (((t + T) & kk) == 0);
            kA = (upA == lower) ? (kA < okA ? kA : okA) : (kA < okA ? okA : kA);
            kB = (upB == lower) ? (kB < okB ? kB : okB) : (kB < okB ? okB : kB);
          }
        }
      }
    }
    if (act) {
      unsigned posA = (unsigned)(kA & 0xffffffffu);
      unsigned posB = (unsigned)(kB & 0xffffffffu);
      if (r == 0) { valA = posA; valB = posB; }
      else        { valA = perm[pb][posA]; valB = perm[pb][posB]; }
    }
    if (r + 1 < R) {
      __syncthreads();
      if (act) { perm[pb ^ 1][t] = valA; perm[pb ^ 1][t + T] = valB; }
      pb ^= 1;
      __syncthreads();
    }
    k0 = a0; k1 = a1;
  }
  if (t < m) out[t] = (int)valA;
}

// ---------------- kNN: wave-per-query top-11, drop slot 0 ----------------
__global__ __launch_bounds__(256) void knn_wave_kernel(const float* __restrict__ v, int N,
                                                       int* __restrict__ out) {
  __shared__ float4 pts[2048];
  int b = blockIdx.y;
  const float* vb = v + (size_t)b * N * 3;
  for (int i = threadIdx.x; i < N; i += blockDim.x) {
    float x = vb[i * 3], y = vb[i * 3 + 1], z = vb[i * 3 + 2];
    pts[i] = make_float4(x, y, z, x * x + y * y + z * z);
  }
  __syncthreads();
  int wave = threadIdx.x >> 6;
  int lane = threadIdx.x & 63;
  int qi = blockIdx.x * 4 + wave;
  float4 p = pts[qi];
  float bd[KNN_K]; int bi[KNN_K];
#pragma unroll
  for (int t = 0; t < KNN_K; ++t) { bd[t] = 3.4e38f; bi[t] = 0x7fffffff; }
  for (int j = lane; j < N; j += 64) {
    float4 q = pts[j];
    float dot = p.x * q.x + p.y * q.y + p.z * q.z;
    float d = p.w + q.w - 2.0f * dot;
    if (d < bd[KNN_K - 1]) {
      float cd = d; int ci = j;
#pragma unroll
      for (int t = 0; t < KNN_K; ++t) {
        bool sw = cd < bd[t];
        float td = bd[t]; int ti = bi[t];
        bd[t] = sw ? cd : td; bi[t] = sw ? ci : ti;
        cd = sw ? td : cd;   ci = sw ? ti : ci;
      }
    }
  }
  int ptr = 0;
  int* o = out + ((size_t)b * N + qi) * NB;
#pragma unroll 1
  for (int t = 0; t < KNN_K; ++t) {
    float d = (ptr < KNN_K) ? bd[ptr] : 3.4e38f;
    int idx = (ptr < KNN_K) ? bi[ptr] : 0x7fffffff;
    float rd = d; int ridx = idx;
#pragma unroll
    for (int s = 32; s > 0; s >>= 1) {
      float od = __shfl_xor(rd, s);
      int oi = __shfl_xor(ridx, s);
      if (od < rd || (od == rd && oi < ridx)) { rd = od; ridx = oi; }
    }
    if (d == rd && idx == ridx) ptr++;
    if (t >= 1 && lane == 0) o[t - 1] = ridx;
  }
}

// ---------------- normalize all direction matrices once (norm over the 3-dim axis) ----------------
__global__ __launch_bounds__(256) void dirnorm_kernel(const float* __restrict__ s0, float* __restrict__ o0,
                                                      const float* __restrict__ s1, float* __restrict__ o1,
                                                      const float* __restrict__ s2, float* __restrict__ o2,
                                                      const float* __restrict__ s3, float* __restrict__ o3,
                                                      const float* __restrict__ s4, float* __restrict__ o4) {
  int e = blockIdx.x * 256 + threadIdx.x;
  const float* S; float* D; int W;
  if (e < 448)                      { S = s0; D = o0; W = 448; }
  else if (e < 448 + 896)           { e -= 448; S = s1; D = o1; W = 896; }
  else if (e < 448 + 896 + 1792)    { e -= 448 + 896; S = s2; D = o2; W = 1792; }
  else if (e < 448 + 896 + 3584)    { e -= 448 + 896 + 1792; S = s3; D = o3; W = 1792; }
  else if (e < 448 + 896 + 3584 + 3584) { e -= 448 + 896 + 3584; S = s4; D = o4; W = 3584; }
  else return;
  float a = S[e], b = S[W + e], c = S[2 * W + e];
  float nr = fmaxf(sqrtf(a * a + b * b + c * c), 1e-12f);
  D[e] = a / nr; D[W + e] = b / nr; D[2 * W + e] = c / nr;
}

// ---------------- fused fm0: conv_surface (ch 0..63) + bn(relu(rgb)) (ch 64..127) ----------------
__global__ __launch_bounds__(256) void fm0_kernel(const float* __restrict__ v, const int* __restrict__ idx,
                                                  const float* __restrict__ dir0n,
                                                  const float* __restrict__ rgb_f, const float* __restrict__ w,
                                                  const float* __restrict__ bias, const float* __restrict__ g,
                                                  const float* __restrict__ bb, const float* __restrict__ mm,
                                                  const float* __restrict__ vv,
                                                  float* __restrict__ fm0, __hip_bfloat16* __restrict__ fm0b) {
  __shared__ float dn[4][NB][3];
  int b = blockIdx.y;
  int n0 = blockIdx.x * 4;
  int tid = threadIdx.x;
  if (tid < 4 * NB) {
    int p = tid / NB, k = tid % NB;
    size_t row = (size_t)b * 2048 + (n0 + p);
    const float* c = v + row * 3;
    int nb = idx[row * NB + k];
    const float* q = v + ((size_t)b * 2048 + nb) * 3;
    float dx = q[0] - c[0], dy = q[1] - c[1], dz = q[2] - c[2];
    float nr = fmaxf(sqrtf(dx * dx + dy * dy + dz * dz), 1e-12f);
    dn[p][k][0] = dx / nr; dn[p][k][1] = dy / nr; dn[p][k][2] = dz / nr;
  }
  __syncthreads();
  int p = tid >> 6, c = tid & 63;
  int n = n0 + p;
  // surface half
  float acc = 0.f;
  for (int s = 0; s < 7; ++s) {
    int e = s * 64 + c;
    float d0 = dir0n[e], d1 = dir0n[448 + e], d2 = dir0n[896 + e];
    float mx = 0.f;
#pragma unroll
    for (int k = 0; k < NB; ++k) {
      float t = dn[p][k][0] * d0 + dn[p][k][1] * d1 + dn[p][k][2] * d2;
      mx = fmaxf(mx, fmaxf(t, 0.f));
    }
    acc += mx;
  }
  acc = fmaxf(acc, 0.f);
  // rgb half
  const float* f = rgb_f + (size_t)b * 32 * 2048;
  float a2 = bias[c];
  for (int cc = 0; cc < 32; ++cc) a2 += w[c * 32 + cc] * f[cc * 2048 + n];
  a2 = fmaxf(a2, 0.f);
  a2 = (a2 - mm[c]) / sqrtf(vv[c] + 1e-5f) * g[c] + bb[c];
  size_t o = ((size_t)b * 2048 + n) * 128;
  fm0[o + c] = acc;
  fm0[o + 64 + c] = a2;
  fm0b[o + c] = __float2bfloat16(acc);
  fm0b[o + 64 + c] = __float2bfloat16(a2);
}

// ---------------- weight transpose+convert: W[K][N] fp32 -> WT[N][K] bf16 ----------------
__global__ __launch_bounds__(256) void wt_kernel(const float* __restrict__ w1, __hip_bfloat16* __restrict__ o1,
                                                 const float* __restrict__ w2, __hip_bfloat16* __restrict__ o2,
                                                 const float* __restrict__ w3, __hip_bfloat16* __restrict__ o3,
                                                 const float* __restrict__ w4, __hip_bfloat16* __restrict__ o4) {
  __shared__ float tbuf[32][33];
  int bid = blockIdx.x;
  const float* W; __hip_bfloat16* O; int K, N;
  if (bid < 128)      { W = w1; O = o1; K = 128; N = 1024; }
  else if (bid < 384) { bid -= 128; W = w2; O = o2; K = 128; N = 2048; }
  else if (bid < 896) { bid -= 384; W = w3; O = o3; K = 256; N = 2048; }
  else                { bid -= 896; W = w4; O = o4; K = 256; N = 4096; }
  int tpr = N / 32;
  int tk = bid / tpr, tn = bid % tpr;
  int tx = threadIdx.x & 31, ty = threadIdx.x >> 5;  // (32, 8)
#pragma unroll
  for (int i = 0; i < 4; ++i)
    tbuf[ty + 8 * i][tx] = W[(size_t)(tk * 32 + ty + 8 * i) * N + tn * 32 + tx];
  __syncthreads();
#pragma unroll
  for (int i = 0; i < 4; ++i)
    O[(size_t)(tn * 32 + ty + 8 * i) * K + tk * 32 + tx] = __float2bfloat16(tbuf[tx][ty + 8 * i]);
}

// ---------------- bf16 MFMA GEMM: C[M][N] = A[M][K] @ BT[N][K]^T + bias ----------------
__global__ __launch_bounds__(256) void mfma_gemm_kernel(const __hip_bfloat16* __restrict__ A,
                                                        const __hip_bfloat16* __restrict__ BT,
                                                        const float* __restrict__ bias,
                                                        float* __restrict__ C,
                                                        int M, int K, int N) {
  __shared__ __hip_bfloat16 Al[128 * 32];
  __shared__ __hip_bfloat16 Bl[128 * 32];
  int t = threadIdx.x;
  int l = t & 63;
  int w = t >> 6;
  int wm = w >> 1, wn = w & 1;
  int m0 = blockIdx.y * 128, n0 = blockIdx.x * 128;
  f32x4 zero = {0.f, 0.f, 0.f, 0.f};
  f32x4 acc[4][4];
#pragma unroll
  for (int i = 0; i < 4; ++i)
#pragma unroll
    for (int j = 0; j < 4; ++j) acc[i][j] = zero;

  for (int kt = 0; kt < K; kt += 32) {
#pragma unroll
    for (int j = 0; j < 2; ++j) {
      int c = t + 256 * j;
      int r = c >> 2, o = c & 3;
      *(uint4*)&Al[r * 32 + o * 8] = *(const uint4*)&A[(size_t)(m0 + r) * K + kt + o * 8];
      *(uint4*)&Bl[r * 32 + o * 8] = *(const uint4*)&BT[(size_t)(n0 + r) * K + kt + o * 8];
    }
    __syncthreads();
    bf16x8 af[4], bfv[4];
#pragma unroll
    for (int f = 0; f < 4; ++f) {
      af[f]  = *(const bf16x8*)&Al[(wm * 64 + f * 16 + (l & 15)) * 32 + (l >> 4) * 8];
      bfv[f] = *(const bf16x8*)&Bl[(wn * 64 + f * 16 + (l & 15)) * 32 + (l >> 4) * 8];
    }
#pragma unroll
    for (int i = 0; i < 4; ++i)
#pragma unroll
      for (int j = 0; j < 4; ++j)
        acc[i][j] = __builtin_amdgcn_mfma_f32_16x16x32_bf16(af[i], bfv[j], acc[i][j], 0, 0, 0);
    __syncthreads();
  }
  int col_l = l & 15, rbase = (l >> 4) * 4;
#pragma unroll
  for (int i = 0; i < 4; ++i) {
#pragma unroll
    for (int j = 0; j < 4; ++j) {
      int col = n0 + wn * 64 + j * 16 + col_l;
      float bv = bias[col];
#pragma unroll
      for (int r = 0; r < 4; ++r) {
        int m = m0 + wm * 64 + i * 16 + rbase + r;
        C[(size_t)m * N + col] = acc[i][j][r] + bv;
      }
    }
  }
}

// ---------------- conv_layer combine v2: wave-per-point, VEC channels/lane ----------------
template <int VEC>
__global__ __launch_bounds__(256) void conv_combine2_kernel(
    const int* __restrict__ idx, const float* __restrict__ v,
    const float* __restrict__ fout, const float* __restrict__ dirn,
    const float* __restrict__ g, const float* __restrict__ bb,
    const float* __restrict__ mm, const float* __restrict__ vv,
    int use_bn_relu, float* __restrict__ outf, __hip_bfloat16* __restrict__ outb,
    int Np, int Cout) {
  __shared__ float dnS[4][NB][3];
  __shared__ int nbS[4][NB];
  int b = blockIdx.y;
  int tid = threadIdx.x;
  int w = tid >> 6, lane = tid & 63;
  if (tid < 4 * NB) {
    int p = tid / NB, k = tid - p * NB;
    size_t prow = (size_t)b * Np + blockIdx.x * 4 + p;
    int nb = idx[prow * NB + k];
    const float* cpt = v + prow * 3;
    const float* q = v + ((size_t)b * Np + nb) * 3;
    float dx = q[0] - cpt[0], dy = q[1] - cpt[1], dz = q[2] - cpt[2];
    float nr = fmaxf(sqrtf(dx * dx + dy * dy + dz * dz), 1e-12f);
    dnS[p][k][0] = dx / nr; dnS[p][k][1] = dy / nr; dnS[p][k][2] = dz / nr;
    nbS[p][k] = b * Np + nb;
  }
  __syncthreads();
  int n = blockIdx.x * 4 + w;
  size_t row = (size_t)b * Np + n;
  float dn0[NB], dn1[NB], dn2[NB]; int nbr[NB];
#pragma unroll
  for (int k = 0; k < NB; ++k) {
    dn0[k] = dnS[w][k][0]; dn1[k] = dnS[w][k][1]; dn2[k] = dnS[w][k][2];
    nbr[k] = nbS[w][k];
  }
  int F = 8 * Cout, W7 = 7 * Cout;
  int c0 = lane * VEC;
  float acc[VEC];
#pragma unroll
  for (int u = 0; u < VEC; ++u) acc[u] = fout[row * (size_t)F + c0 + u];  // center
  for (int s = 0; s < 7; ++s) {
    int e0 = s * Cout + c0;
    float d0[VEC], d1[VEC], d2[VEC], mx[VEC];
#pragma unroll
    for (int u = 0; u < VEC; ++u) {
      d0[u] = dirn[e0 + u]; d1[u] = dirn[W7 + e0 + u]; d2[u] = dirn[2 * W7 + e0 + u];
      mx[u] = -3.4e38f;
    }
#pragma unroll
    for (int k = 0; k < NB; ++k) {
      const float* sp = &fout[(size_t)nbr[k] * F + Cout + e0];
#pragma unroll
      for (int u = 0; u < VEC; ++u) {
        float t = fmaxf(dn0[k] * d0[u] + dn1[k] * d1[u] + dn2[k] * d2[u], 0.f);
        mx[u] = fmaxf(mx[u], t * sp[u]);
      }
    }
#pragma unroll
    for (int u = 0; u < VEC; ++u) acc[u] += mx[u];
  }
#pragma unroll
  for (int u = 0; u < VEC; ++u) {
    float a = acc[u];
    if (use_bn_relu) {
      int c = c0 + u;
      a = (a - mm[c]) / sqrtf(vv[c] + 1e-5f) * g[c] + bb[c];
      a = fmaxf(a, 0.f);
    }
    acc[u] = a;
  }
#pragma unroll
  for (int u = 0; u < VEC; ++u) outf[row * (size_t)Cout + c0 + u] = acc[u];
  if (outb) {
#pragma unroll
    for (int u = 0; u < VEC; ++u) outb[row * (size_t)Cout + c0 + u] = __float2bfloat16(acc[u]);
  }
}

// ---------------- pool: max over first-4 neighbors at sampled rows ----------------
__global__ void pool_kernel(const float* __restrict__ v, const float* __restrict__ fm,
                            const int* __restrict__ idx10, const int* __restrict__ samp,
                            float* __restrict__ v_out, float* __restrict__ f_out,
                            __hip_bfloat16* __restrict__ f_out_b, int Nin, int C) {
  int b = blockIdx.y, mi = blockIdx.x, c = threadIdx.x;
  int n = samp[mi];
  size_t row = (size_t)b * Nin + n;
  float mx = -3.4e38f;
#pragma unroll
  for (int j = 0; j < 4; ++j) {
    int nb = idx10[row * NB + j];
    mx = fmaxf(mx, fm[((size_t)b * Nin + nb) * C + c]);
  }
  int Mout = gridDim.x;
  f_out[((size_t)b * Mout + mi) * C + c] = mx;
  f_out_b[((size_t)b * Mout + mi) * C + c] = __float2bfloat16(mx);
  if (c < 3) v_out[((size_t)b * Mout + mi) * 3 + c] = v[row * 3 + c];
}

// ---------------- global max over points of fm4 ----------------
__global__ void global_max_kernel(const float* __restrict__ fm4, float* __restrict__ fg) {
  int b = blockIdx.x, c = threadIdx.x;
  float mx = -3.4e38f;
  for (int p = 0; p < 128; ++p) mx = fmaxf(mx, fm4[((size_t)b * 128 + p) * 512 + c]);
  fg[b * 512 + c] = mx;
}

// ---------------- both nearest-source-index kernels in one (z selects level) ----------------
__global__ void nearest2_kernel(const float* __restrict__ tgt, const float* __restrict__ v1,
                                const float* __restrict__ v2, int* __restrict__ ni1,
                                int* __restrict__ ni2) {
  __shared__ float4 sp[512];
  int z = blockIdx.z;
  const float* src = z ? v2 : v1;
  int S = z ? 128 : 512;
  int* out = z ? ni2 : ni1;
  int b = blockIdx.y;
  for (int i = threadIdx.x; i < S; i += blockDim.x) {
    const float* q = src + ((size_t)b * S + i) * 3;
    float x = q[0], y = q[1], zz = q[2];
    sp[i] = make_float4(x, y, zz, x * x + y * y + zz * zz);
  }
  __syncthreads();
  int n = blockIdx.x * blockDim.x + threadIdx.x;
  const float* t = tgt + ((size_t)b * 2048 + n) * 3;
  float x = t[0], y = t[1], zz = t[2];
  float sqt = x * x + y * y + zz * zz;
  float best = 3.4e38f; int bi = 0;
  for (int s = 0; s < S; ++s) {
    float4 q = sp[s];
    float d = q.w + sqt - 2.f * (x * q.x + y * q.y + zz * q.z);
    if (d < best) { best = d; bi = s; }
  }
  out[(size_t)b * 2048 + n] = bi;
}

// ---------------- output v2: 64n x 32cc LDS-tiled transpose, coalesced both ways ----------------
__global__ __launch_bounds__(256) void output2_kernel(
    const float* __restrict__ fm0, const float* __restrict__ fm1,
    const float* __restrict__ fm2, const float* __restrict__ fm3,
    const float* __restrict__ fm4, const float* __restrict__ fg,
    const int* __restrict__ ni1, const int* __restrict__ ni2,
    float* __restrict__ out) {
  __shared__ float tile[64][33];
  __shared__ int srow[64];
  int b = blockIdx.z;
  int cc0 = blockIdx.y * 32;
  int n0 = blockIdx.x * 64;
  int tid = threadIdx.x;
  const float* P; int Cs, coff, mode;
  if (cc0 < 128)       { P = fm0; Cs = 128; coff = cc0;        mode = 0; }
  else if (cc0 < 256)  { P = fm1; Cs = 128; coff = cc0 - 128;  mode = 0; }
  else if (cc0 < 512)  { P = fm2; Cs = 256; coff = cc0 - 256;  mode = 1; }
  else if (cc0 < 768)  { P = fm3; Cs = 256; coff = cc0 - 512;  mode = 1; }
  else if (cc0 < 1280) { P = fm4; Cs = 512; coff = cc0 - 768;  mode = 2; }
  else                 { P = fg;  Cs = 512; coff = cc0 - 1280; mode = 3; }
  if (tid < 64) {
    int n = n0 + tid;
    size_t r2 = (size_t)b * 2048 + n;
    int sr;
    if (mode == 0)      sr = b * 2048 + n;
    else if (mode == 1) sr = b * 512 + ni1[r2];
    else if (mode == 2) sr = b * 128 + ni2[r2];
    else                sr = b;
    srow[tid] = sr;
  }
  __syncthreads();
  int tx = tid & 31, ty = tid >> 5;  // 32 x 8
#pragma unroll
  for (int r = 0; r < 8; ++r) {
    int nl = ty + 8 * r;
    tile[nl][tx] = P[(size_t)srow[nl] * Cs + coff + tx];
  }
  __syncthreads();
  int lx = tid & 63, ly = tid >> 6;  // 64 x 4
  float* out0 = out;                              // (4,1280,2048)
  float* out1 = out + (size_t)4 * 1280 * 2048;    // (4,1792,2048)
#pragma unroll
  for (int ci = 0; ci < 8; ++ci) {
    int cl = ly + 4 * ci;
    int cc = cc0 + cl;
    float vv = tile[lx][cl];
    out1[((size_t)b * 1792 + cc) * 2048 + n0 + lx] = vv;
    if (cc < 1280) out0[((size_t)b * 1280 + cc) * 2048 + n0 + lx] = vv;
  }
}

extern "C" void kernel_launch(void* const* d_in, const int* in_sizes, int n_in,
                              void* d_out, int out_size, void* d_ws, size_t ws_size,
                              hipStream_t stream) {
  (void)in_sizes; (void)n_in; (void)out_size; (void)ws_size;
  const float* vertices = (const float*)d_in[0];
  const float* rgb_f    = (const float*)d_in[1];
  const float* dir0     = (const float*)d_in[2];
  const float* w1 = (const float*)d_in[3],  *b1 = (const float*)d_in[4],  *d1 = (const float*)d_in[5];
  const float* w2 = (const float*)d_in[6],  *b2 = (const float*)d_in[7],  *d2 = (const float*)d_in[8];
  const float* w3 = (const float*)d_in[9],  *b3 = (const float*)d_in[10], *d3 = (const float*)d_in[11];
  const float* w4 = (const float*)d_in[12], *b4 = (const float*)d_in[13], *d4 = (const float*)d_in[14];
  const float* rgb_w = (const float*)d_in[15], *rgb_b = (const float*)d_in[16];
  const float* rbn_g = (const float*)d_in[17], *rbn_b = (const float*)d_in[18];
  const float* rbn_m = (const float*)d_in[19], *rbn_v = (const float*)d_in[20];
  const float* bn1_g = (const float*)d_in[21], *bn1_b = (const float*)d_in[22];
  const float* bn1_m = (const float*)d_in[23], *bn1_v = (const float*)d_in[24];
  const float* bn2_g = (const float*)d_in[25], *bn2_b = (const float*)d_in[26];
  const float* bn2_m = (const float*)d_in[27], *bn2_v = (const float*)d_in[28];
  const float* bn3_g = (const float*)d_in[29], *bn3_b = (const float*)d_in[30];
  const float* bn3_m = (const float*)d_in[31], *bn3_v = (const float*)d_in[32];
  float* out = (float*)d_out;

  char* ws = (char*)d_ws;
  size_t off = 0;
  auto alloc = [&](size_t bytes) -> void* {
    void* p = ws + off;
    off += (bytes + 255) & ~(size_t)255;
    return p;
  };
  int*   samp1 = (int*)alloc(512 * 4);
  int*   samp2 = (int*)alloc(128 * 4);
  int*   idx0  = (int*)alloc((size_t)4 * 2048 * NB * 4);
  int*   idx1  = (int*)alloc((size_t)4 * 512 * NB * 4);
  int*   idx2  = (int*)alloc((size_t)4 * 128 * NB * 4);
  float* fm0   = (float*)alloc((size_t)4 * 2048 * 128 * 4);
  float* fm1   = (float*)alloc((size_t)4 * 2048 * 128 * 4);
  float* fout  = (float*)alloc((size_t)4 * 2048 * 1024 * 4);  // reused by all 4 layers
  float* v1    = (float*)alloc((size_t)4 * 512 * 3 * 4);
  float* fp1   = (float*)alloc((size_t)4 * 512 * 128 * 4);
  float* fm2   = (float*)alloc((size_t)4 * 512 * 256 * 4);
  float* fm3   = (float*)alloc((size_t)4 * 512 * 256 * 4);
  float* v2    = (float*)alloc((size_t)4 * 128 * 3 * 4);
  float* fp2   = (float*)alloc((size_t)4 * 128 * 256 * 4);
  float* fm4   = (float*)alloc((size_t)4 * 128 * 512 * 4);
  float* fg    = (float*)alloc((size_t)4 * 512 * 4);
  int*   ni1   = (int*)alloc((size_t)4 * 2048 * 4);
  int*   ni2   = (int*)alloc((size_t)4 * 2048 * 4);
  // bf16 matmul operands
  __hip_bfloat16* fm0b = (__hip_bfloat16*)alloc((size_t)4 * 2048 * 128 * 2);
  __hip_bfloat16* fp1b = (__hip_bfloat16*)alloc((size_t)4 * 512 * 128 * 2);
  __hip_bfloat16* fm2b = (__hip_bfloat16*)alloc((size_t)4 * 512 * 256 * 2);
  __hip_bfloat16* fp2b = (__hip_bfloat16*)alloc((size_t)4 * 128 * 256 * 2);
  __hip_bfloat16* wt1  = (__hip_bfloat16*)alloc((size_t)1024 * 128 * 2);
  __hip_bfloat16* wt2  = (__hip_bfloat16*)alloc((size_t)2048 * 128 * 2);
  __hip_bfloat16* wt3  = (__hip_bfloat16*)alloc((size_t)2048 * 256 * 2);
  __hip_bfloat16* wt4  = (__hip_bfloat16*)alloc((size_t)4096 * 256 * 2);
  // normalized directions
  float* d0n = (float*)alloc((size_t)3 * 448 * 4);
  float* d1n = (float*)alloc((size_t)3 * 896 * 4);
  float* d2n = (float*)alloc((size_t)3 * 1792 * 4);
  float* d3n = (float*)alloc((size_t)3 * 1792 * 4);
  float* d4n = (float*)alloc((size_t)3 * 3584 * 4);

  // one-shot prep: weight transpose+convert, direction normalization, permutations
  wt_kernel<<<1920, 256, 0, stream>>>(w1, wt1, w2, wt2, w3, wt3, w4, wt4);
  dirnorm_kernel<<<34, 256, 0, stream>>>(dir0, d0n, d1, d1n, d2, d2n, d3, d3n, d4, d4n);
  perm2_kernel<<<2, 1024, 0, stream>>>(samp1, samp2);

  // level-0 kNN (wave-per-query)
  knn_wave_kernel<<<dim3(2048 / 4, 4), 256, 0, stream>>>(vertices, 2048, idx0);

  // fm0 = [conv_surface(64ch) | bn(relu(rgb))(64ch)]  (fused)
  fm0_kernel<<<dim3(512, 4), 256, 0, stream>>>(vertices, idx0, d0n, rgb_f, rgb_w, rgb_b,
                                               rbn_g, rbn_b, rbn_m, rbn_v, fm0, fm0b);

  // layer 1
  mfma_gemm_kernel<<<dim3(1024 / 128, 8192 / 128), 256, 0, stream>>>(fm0b, wt1, b1, fout, 8192, 128, 1024);
  conv_combine2_kernel<2><<<dim3(512, 4), 256, 0, stream>>>(idx0, vertices, fout, d1n,
      bn1_g, bn1_b, bn1_m, bn1_v, 1, fm1, nullptr, 2048, 128);

  // pool 1 -> v1, fp1(+bf16) ; level-1 kNN
  pool_kernel<<<dim3(512, 4), 128, 0, stream>>>(vertices, fm1, idx0, samp1, v1, fp1, fp1b, 2048, 128);
  knn_wave_kernel<<<dim3(512 / 4, 4), 256, 0, stream>>>(v1, 512, idx1);

  // layer 2 (emit fm2 bf16 for layer-3 A)
  mfma_gemm_kernel<<<dim3(2048 / 128, 2048 / 128), 256, 0, stream>>>(fp1b, wt2, b2, fout, 2048, 128, 2048);
  conv_combine2_kernel<4><<<dim3(128, 4), 256, 0, stream>>>(idx1, v1, fout, d2n,
      bn2_g, bn2_b, bn2_m, bn2_v, 1, fm2, fm2b, 512, 256);
  // layer 3
  mfma_gemm_kernel<<<dim3(2048 / 128, 2048 / 128), 256, 0, stream>>>(fm2b, wt3, b3, fout, 2048, 256, 2048);
  conv_combine2_kernel<4><<<dim3(128, 4), 256, 0, stream>>>(idx1, v1, fout, d3n,
      bn3_g, bn3_b, bn3_m, bn3_v, 1, fm3, nullptr, 512, 256);

  // pool 2 -> v2, fp2(+bf16) ; level-2 kNN
  pool_kernel<<<dim3(128, 4), 256, 0, stream>>>(v1, fm3, idx1, samp2, v2, fp2, fp2b, 512, 256);
  knn_wave_kernel<<<dim3(128 / 4, 4), 256, 0, stream>>>(v2, 128, idx2);

  // layer 4 (no bn, no relu)
  mfma_gemm_kernel<<<dim3(4096 / 128, 512 / 128), 256, 0, stream>>>(fp2b, wt4, b4, fout, 512, 256, 4096);
  conv_combine2_kernel<8><<<dim3(32, 4), 256, 0, stream>>>(idx2, v2, fout, d4n,
      nullptr, nullptr, nullptr, nullptr, 0, fm4, nullptr, 128, 512);

  // global max + upsample indices (both levels in one launch)
  global_max_kernel<<<4, 512, 0, stream>>>(fm4, fg);
  nearest2_kernel<<<dim3(8, 4, 2), 256, 0, stream>>>(vertices, v1, v2, ni1, ni2);

  // outputs (LDS-tiled transpose)
  output2_kernel<<<dim3(32, 56, 4), 256, 0, stream>>>(fm0, fm1, fm2, fm3, fm4, fg, ni1, ni2, out);
}

// Round 7
// 337.031 us; speedup vs baseline: 4.2318x; 1.0104x over previous
//
#include <hip/hip_runtime.h>
#include <hip/hip_bf16.h>
#include <math.h>

#define NB 10
#define KNN_K 11

typedef __attribute__((ext_vector_type(8))) short bf16x8;
typedef __attribute__((ext_vector_type(4))) float f32x4;

__device__ __forceinline__ float toF(float x) { return x; }
__device__ __forceinline__ float toF(__hip_bfloat16 x) { return __bfloat162float(x); }

// ---------------- Threefry-2x32-20 (JAX) ----------------
__device__ __forceinline__ void tf2x32(unsigned k0, unsigned k1, unsigned& x0, unsigned& x1) {
  unsigned ks0 = k0, ks1 = k1, ks2 = k0 ^ k1 ^ 0x1BD11BDAu;
  x0 += ks0; x1 += ks1;
#define TF_R(r) { x0 += x1; x1 = (x1 << (r)) | (x1 >> (32 - (r))); x1 ^= x0; }
  TF_R(13) TF_R(15) TF_R(26) TF_R(6)  x0 += ks1; x1 += ks2 + 1u;
  TF_R(17) TF_R(29) TF_R(16) TF_R(24) x0 += ks2; x1 += ks0 + 2u;
  TF_R(13) TF_R(15) TF_R(26) TF_R(6)  x0 += ks0; x1 += ks1 + 3u;
  TF_R(17) TF_R(29) TF_R(16) TF_R(24) x0 += ks1; x1 += ks2 + 4u;
  TF_R(13) TF_R(15) TF_R(26) TF_R(6)  x0 += ks2; x1 += ks0 + 5u;
#undef TF_R
}

__device__ __forceinline__ unsigned long long shfl_xor_u64(unsigned long long v, int m) {
  unsigned lo = (unsigned)v, hi = (unsigned)(v >> 32);
  lo = (unsigned)__shfl_xor((int)lo, m);
  hi = (unsigned)__shfl_xor((int)hi, m);
  return ((unsigned long long)hi << 32) | lo;
}

// Both jax.random.permutation replications in one kernel, one block each.
__global__ __launch_bounds__(1024) void perm2_kernel(int* __restrict__ samp1,
                                                     int* __restrict__ samp2) {
  __shared__ unsigned long long buf[2][2048];
  __shared__ unsigned perm[2][2048];
  int which = blockIdx.x;
  int n = (which == 0) ? 2048 : 512;
  int m = (which == 0) ? 512 : 128;
  int R = (which == 0) ? 2 : 1;
  unsigned k0 = 0u, k1 = (which == 0) ? 1u : 2u;
  int* out = (which == 0) ? samp1 : samp2;
  int T = n >> 1;
  int t = threadIdx.x;
  bool act = (t < T);  // T is a multiple of 64 -> wave-uniform
  int pb = 0;
  unsigned valA = 0, valB = 0;
  int lb = 0;
  for (int r = 0; r < R; ++r) {
    unsigned a0 = 0u, a1 = 0u, s0 = 0u, s1 = 1u;
    tf2x32(k0, k1, a0, a1);
    tf2x32(k0, k1, s0, s1);
    unsigned long long kA = 0, kB = 0;
    if (act) {
      unsigned y0 = 0u, y1 = (unsigned)t;
      tf2x32(s0, s1, y0, y1);
      kA = ((unsigned long long)(y0 ^ y1) << 32) | (unsigned)t;
      y0 = 0u; y1 = (unsigned)(t + T);
      tf2x32(s0, s1, y0, y1);
      kB = ((unsigned long long)(y0 ^ y1) << 32) | (unsigned)(t + T);
    }
    for (int kk = 2; kk <= n; kk <<= 1) {
      for (int j = kk >> 1; j > 0; j >>= 1) {
        if (j == T) {
          if (act) {
            unsigned long long lo = (kA < kB) ? kA : kB;
            unsigned long long hi = (kA < kB) ? kB : kA;
            kA = lo; kB = hi;
          }
        } else if (j >= 64) {
          if (act) { buf[lb][t] = kA; buf[lb][t + T] = kB; }
          __syncthreads();
          if (act) {
            unsigned long long okA = buf[lb][t ^ j];
            unsigned long long okB = buf[lb][(t ^ j) + T];
            bool lower = ((t & j) == 0);
            bool upA = ((t & kk) == 0);
            bool upB = (((t + T) & kk) == 0);
            kA = (upA == lower) ? (kA < okA ? kA : okA) : (kA < okA ? okA : kA);
            kB = (upB == lower) ? (kB < okB ? kB : okB) : (kB < okB ? okB : kB);
          }
          lb ^= 1;
        } else {
          unsigned long long okA = shfl_xor_u64(kA, j);
          unsigned long long okB = shfl_xor_u64(kB, j);
          if (act) {
            bool lower = ((t & j) == 0);
            bool upA = ((t & kk) == 0);
            bool upB = (((t + T) & kk) == 0);
            kA = (upA == lower) ? (kA < okA ? kA : okA) : (kA < okA ? okA : kA);
            kB = (upB == lower) ? (kB < okB ? kB : okB) : (kB < okB ? okB : kB);
          }
        }
      }
    }
    if (act) {
      unsigned posA = (unsigned)(kA & 0xffffffffu);
      unsigned posB = (unsigned)(kB & 0xffffffffu);
      if (r == 0) { valA = posA; valB = posB; }
      else        { valA = perm[pb][posA]; valB = perm[pb][posB]; }
    }
    if (r + 1 < R) {
      __syncthreads();
      if (act) { perm[pb ^ 1][t] = valA; perm[pb ^ 1][t + T] = valB; }
      pb ^= 1;
      __syncthreads();
    }
    k0 = a0; k1 = a1;
  }
  if (t < m) out[t] = (int)valA;
}

// ---------------- kNN: wave-per-query top-11, drop slot 0 ----------------
__global__ __launch_bounds__(256) void knn_wave_kernel(const float* __restrict__ v, int N,
                                                       int* __restrict__ out) {
  __shared__ float4 pts[2048];
  int b = blockIdx.y;
  const float* vb = v + (size_t)b * N * 3;
  for (int i = threadIdx.x; i < N; i += blockDim.x) {
    float x = vb[i * 3], y = vb[i * 3 + 1], z = vb[i * 3 + 2];
    pts[i] = make_float4(x, y, z, x * x + y * y + z * z);
  }
  __syncthreads();
  int wave = threadIdx.x >> 6;
  int lane = threadIdx.x & 63;
  int qi = blockIdx.x * 4 + wave;
  float4 p = pts[qi];
  float bd[KNN_K]; int bi[KNN_K];
#pragma unroll
  for (int t = 0; t < KNN_K; ++t) { bd[t] = 3.4e38f; bi[t] = 0x7fffffff; }
  for (int j = lane; j < N; j += 64) {
    float4 q = pts[j];
    float dot = p.x * q.x + p.y * q.y + p.z * q.z;
    float d = p.w + q.w - 2.0f * dot;
    if (d < bd[KNN_K - 1]) {
      float cd = d; int ci = j;
#pragma unroll
      for (int t = 0; t < KNN_K; ++t) {
        bool sw = cd < bd[t];
        float td = bd[t]; int ti = bi[t];
        bd[t] = sw ? cd : td; bi[t] = sw ? ci : ti;
        cd = sw ? td : cd;   ci = sw ? ti : ci;
      }
    }
  }
  int ptr = 0;
  int* o = out + ((size_t)b * N + qi) * NB;
#pragma unroll 1
  for (int t = 0; t < KNN_K; ++t) {
    float d = (ptr < KNN_K) ? bd[ptr] : 3.4e38f;
    int idx = (ptr < KNN_K) ? bi[ptr] : 0x7fffffff;
    float rd = d; int ridx = idx;
#pragma unroll
    for (int s = 32; s > 0; s >>= 1) {
      float od = __shfl_xor(rd, s);
      int oi = __shfl_xor(ridx, s);
      if (od < rd || (od == rd && oi < ridx)) { rd = od; ridx = oi; }
    }
    if (d == rd && idx == ridx) ptr++;
    if (t >= 1 && lane == 0) o[t - 1] = ridx;
  }
}

// ---------------- prep: weight transpose+convert (blocks 0..1919) + dir normalize (1920..1953) ----------------
__global__ __launch_bounds__(256) void prep_kernel(
    const float* __restrict__ w1, __hip_bfloat16* __restrict__ o1,
    const float* __restrict__ w2, __hip_bfloat16* __restrict__ o2,
    const float* __restrict__ w3, __hip_bfloat16* __restrict__ o3,
    const float* __restrict__ w4, __hip_bfloat16* __restrict__ o4,
    const float* __restrict__ s0, float* __restrict__ n0,
    const float* __restrict__ s1, float* __restrict__ n1,
    const float* __restrict__ s2, float* __restrict__ n2,
    const float* __restrict__ s3, float* __restrict__ n3,
    const float* __restrict__ s4, float* __restrict__ n4) {
  int bid = blockIdx.x;
  if (bid >= 1920) {
    // dirnorm tail: normalize direction matrices over the 3-dim axis
    int e = (bid - 1920) * 256 + threadIdx.x;
    const float* S; float* D; int W;
    if (e < 448)                          { S = s0; D = n0; W = 448; }
    else if (e < 448 + 896)               { e -= 448; S = s1; D = n1; W = 896; }
    else if (e < 448 + 896 + 1792)        { e -= 448 + 896; S = s2; D = n2; W = 1792; }
    else if (e < 448 + 896 + 3584)        { e -= 448 + 896 + 1792; S = s3; D = n3; W = 1792; }
    else if (e < 448 + 896 + 3584 + 3584) { e -= 448 + 896 + 3584; S = s4; D = n4; W = 3584; }
    else return;
    float a = S[e], b = S[W + e], c = S[2 * W + e];
    float nr = fmaxf(sqrtf(a * a + b * b + c * c), 1e-12f);
    D[e] = a / nr; D[W + e] = b / nr; D[2 * W + e] = c / nr;
    return;
  }
  __shared__ float tbuf[32][33];
  const float* W; __hip_bfloat16* O; int K, N;
  if (bid < 128)      { W = w1; O = o1; K = 128; N = 1024; }
  else if (bid < 384) { bid -= 128; W = w2; O = o2; K = 128; N = 2048; }
  else if (bid < 896) { bid -= 384; W = w3; O = o3; K = 256; N = 2048; }
  else                { bid -= 896; W = w4; O = o4; K = 256; N = 4096; }
  int tpr = N / 32;
  int tk = bid / tpr, tn = bid % tpr;
  int tx = threadIdx.x & 31, ty = threadIdx.x >> 5;  // (32, 8)
#pragma unroll
  for (int i = 0; i < 4; ++i)
    tbuf[ty + 8 * i][tx] = W[(size_t)(tk * 32 + ty + 8 * i) * N + tn * 32 + tx];
  __syncthreads();
#pragma unroll
  for (int i = 0; i < 4; ++i)
    O[(size_t)(tn * 32 + ty + 8 * i) * K + tk * 32 + tx] = __float2bfloat16(tbuf[tx][ty + 8 * i]);
}

// ---------------- fused fm0: conv_surface (ch 0..63) + bn(relu(rgb)) (ch 64..127) ----------------
__global__ __launch_bounds__(256) void fm0_kernel(const float* __restrict__ v, const int* __restrict__ idx,
                                                  const float* __restrict__ dir0n,
                                                  const float* __restrict__ rgb_f, const float* __restrict__ w,
                                                  const float* __restrict__ bias, const float* __restrict__ g,
                                                  const float* __restrict__ bb, const float* __restrict__ mm,
                                                  const float* __restrict__ vv,
                                                  float* __restrict__ fm0, __hip_bfloat16* __restrict__ fm0b) {
  __shared__ float dn[4][NB][3];
  int b = blockIdx.y;
  int n0 = blockIdx.x * 4;
  int tid = threadIdx.x;
  if (tid < 4 * NB) {
    int p = tid / NB, k = tid % NB;
    size_t row = (size_t)b * 2048 + (n0 + p);
    const float* c = v + row * 3;
    int nb = idx[row * NB + k];
    const float* q = v + ((size_t)b * 2048 + nb) * 3;
    float dx = q[0] - c[0], dy = q[1] - c[1], dz = q[2] - c[2];
    float nr = fmaxf(sqrtf(dx * dx + dy * dy + dz * dz), 1e-12f);
    dn[p][k][0] = dx / nr; dn[p][k][1] = dy / nr; dn[p][k][2] = dz / nr;
  }
  __syncthreads();
  int p = tid >> 6, c = tid & 63;
  int n = n0 + p;
  // surface half
  float acc = 0.f;
  for (int s = 0; s < 7; ++s) {
    int e = s * 64 + c;
    float d0 = dir0n[e], d1 = dir0n[448 + e], d2 = dir0n[896 + e];
    float mx = 0.f;
#pragma unroll
    for (int k = 0; k < NB; ++k) {
      float t = dn[p][k][0] * d0 + dn[p][k][1] * d1 + dn[p][k][2] * d2;
      mx = fmaxf(mx, fmaxf(t, 0.f));
    }
    acc += mx;
  }
  acc = fmaxf(acc, 0.f);
  // rgb half
  const float* f = rgb_f + (size_t)b * 32 * 2048;
  float a2 = bias[c];
  for (int cc = 0; cc < 32; ++cc) a2 += w[c * 32 + cc] * f[cc * 2048 + n];
  a2 = fmaxf(a2, 0.f);
  a2 = (a2 - mm[c]) / sqrtf(vv[c] + 1e-5f) * g[c] + bb[c];
  size_t o = ((size_t)b * 2048 + n) * 128;
  fm0[o + c] = acc;
  fm0[o + 64 + c] = a2;
  fm0b[o + c] = __float2bfloat16(acc);
  fm0b[o + 64 + c] = __float2bfloat16(a2);
}

// ---------------- bf16 MFMA GEMM: C = A @ BT^T + bias; writes fp32 C and/or bf16 Cb ----------------
__global__ __launch_bounds__(256) void mfma_gemm_kernel(const __hip_bfloat16* __restrict__ A,
                                                        const __hip_bfloat16* __restrict__ BT,
                                                        const float* __restrict__ bias,
                                                        float* __restrict__ C,
                                                        __hip_bfloat16* __restrict__ Cb,
                                                        int M, int K, int N) {
  __shared__ __hip_bfloat16 Al[128 * 32];
  __shared__ __hip_bfloat16 Bl[128 * 32];
  int t = threadIdx.x;
  int l = t & 63;
  int w = t >> 6;
  int wm = w >> 1, wn = w & 1;
  int m0 = blockIdx.y * 128, n0 = blockIdx.x * 128;
  f32x4 zero = {0.f, 0.f, 0.f, 0.f};
  f32x4 acc[4][4];
#pragma unroll
  for (int i = 0; i < 4; ++i)
#pragma unroll
    for (int j = 0; j < 4; ++j) acc[i][j] = zero;

  for (int kt = 0; kt < K; kt += 32) {
#pragma unroll
    for (int j = 0; j < 2; ++j) {
      int c = t + 256 * j;
      int r = c >> 2, o = c & 3;
      *(uint4*)&Al[r * 32 + o * 8] = *(const uint4*)&A[(size_t)(m0 + r) * K + kt + o * 8];
      *(uint4*)&Bl[r * 32 + o * 8] = *(const uint4*)&BT[(size_t)(n0 + r) * K + kt + o * 8];
    }
    __syncthreads();
    bf16x8 af[4], bfv[4];
#pragma unroll
    for (int f = 0; f < 4; ++f) {
      af[f]  = *(const bf16x8*)&Al[(wm * 64 + f * 16 + (l & 15)) * 32 + (l >> 4) * 8];
      bfv[f] = *(const bf16x8*)&Bl[(wn * 64 + f * 16 + (l & 15)) * 32 + (l >> 4) * 8];
    }
#pragma unroll
    for (int i = 0; i < 4; ++i)
#pragma unroll
      for (int j = 0; j < 4; ++j)
        acc[i][j] = __builtin_amdgcn_mfma_f32_16x16x32_bf16(af[i], bfv[j], acc[i][j], 0, 0, 0);
    __syncthreads();
  }
  int col_l = l & 15, rbase = (l >> 4) * 4;
#pragma unroll
  for (int i = 0; i < 4; ++i) {
#pragma unroll
    for (int j = 0; j < 4; ++j) {
      int col = n0 + wn * 64 + j * 16 + col_l;
      float bv = bias[col];
#pragma unroll
      for (int r = 0; r < 4; ++r) {
        int m = m0 + wm * 64 + i * 16 + rbase + r;
        float val = acc[i][j][r] + bv;
        if (C)  C[(size_t)m * N + col] = val;
        if (Cb) Cb[(size_t)m * N + col] = __float2bfloat16(val);
      }
    }
  }
}

// ---------------- conv_layer combine v2: wave-per-point, VEC channels/lane, fout dtype T ----------------
template <int VEC, typename T>
__global__ __launch_bounds__(256) void conv_combine2_kernel(
    const int* __restrict__ idx, const float* __restrict__ v,
    const T* __restrict__ fout, const float* __restrict__ dirn,
    const float* __restrict__ g, const float* __restrict__ bb,
    const float* __restrict__ mm, const float* __restrict__ vv,
    int use_bn_relu, float* __restrict__ outf, __hip_bfloat16* __restrict__ outb,
    int Np, int Cout) {
  __shared__ float dnS[4][NB][3];
  __shared__ int nbS[4][NB];
  int b = blockIdx.y;
  int tid = threadIdx.x;
  int w = tid >> 6, lane = tid & 63;
  if (tid < 4 * NB) {
    int p = tid / NB, k = tid - p * NB;
    size_t prow = (size_t)b * Np + blockIdx.x * 4 + p;
    int nb = idx[prow * NB + k];
    const float* cpt = v + prow * 3;
    const float* q = v + ((size_t)b * Np + nb) * 3;
    float dx = q[0] - cpt[0], dy = q[1] - cpt[1], dz = q[2] - cpt[2];
    float nr = fmaxf(sqrtf(dx * dx + dy * dy + dz * dz), 1e-12f);
    dnS[p][k][0] = dx / nr; dnS[p][k][1] = dy / nr; dnS[p][k][2] = dz / nr;
    nbS[p][k] = b * Np + nb;
  }
  __syncthreads();
  int n = blockIdx.x * 4 + w;
  size_t row = (size_t)b * Np + n;
  float dn0[NB], dn1[NB], dn2[NB]; int nbr[NB];
#pragma unroll
  for (int k = 0; k < NB; ++k) {
    dn0[k] = dnS[w][k][0]; dn1[k] = dnS[w][k][1]; dn2[k] = dnS[w][k][2];
    nbr[k] = nbS[w][k];
  }
  int F = 8 * Cout, W7 = 7 * Cout;
  int c0 = lane * VEC;
  float acc[VEC];
#pragma unroll
  for (int u = 0; u < VEC; ++u) acc[u] = toF(fout[row * (size_t)F + c0 + u]);  // center
  for (int s = 0; s < 7; ++s) {
    int e0 = s * Cout + c0;
    float d0[VEC], d1[VEC], d2[VEC], mx[VEC];
#pragma unroll
    for (int u = 0; u < VEC; ++u) {
      d0[u] = dirn[e0 + u]; d1[u] = dirn[W7 + e0 + u]; d2[u] = dirn[2 * W7 + e0 + u];
      mx[u] = -3.4e38f;
    }
#pragma unroll
    for (int k = 0; k < NB; ++k) {
      const T* sp = &fout[(size_t)nbr[k] * F + Cout + e0];
      float sv[VEC];
#pragma unroll
      for (int u = 0; u < VEC; ++u) sv[u] = toF(sp[u]);
#pragma unroll
      for (int u = 0; u < VEC; ++u) {
        float t = fmaxf(dn0[k] * d0[u] + dn1[k] * d1[u] + dn2[k] * d2[u], 0.f);
        mx[u] = fmaxf(mx[u], t * sv[u]);
      }
    }
#pragma unroll
    for (int u = 0; u < VEC; ++u) acc[u] += mx[u];
  }
#pragma unroll
  for (int u = 0; u < VEC; ++u) {
    float a = acc[u];
    if (use_bn_relu) {
      int c = c0 + u;
      a = (a - mm[c]) / sqrtf(vv[c] + 1e-5f) * g[c] + bb[c];
      a = fmaxf(a, 0.f);
    }
    acc[u] = a;
  }
#pragma unroll
  for (int u = 0; u < VEC; ++u) outf[row * (size_t)Cout + c0 + u] = acc[u];
  if (outb) {
#pragma unroll
    for (int u = 0; u < VEC; ++u) outb[row * (size_t)Cout + c0 + u] = __float2bfloat16(acc[u]);
  }
}

// ---------------- pool: max over first-4 neighbors at sampled rows ----------------
__global__ void pool_kernel(const float* __restrict__ v, const float* __restrict__ fm,
                            const int* __restrict__ idx10, const int* __restrict__ samp,
                            float* __restrict__ v_out, float* __restrict__ f_out,
                            __hip_bfloat16* __restrict__ f_out_b, int Nin, int C) {
  int b = blockIdx.y, mi = blockIdx.x, c = threadIdx.x;
  int n = samp[mi];
  size_t row = (size_t)b * Nin + n;
  float mx = -3.4e38f;
#pragma unroll
  for (int j = 0; j < 4; ++j) {
    int nb = idx10[row * NB + j];
    mx = fmaxf(mx, fm[((size_t)b * Nin + nb) * C + c]);
  }
  int Mout = gridDim.x;
  f_out[((size_t)b * Mout + mi) * C + c] = mx;
  f_out_b[((size_t)b * Mout + mi) * C + c] = __float2bfloat16(mx);
  if (c < 3) v_out[((size_t)b * Mout + mi) * 3 + c] = v[row * 3 + c];
}

// ---------------- nearest-source indices (z=0: v1, z=1: v2) + global max of fm4 (z=2) ----------------
__global__ void nearest2_kernel(const float* __restrict__ tgt, const float* __restrict__ v1,
                                const float* __restrict__ v2, const float* __restrict__ fm4,
                                int* __restrict__ ni1, int* __restrict__ ni2,
                                float* __restrict__ fg) {
  __shared__ float4 sp[512];
  int z = blockIdx.z;
  int b = blockIdx.y;
  if (z == 2) {
    // global max over 128 points of fm4 -> fg[b][512]; 2 x-blocks of 256 thr cover 512 ch
    if (blockIdx.x >= 2) return;
    int c = blockIdx.x * 256 + threadIdx.x;
    float mx = -3.4e38f;
    for (int p = 0; p < 128; ++p) mx = fmaxf(mx, fm4[((size_t)b * 128 + p) * 512 + c]);
    fg[b * 512 + c] = mx;
    return;
  }
  const float* src = z ? v2 : v1;
  int S = z ? 128 : 512;
  int* out = z ? ni2 : ni1;
  for (int i = threadIdx.x; i < S; i += blockDim.x) {
    const float* q = src + ((size_t)b * S + i) * 3;
    float x = q[0], y = q[1], zz = q[2];
    sp[i] = make_float4(x, y, zz, x * x + y * y + zz * zz);
  }
  __syncthreads();
  int n = blockIdx.x * blockDim.x + threadIdx.x;
  const float* t = tgt + ((size_t)b * 2048 + n) * 3;
  float x = t[0], y = t[1], zz = t[2];
  float sqt = x * x + y * y + zz * zz;
  float best = 3.4e38f; int bi = 0;
  for (int s = 0; s < S; ++s) {
    float4 q = sp[s];
    float d = q.w + sqt - 2.f * (x * q.x + y * q.y + zz * q.z);
    if (d < best) { best = d; bi = s; }
  }
  out[(size_t)b * 2048 + n] = bi;
}

// ---------------- output v2: 64n x 32cc LDS-tiled transpose, coalesced both ways ----------------
__global__ __launch_bounds__(256) void output2_kernel(
    const float* __restrict__ fm0, const float* __restrict__ fm1,
    const float* __restrict__ fm2, const float* __restrict__ fm3,
    const float* __restrict__ fm4, const float* __restrict__ fg,
    const int* __restrict__ ni1, const int* __restrict__ ni2,
    float* __restrict__ out) {
  __shared__ float tile[64][33];
  __shared__ int srow[64];
  int b = blockIdx.z;
  int cc0 = blockIdx.y * 32;
  int n0 = blockIdx.x * 64;
  int tid = threadIdx.x;
  const float* P; int Cs, coff, mode;
  if (cc0 < 128)       { P = fm0; Cs = 128; coff = cc0;        mode = 0; }
  else if (cc0 < 256)  { P = fm1; Cs = 128; coff = cc0 - 128;  mode = 0; }
  else if (cc0 < 512)  { P = fm2; Cs = 256; coff = cc0 - 256;  mode = 1; }
  else if (cc0 < 768)  { P = fm3; Cs = 256; coff = cc0 - 512;  mode = 1; }
  else if (cc0 < 1280) { P = fm4; Cs = 512; coff = cc0 - 768;  mode = 2; }
  else                 { P = fg;  Cs = 512; coff = cc0 - 1280; mode = 3; }
  if (tid < 64) {
    int n = n0 + tid;
    size_t r2 = (size_t)b * 2048 + n;
    int sr;
    if (mode == 0)      sr = b * 2048 + n;
    else if (mode == 1) sr = b * 512 + ni1[r2];
    else if (mode == 2) sr = b * 128 + ni2[r2];
    else                sr = b;
    srow[tid] = sr;
  }
  __syncthreads();
  int tx = tid & 31, ty = tid >> 5;  // 32 x 8
#pragma unroll
  for (int r = 0; r < 8; ++r) {
    int nl = ty + 8 * r;
    tile[nl][tx] = P[(size_t)srow[nl] * Cs + coff + tx];
  }
  __syncthreads();
  int lx = tid & 63, ly = tid >> 6;  // 64 x 4
  float* out0 = out;                              // (4,1280,2048)
  float* out1 = out + (size_t)4 * 1280 * 2048;    // (4,1792,2048)
#pragma unroll
  for (int ci = 0; ci < 8; ++ci) {
    int cl = ly + 4 * ci;
    int cc = cc0 + cl;
    float vv = tile[lx][cl];
    out1[((size_t)b * 1792 + cc) * 2048 + n0 + lx] = vv;
    if (cc < 1280) out0[((size_t)b * 1280 + cc) * 2048 + n0 + lx] = vv;
  }
}

extern "C" void kernel_launch(void* const* d_in, const int* in_sizes, int n_in,
                              void* d_out, int out_size, void* d_ws, size_t ws_size,
                              hipStream_t stream) {
  (void)in_sizes; (void)n_in; (void)out_size; (void)ws_size;
  const float* vertices = (const float*)d_in[0];
  const float* rgb_f    = (const float*)d_in[1];
  const float* dir0     = (const float*)d_in[2];
  const float* w1 = (const float*)d_in[3],  *b1 = (const float*)d_in[4],  *d1 = (const float*)d_in[5];
  const float* w2 = (const float*)d_in[6],  *b2 = (const float*)d_in[7],  *d2 = (const float*)d_in[8];
  const float* w3 = (const float*)d_in[9],  *b3 = (const float*)d_in[10], *d3 = (const float*)d_in[11];
  const float* w4 = (const float*)d_in[12], *b4 = (const float*)d_in[13], *d4 = (const float*)d_in[14];
  const float* rgb_w = (const float*)d_in[15], *rgb_b = (const float*)d_in[16];
  const float* rbn_g = (const float*)d_in[17], *rbn_b = (const float*)d_in[18];
  const float* rbn_m = (const float*)d_in[19], *rbn_v = (const float*)d_in[20];
  const float* bn1_g = (const float*)d_in[21], *bn1_b = (const float*)d_in[22];
  const float* bn1_m = (const float*)d_in[23], *bn1_v = (const float*)d_in[24];
  const float* bn2_g = (const float*)d_in[25], *bn2_b = (const float*)d_in[26];
  const float* bn2_m = (const float*)d_in[27], *bn2_v = (const float*)d_in[28];
  const float* bn3_g = (const float*)d_in[29], *bn3_b = (const float*)d_in[30];
  const float* bn3_m = (const float*)d_in[31], *bn3_v = (const float*)d_in[32];
  float* out = (float*)d_out;

  char* ws = (char*)d_ws;
  size_t off = 0;
  auto alloc = [&](size_t bytes) -> void* {
    void* p = ws + off;
    off += (bytes + 255) & ~(size_t)255;
    return p;
  };
  int*   samp1 = (int*)alloc(512 * 4);
  int*   samp2 = (int*)alloc(128 * 4);
  int*   idx0  = (int*)alloc((size_t)4 * 2048 * NB * 4);
  int*   idx1  = (int*)alloc((size_t)4 * 512 * NB * 4);
  int*   idx2  = (int*)alloc((size_t)4 * 128 * NB * 4);
  float* fm0   = (float*)alloc((size_t)4 * 2048 * 128 * 4);
  float* fm1   = (float*)alloc((size_t)4 * 2048 * 128 * 4);
  float* fout  = (float*)alloc((size_t)4 * 2048 * 1024 * 4);   // fp32 fout (layer 4 only)
  __hip_bfloat16* foutb = (__hip_bfloat16*)alloc((size_t)4 * 2048 * 1024 * 2);  // bf16 fout (layers 1-3)
  float* v1    = (float*)alloc((size_t)4 * 512 * 3 * 4);
  float* fp1   = (float*)alloc((size_t)4 * 512 * 128 * 4);
  float* fm2   = (float*)alloc((size_t)4 * 512 * 256 * 4);
  float* fm3   = (float*)alloc((size_t)4 * 512 * 256 * 4);
  float* v2    = (float*)alloc((size_t)4 * 128 * 3 * 4);
  float* fp2   = (float*)alloc((size_t)4 * 128 * 256 * 4);
  float* fm4   = (float*)alloc((size_t)4 * 128 * 512 * 4);
  float* fg    = (float*)alloc((size_t)4 * 512 * 4);
  int*   ni1   = (int*)alloc((size_t)4 * 2048 * 4);
  int*   ni2   = (int*)alloc((size_t)4 * 2048 * 4);
  // bf16 matmul operands
  __hip_bfloat16* fm0b = (__hip_bfloat16*)alloc((size_t)4 * 2048 * 128 * 2);
  __hip_bfloat16* fp1b = (__hip_bfloat16*)alloc((size_t)4 * 512 * 128 * 2);
  __hip_bfloat16* fm2b = (__hip_bfloat16*)alloc((size_t)4 * 512 * 256 * 2);
  __hip_bfloat16* fp2b = (__hip_bfloat16*)alloc((size_t)4 * 128 * 256 * 2);
  __hip_bfloat16* wt1  = (__hip_bfloat16*)alloc((size_t)1024 * 128 * 2);
  __hip_bfloat16* wt2  = (__hip_bfloat16*)alloc((size_t)2048 * 128 * 2);
  __hip_bfloat16* wt3  = (__hip_bfloat16*)alloc((size_t)2048 * 256 * 2);
  __hip_bfloat16* wt4  = (__hip_bfloat16*)alloc((size_t)4096 * 256 * 2);
  // normalized directions
  float* d0n = (float*)alloc((size_t)3 * 448 * 4);
  float* d1n = (float*)alloc((size_t)3 * 896 * 4);
  float* d2n = (float*)alloc((size_t)3 * 1792 * 4);
  float* d3n = (float*)alloc((size_t)3 * 1792 * 4);
  float* d4n = (float*)alloc((size_t)3 * 3584 * 4);

  // one-shot prep: weight transpose+convert + dir normalize (one kernel), permutations
  prep_kernel<<<1954, 256, 0, stream>>>(w1, wt1, w2, wt2, w3, wt3, w4, wt4,
                                        dir0, d0n, d1, d1n, d2, d2n, d3, d3n, d4, d4n);
  perm2_kernel<<<2, 1024, 0, stream>>>(samp1, samp2);

  // level-0 kNN (wave-per-query)
  knn_wave_kernel<<<dim3(2048 / 4, 4), 256, 0, stream>>>(vertices, 2048, idx0);

  // fm0 = [conv_surface(64ch) | bn(relu(rgb))(64ch)]  (fused)
  fm0_kernel<<<dim3(512, 4), 256, 0, stream>>>(vertices, idx0, d0n, rgb_f, rgb_w, rgb_b,
                                               rbn_g, rbn_b, rbn_m, rbn_v, fm0, fm0b);

  // layer 1 (fout in bf16)
  mfma_gemm_kernel<<<dim3(1024 / 128, 8192 / 128), 256, 0, stream>>>(fm0b, wt1, b1, nullptr, foutb, 8192, 128, 1024);
  conv_combine2_kernel<2, __hip_bfloat16><<<dim3(512, 4), 256, 0, stream>>>(idx0, vertices, foutb, d1n,
      bn1_g, bn1_b, bn1_m, bn1_v, 1, fm1, nullptr, 2048, 128);

  // pool 1 -> v1, fp1(+bf16) ; level-1 kNN
  pool_kernel<<<dim3(512, 4), 128, 0, stream>>>(vertices, fm1, idx0, samp1, v1, fp1, fp1b, 2048, 128);
  knn_wave_kernel<<<dim3(512 / 4, 4), 256, 0, stream>>>(v1, 512, idx1);

  // layer 2 (fout bf16; emit fm2 bf16 for layer-3 A)
  mfma_gemm_kernel<<<dim3(2048 / 128, 2048 / 128), 256, 0, stream>>>(fp1b, wt2, b2, nullptr, foutb, 2048, 128, 2048);
  conv_combine2_kernel<4, __hip_bfloat16><<<dim3(128, 4), 256, 0, stream>>>(idx1, v1, foutb, d2n,
      bn2_g, bn2_b, bn2_m, bn2_v, 1, fm2, fm2b, 512, 256);
  // layer 3 (fout bf16)
  mfma_gemm_kernel<<<dim3(2048 / 128, 2048 / 128), 256, 0, stream>>>(fm2b, wt3, b3, nullptr, foutb, 2048, 256, 2048);
  conv_combine2_kernel<4, __hip_bfloat16><<<dim3(128, 4), 256, 0, stream>>>(idx1, v1, foutb, d3n,
      bn3_g, bn3_b, bn3_m, bn3_v, 1, fm3, nullptr, 512, 256);

  // pool 2 -> v2, fp2(+bf16) ; level-2 kNN
  pool_kernel<<<dim3(128, 4), 256, 0, stream>>>(v1, fm3, idx1, samp2, v2, fp2, fp2b, 512, 256);
  knn_wave_kernel<<<dim3(128 / 4, 4), 256, 0, stream>>>(v2, 128, idx2);

  // layer 4 (fout fp32 — final layer feeds fm4 directly, keep precision)
  mfma_gemm_kernel<<<dim3(4096 / 128, 512 / 128), 256, 0, stream>>>(fp2b, wt4, b4, fout, nullptr, 512, 256, 4096);
  conv_combine2_kernel<8, float><<<dim3(32, 4), 256, 0, stream>>>(idx2, v2, fout, d4n,
      nullptr, nullptr, nullptr, nullptr, 0, fm4, nullptr, 128, 512);

  // upsample indices + global max (one kernel: z=0 -> ni1, z=1 -> ni2, z=2 -> fg)
  nearest2_kernel<<<dim3(8, 4, 3), 256, 0, stream>>>(vertices, v1, v2, fm4, ni1, ni2, fg);

  // outputs (LDS-tiled transpose)
  output2_kernel<<<dim3(32, 56, 4), 256, 0, stream>>>(fm0, fm1, fm2, fm3, fm4, fg, ni1, ni2, out);
}

// Round 8
// 297.096 us; speedup vs baseline: 4.8006x; 1.1344x over previous
//
#include <hip/hip_runtime.h>
#include <hip/hip_bf16.h>
#include <math.h>

#define NB 10
#define KNN_K 11

typedef __attribute__((ext_vector_type(8))) short bf16x8;
typedef __attribute__((ext_vector_type(4))) float f32x4;

__device__ __forceinline__ float toF(float x) { return x; }
__device__ __forceinline__ float toF(__hip_bfloat16 x) { return __bfloat162float(x); }

// ---------------- Threefry-2x32-20 (JAX) ----------------
__device__ __forceinline__ void tf2x32(unsigned k0, unsigned k1, unsigned& x0, unsigned& x1) {
  unsigned ks0 = k0, ks1 = k1, ks2 = k0 ^ k1 ^ 0x1BD11BDAu;
  x0 += ks0; x1 += ks1;
#define TF_R(r) { x0 += x1; x1 = (x1 << (r)) | (x1 >> (32 - (r))); x1 ^= x0; }
  TF_R(13) TF_R(15) TF_R(26) TF_R(6)  x0 += ks1; x1 += ks2 + 1u;
  TF_R(17) TF_R(29) TF_R(16) TF_R(24) x0 += ks2; x1 += ks0 + 2u;
  TF_R(13) TF_R(15) TF_R(26) TF_R(6)  x0 += ks0; x1 += ks1 + 3u;
  TF_R(17) TF_R(29) TF_R(16) TF_R(24) x0 += ks1; x1 += ks2 + 4u;
  TF_R(13) TF_R(15) TF_R(26) TF_R(6)  x0 += ks2; x1 += ks0 + 5u;
#undef TF_R
}

__device__ __forceinline__ unsigned long long shfl_xor_u64(unsigned long long v, int m) {
  unsigned lo = (unsigned)v, hi = (unsigned)(v >> 32);
  lo = (unsigned)__shfl_xor((int)lo, m);
  hi = (unsigned)__shfl_xor((int)hi, m);
  return ((unsigned long long)hi << 32) | lo;
}

// Both jax.random.permutation replications in one kernel, one block each.
__global__ __launch_bounds__(1024) void perm2_kernel(int* __restrict__ samp1,
                                                     int* __restrict__ samp2) {
  __shared__ unsigned long long buf[2][2048];
  __shared__ unsigned perm[2][2048];
  int which = blockIdx.x;
  int n = (which == 0) ? 2048 : 512;
  int m = (which == 0) ? 512 : 128;
  int R = (which == 0) ? 2 : 1;
  unsigned k0 = 0u, k1 = (which == 0) ? 1u : 2u;
  int* out = (which == 0) ? samp1 : samp2;
  int T = n >> 1;
  int t = threadIdx.x;
  bool act = (t < T);  // T is a multiple of 64 -> wave-uniform
  int pb = 0;
  unsigned valA = 0, valB = 0;
  int lb = 0;
  for (int r = 0; r < R; ++r) {
    unsigned a0 = 0u, a1 = 0u, s0 = 0u, s1 = 1u;
    tf2x32(k0, k1, a0, a1);
    tf2x32(k0, k1, s0, s1);
    unsigned long long kA = 0, kB = 0;
    if (act) {
      unsigned y0 = 0u, y1 = (unsigned)t;
      tf2x32(s0, s1, y0, y1);
      kA = ((unsigned long long)(y0 ^ y1) << 32) | (unsigned)t;
      y0 = 0u; y1 = (unsigned)(t + T);
      tf2x32(s0, s1, y0, y1);
      kB = ((unsigned long long)(y0 ^ y1) << 32) | (unsigned)(t + T);
    }
    for (int kk = 2; kk <= n; kk <<= 1) {
      for (int j = kk >> 1; j > 0; j >>= 1) {
        if (j == T) {
          if (act) {
            unsigned long long lo = (kA < kB) ? kA : kB;
            unsigned long long hi = (kA < kB) ? kB : kA;
            kA = lo; kB = hi;
          }
        } else if (j >= 64) {
          if (act) { buf[lb][t] = kA; buf[lb][t + T] = kB; }
          __syncthreads();
          if (act) {
            unsigned long long okA = buf[lb][t ^ j];
            unsigned long long okB = buf[lb][(t ^ j) + T];
            bool lower = ((t & j) == 0);
            bool upA = ((t & kk) == 0);
            bool upB = (((t + T) & kk) == 0);
            kA = (upA == lower) ? (kA < okA ? kA : okA) : (kA < okA ? okA : kA);
            kB = (upB == lower) ? (kB < okB ? kB : okB) : (kB < okB ? okB : kB);
          }
          lb ^= 1;
        } else {
          unsigned long long okA = shfl_xor_u64(kA, j);
          unsigned long long okB = shfl_xor_u64(kB, j);
          if (act) {
            bool lower = ((t & j) == 0);
            bool upA = ((t & kk) == 0);
            bool upB = (((t + T) & kk) == 0);
            kA = (upA == lower) ? (kA < okA ? kA : okA) : (kA < okA ? okA : kA);
            kB = (upB == lower) ? (kB < okB ? kB : okB) : (kB < okB ? okB : kB);
          }
        }
      }
    }
    if (act) {
      unsigned posA = (unsigned)(kA & 0xffffffffu);
      unsigned posB = (unsigned)(kB & 0xffffffffu);
      if (r == 0) { valA = posA; valB = posB; }
      else        { valA = perm[pb][posA]; valB = perm[pb][posB]; }
    }
    if (r + 1 < R) {
      __syncthreads();
      if (act) { perm[pb ^ 1][t] = valA; perm[pb ^ 1][t + T] = valB; }
      pb ^= 1;
      __syncthreads();
    }
    k0 = a0; k1 = a1;
  }
  if (t < m) out[t] = (int)valA;
}

// ---------------- kNN: wave-per-query top-11, drop slot 0 (blockDim-flexible) ----------------
__global__ __launch_bounds__(1024) void knn_wave_kernel(const float* __restrict__ v, int N,
                                                        int* __restrict__ out) {
  __shared__ float4 pts[2048];
  int b = blockIdx.y;
  const float* vb = v + (size_t)b * N * 3;
  for (int i = threadIdx.x; i < N; i += blockDim.x) {
    float x = vb[i * 3], y = vb[i * 3 + 1], z = vb[i * 3 + 2];
    pts[i] = make_float4(x, y, z, x * x + y * y + z * z);
  }
  __syncthreads();
  int qpb = blockDim.x >> 6;
  int wave = threadIdx.x >> 6;
  int lane = threadIdx.x & 63;
  int qi = blockIdx.x * qpb + wave;  // grid sized so qi < N always
  float4 p = pts[qi];
  float bd[KNN_K]; int bi[KNN_K];
#pragma unroll
  for (int t = 0; t < KNN_K; ++t) { bd[t] = 3.4e38f; bi[t] = 0x7fffffff; }
  for (int j = lane; j < N; j += 64) {
    float4 q = pts[j];
    float dot = p.x * q.x + p.y * q.y + p.z * q.z;
    float d = p.w + q.w - 2.0f * dot;
    if (d < bd[KNN_K - 1]) {
      float cd = d; int ci = j;
#pragma unroll
      for (int t = 0; t < KNN_K; ++t) {
        bool sw = cd < bd[t];
        float td = bd[t]; int ti = bi[t];
        bd[t] = sw ? cd : td; bi[t] = sw ? ci : ti;
        cd = sw ? td : cd;   ci = sw ? ti : ci;
      }
    }
  }
  int ptr = 0;
  int* o = out + ((size_t)b * N + qi) * NB;
#pragma unroll 1
  for (int t = 0; t < KNN_K; ++t) {
    float d = (ptr < KNN_K) ? bd[ptr] : 3.4e38f;
    int idx = (ptr < KNN_K) ? bi[ptr] : 0x7fffffff;
    float rd = d; int ridx = idx;
#pragma unroll
    for (int s = 32; s > 0; s >>= 1) {
      float od = __shfl_xor(rd, s);
      int oi = __shfl_xor(ridx, s);
      if (od < rd || (od == rd && oi < ridx)) { rd = od; ridx = oi; }
    }
    if (d == rd && idx == ridx) ptr++;
    if (t >= 1 && lane == 0) o[t - 1] = ridx;
  }
}

// ---------------- prep: weight transpose+convert (blocks 0..1919) + dir normalize (1920..1953) ----------------
__global__ __launch_bounds__(256) void prep_kernel(
    const float* __restrict__ w1, __hip_bfloat16* __restrict__ o1,
    const float* __restrict__ w2, __hip_bfloat16* __restrict__ o2,
    const float* __restrict__ w3, __hip_bfloat16* __restrict__ o3,
    const float* __restrict__ w4, __hip_bfloat16* __restrict__ o4,
    const float* __restrict__ s0, float* __restrict__ n0,
    const float* __restrict__ s1, float* __restrict__ n1,
    const float* __restrict__ s2, float* __restrict__ n2,
    const float* __restrict__ s3, float* __restrict__ n3,
    const float* __restrict__ s4, float* __restrict__ n4) {
  int bid = blockIdx.x;
  if (bid >= 1920) {
    int e = (bid - 1920) * 256 + threadIdx.x;
    const float* S; float* D; int W;
    if (e < 448)                          { S = s0; D = n0; W = 448; }
    else if (e < 448 + 896)               { e -= 448; S = s1; D = n1; W = 896; }
    else if (e < 448 + 896 + 1792)        { e -= 448 + 896; S = s2; D = n2; W = 1792; }
    else if (e < 448 + 896 + 3584)        { e -= 448 + 896 + 1792; S = s3; D = n3; W = 1792; }
    else if (e < 448 + 896 + 3584 + 3584) { e -= 448 + 896 + 3584; S = s4; D = n4; W = 3584; }
    else return;
    float a = S[e], b = S[W + e], c = S[2 * W + e];
    float nr = fmaxf(sqrtf(a * a + b * b + c * c), 1e-12f);
    D[e] = a / nr; D[W + e] = b / nr; D[2 * W + e] = c / nr;
    return;
  }
  __shared__ float tbuf[32][33];
  const float* W; __hip_bfloat16* O; int K, N;
  if (bid < 128)      { W = w1; O = o1; K = 128; N = 1024; }
  else if (bid < 384) { bid -= 128; W = w2; O = o2; K = 128; N = 2048; }
  else if (bid < 896) { bid -= 384; W = w3; O = o3; K = 256; N = 2048; }
  else                { bid -= 896; W = w4; O = o4; K = 256; N = 4096; }
  int tpr = N / 32;
  int tk = bid / tpr, tn = bid % tpr;
  int tx = threadIdx.x & 31, ty = threadIdx.x >> 5;  // (32, 8)
#pragma unroll
  for (int i = 0; i < 4; ++i)
    tbuf[ty + 8 * i][tx] = W[(size_t)(tk * 32 + ty + 8 * i) * N + tn * 32 + tx];
  __syncthreads();
#pragma unroll
  for (int i = 0; i < 4; ++i)
    O[(size_t)(tn * 32 + ty + 8 * i) * K + tk * 32 + tx] = __float2bfloat16(tbuf[tx][ty + 8 * i]);
}

// ---------------- fused fm0: conv_surface (ch 0..63) + bn(relu(rgb)) (ch 64..127) ----------------
__global__ __launch_bounds__(256) void fm0_kernel(const float* __restrict__ v, const int* __restrict__ idx,
                                                  const float* __restrict__ dir0n,
                                                  const float* __restrict__ rgb_f, const float* __restrict__ w,
                                                  const float* __restrict__ bias, const float* __restrict__ g,
                                                  const float* __restrict__ bb, const float* __restrict__ mm,
                                                  const float* __restrict__ vv,
                                                  float* __restrict__ fm0, __hip_bfloat16* __restrict__ fm0b) {
  __shared__ float dn[4][NB][3];
  int b = blockIdx.y;
  int n0 = blockIdx.x * 4;
  int tid = threadIdx.x;
  if (tid < 4 * NB) {
    int p = tid / NB, k = tid % NB;
    size_t row = (size_t)b * 2048 + (n0 + p);
    const float* c = v + row * 3;
    int nb = idx[row * NB + k];
    const float* q = v + ((size_t)b * 2048 + nb) * 3;
    float dx = q[0] - c[0], dy = q[1] - c[1], dz = q[2] - c[2];
    float nr = fmaxf(sqrtf(dx * dx + dy * dy + dz * dz), 1e-12f);
    dn[p][k][0] = dx / nr; dn[p][k][1] = dy / nr; dn[p][k][2] = dz / nr;
  }
  __syncthreads();
  int p = tid >> 6, c = tid & 63;
  int n = n0 + p;
  float acc = 0.f;
  for (int s = 0; s < 7; ++s) {
    int e = s * 64 + c;
    float d0 = dir0n[e], d1 = dir0n[448 + e], d2 = dir0n[896 + e];
    float mx = 0.f;
#pragma unroll
    for (int k = 0; k < NB; ++k) {
      float t = dn[p][k][0] * d0 + dn[p][k][1] * d1 + dn[p][k][2] * d2;
      mx = fmaxf(mx, fmaxf(t, 0.f));
    }
    acc += mx;
  }
  acc = fmaxf(acc, 0.f);
  const float* f = rgb_f + (size_t)b * 32 * 2048;
  float a2 = bias[c];
  for (int cc = 0; cc < 32; ++cc) a2 += w[c * 32 + cc] * f[cc * 2048 + n];
  a2 = fmaxf(a2, 0.f);
  a2 = (a2 - mm[c]) / sqrtf(vv[c] + 1e-5f) * g[c] + bb[c];
  size_t o = ((size_t)b * 2048 + n) * 128;
  fm0[o + c] = acc;
  fm0[o + 64 + c] = a2;
  fm0b[o + c] = __float2bfloat16(acc);
  fm0b[o + 64 + c] = __float2bfloat16(a2);
}

// ---------------- bf16 MFMA GEMM: C = A @ BT^T + bias; writes fp32 C and/or bf16 Cb ----------------
__global__ __launch_bounds__(256) void mfma_gemm_kernel(const __hip_bfloat16* __restrict__ A,
                                                        const __hip_bfloat16* __restrict__ BT,
                                                        const float* __restrict__ bias,
                                                        float* __restrict__ C,
                                                        __hip_bfloat16* __restrict__ Cb,
                                                        int M, int K, int N) {
  __shared__ __hip_bfloat16 Al[128 * 32];
  __shared__ __hip_bfloat16 Bl[128 * 32];
  int t = threadIdx.x;
  int l = t & 63;
  int w = t >> 6;
  int wm = w >> 1, wn = w & 1;
  int m0 = blockIdx.y * 128, n0 = blockIdx.x * 128;
  f32x4 zero = {0.f, 0.f, 0.f, 0.f};
  f32x4 acc[4][4];
#pragma unroll
  for (int i = 0; i < 4; ++i)
#pragma unroll
    for (int j = 0; j < 4; ++j) acc[i][j] = zero;

  for (int kt = 0; kt < K; kt += 32) {
#pragma unroll
    for (int j = 0; j < 2; ++j) {
      int c = t + 256 * j;
      int r = c >> 2, o = c & 3;
      *(uint4*)&Al[r * 32 + o * 8] = *(const uint4*)&A[(size_t)(m0 + r) * K + kt + o * 8];
      *(uint4*)&Bl[r * 32 + o * 8] = *(const uint4*)&BT[(size_t)(n0 + r) * K + kt + o * 8];
    }
    __syncthreads();
    bf16x8 af[4], bfv[4];
#pragma unroll
    for (int f = 0; f < 4; ++f) {
      af[f]  = *(const bf16x8*)&Al[(wm * 64 + f * 16 + (l & 15)) * 32 + (l >> 4) * 8];
      bfv[f] = *(const bf16x8*)&Bl[(wn * 64 + f * 16 + (l & 15)) * 32 + (l >> 4) * 8];
    }
#pragma unroll
    for (int i = 0; i < 4; ++i)
#pragma unroll
      for (int j = 0; j < 4; ++j)
        acc[i][j] = __builtin_amdgcn_mfma_f32_16x16x32_bf16(af[i], bfv[j], acc[i][j], 0, 0, 0);
    __syncthreads();
  }
  int col_l = l & 15, rbase = (l >> 4) * 4;
#pragma unroll
  for (int i = 0; i < 4; ++i) {
#pragma unroll
    for (int j = 0; j < 4; ++j) {
      int col = n0 + wn * 64 + j * 16 + col_l;
      float bv = bias[col];
#pragma unroll
      for (int r = 0; r < 4; ++r) {
        int m = m0 + wm * 64 + i * 16 + rbase + r;
        float val = acc[i][j][r] + bv;
        if (C)  C[(size_t)m * N + col] = val;
        if (Cb) Cb[(size_t)m * N + col] = __float2bfloat16(val);
      }
    }
  }
}

// ---------------- conv_layer combine v3: thread = (point, channel) — max occupancy ----------------
// grid.x = Np*Cout/256; a block covers 256 contiguous channel-slots (1-2 points).
template <typename T>
__global__ __launch_bounds__(256) void conv_combine3_kernel(
    const int* __restrict__ idx, const float* __restrict__ v,
    const T* __restrict__ fout, const float* __restrict__ dirn,
    const float* __restrict__ g, const float* __restrict__ bb,
    const float* __restrict__ mm, const float* __restrict__ vv,
    int use_bn_relu, float* __restrict__ outf, __hip_bfloat16* __restrict__ outb,
    int Np, int Cout) {
  __shared__ float dnS[2][NB][3];
  __shared__ int nbS[2][NB];
  int b = blockIdx.y;
  int tid = threadIdx.x;
  int base = blockIdx.x * 256;
  int p0 = base / Cout;
  int nPts = (Cout < 256) ? 2 : 1;
  if (tid < nPts * NB) {
    int p = tid / NB, k = tid - p * NB;
    size_t prow = (size_t)b * Np + p0 + p;
    int nb = idx[prow * NB + k];
    const float* cpt = v + prow * 3;
    const float* q = v + ((size_t)b * Np + nb) * 3;
    float dx = q[0] - cpt[0], dy = q[1] - cpt[1], dz = q[2] - cpt[2];
    float nr = fmaxf(sqrtf(dx * dx + dy * dy + dz * dz), 1e-12f);
    dnS[p][k][0] = dx / nr; dnS[p][k][1] = dy / nr; dnS[p][k][2] = dz / nr;
    nbS[p][k] = b * Np + nb;
  }
  __syncthreads();
  int gid = base + tid;
  int n = gid / Cout, c = gid - n * Cout;
  int lp = n - p0;
  size_t row = (size_t)b * Np + n;
  float dn0[NB], dn1[NB], dn2[NB]; int nbr[NB];
#pragma unroll
  for (int k = 0; k < NB; ++k) {
    dn0[k] = dnS[lp][k][0]; dn1[k] = dnS[lp][k][1]; dn2[k] = dnS[lp][k][2];
    nbr[k] = nbS[lp][k];
  }
  int F = 8 * Cout, W7 = 7 * Cout;
  float acc = toF(fout[row * (size_t)F + c]);  // center
  for (int s = 0; s < 7; ++s) {
    int e = s * Cout + c;
    float d0 = dirn[e], d1 = dirn[W7 + e], d2 = dirn[2 * W7 + e];
    float mx = -3.4e38f;
#pragma unroll
    for (int k = 0; k < NB; ++k) {
      float t = fmaxf(dn0[k] * d0 + dn1[k] * d1 + dn2[k] * d2, 0.f);
      float sv = toF(fout[(size_t)nbr[k] * F + Cout + e]);
      mx = fmaxf(mx, t * sv);
    }
    acc += mx;
  }
  if (use_bn_relu) {
    acc = (acc - mm[c]) / sqrtf(vv[c] + 1e-5f) * g[c] + bb[c];
    acc = fmaxf(acc, 0.f);
  }
  outf[row * (size_t)Cout + c] = acc;
  if (outb) outb[row * (size_t)Cout + c] = __float2bfloat16(acc);
}

// ---------------- pool: max over first-4 neighbors at sampled rows ----------------
__global__ void pool_kernel(const float* __restrict__ v, const float* __restrict__ fm,
                            const int* __restrict__ idx10, const int* __restrict__ samp,
                            float* __restrict__ v_out, float* __restrict__ f_out,
                            __hip_bfloat16* __restrict__ f_out_b, int Nin, int C) {
  int b = blockIdx.y, mi = blockIdx.x, c = threadIdx.x;
  int n = samp[mi];
  size_t row = (size_t)b * Nin + n;
  float mx = -3.4e38f;
#pragma unroll
  for (int j = 0; j < 4; ++j) {
    int nb = idx10[row * NB + j];
    mx = fmaxf(mx, fm[((size_t)b * Nin + nb) * C + c]);
  }
  int Mout = gridDim.x;
  f_out[((size_t)b * Mout + mi) * C + c] = mx;
  f_out_b[((size_t)b * Mout + mi) * C + c] = __float2bfloat16(mx);
  if (c < 3) v_out[((size_t)b * Mout + mi) * 3 + c] = v[row * 3 + c];
}

// ---------------- nearest v3: wave-per-target argmin (z=0: v1, z=1: v2) + global max (z=2) ----------------
__global__ __launch_bounds__(256) void nearest3_kernel(const float* __restrict__ tgt,
                                                       const float* __restrict__ v1,
                                                       const float* __restrict__ v2,
                                                       const float* __restrict__ fm4,
                                                       int* __restrict__ ni1, int* __restrict__ ni2,
                                                       float* __restrict__ fg) {
  __shared__ float4 sp[512];
  int z = blockIdx.z;
  int b = blockIdx.y;
  if (z == 2) {
    if (blockIdx.x >= 2) return;
    int c = blockIdx.x * 256 + threadIdx.x;
    float mx = -3.4e38f;
    for (int p = 0; p < 128; ++p) mx = fmaxf(mx, fm4[((size_t)b * 128 + p) * 512 + c]);
    fg[b * 512 + c] = mx;
    return;
  }
  const float* src = z ? v2 : v1;
  int S = z ? 128 : 512;
  int* out = z ? ni2 : ni1;
  for (int i = threadIdx.x; i < S; i += blockDim.x) {
    const float* q = src + ((size_t)b * S + i) * 3;
    float x = q[0], y = q[1], zz = q[2];
    sp[i] = make_float4(x, y, zz, x * x + y * y + zz * zz);
  }
  __syncthreads();
  int wave = threadIdx.x >> 6, lane = threadIdx.x & 63;
  int n = blockIdx.x * 4 + wave;
  const float* t = tgt + ((size_t)b * 2048 + n) * 3;
  float x = t[0], y = t[1], zz = t[2];
  float sqt = x * x + y * y + zz * zz;
  float best = 3.4e38f; int bi = 0x7fffffff;
  for (int s = lane; s < S; s += 64) {
    float4 q = sp[s];
    float d = q.w + sqt - 2.f * (x * q.x + y * q.y + zz * q.z);
    if (d < best) { best = d; bi = s; }   // strict < keeps lowest s within lane
  }
#pragma unroll
  for (int m = 32; m > 0; m >>= 1) {
    float od = __shfl_xor(best, m);
    int oi = __shfl_xor(bi, m);
    if (od < best || (od == best && oi < bi)) { best = od; bi = oi; }  // tie -> lower index (argmin)
  }
  if (lane == 0) out[(size_t)b * 2048 + n] = bi;
}

// ---------------- output v2: 64n x 32cc LDS-tiled transpose, coalesced both ways ----------------
__global__ __launch_bounds__(256) void output2_kernel(
    const float* __restrict__ fm0, const float* __restrict__ fm1,
    const float* __restrict__ fm2, const float* __restrict__ fm3,
    const float* __restrict__ fm4, const float* __restrict__ fg,
    const int* __restrict__ ni1, const int* __restrict__ ni2,
    float* __restrict__ out) {
  __shared__ float tile[64][33];
  __shared__ int srow[64];
  int b = blockIdx.z;
  int cc0 = blockIdx.y * 32;
  int n0 = blockIdx.x * 64;
  int tid = threadIdx.x;
  const float* P; int Cs, coff, mode;
  if (cc0 < 128)       { P = fm0; Cs = 128; coff = cc0;        mode = 0; }
  else if (cc0 < 256)  { P = fm1; Cs = 128; coff = cc0 - 128;  mode = 0; }
  else if (cc0 < 512)  { P = fm2; Cs = 256; coff = cc0 - 256;  mode = 1; }
  else if (cc0 < 768)  { P = fm3; Cs = 256; coff = cc0 - 512;  mode = 1; }
  else if (cc0 < 1280) { P = fm4; Cs = 512; coff = cc0 - 768;  mode = 2; }
  else                 { P = fg;  Cs = 512; coff = cc0 - 1280; mode = 3; }
  if (tid < 64) {
    int n = n0 + tid;
    size_t r2 = (size_t)b * 2048 + n;
    int sr;
    if (mode == 0)      sr = b * 2048 + n;
    else if (mode == 1) sr = b * 512 + ni1[r2];
    else if (mode == 2) sr = b * 128 + ni2[r2];
    else                sr = b;
    srow[tid] = sr;
  }
  __syncthreads();
  int tx = tid & 31, ty = tid >> 5;  // 32 x 8
#pragma unroll
  for (int r = 0; r < 8; ++r) {
    int nl = ty + 8 * r;
    tile[nl][tx] = P[(size_t)srow[nl] * Cs + coff + tx];
  }
  __syncthreads();
  int lx = tid & 63, ly = tid >> 6;  // 64 x 4
  float* out0 = out;                              // (4,1280,2048)
  float* out1 = out + (size_t)4 * 1280 * 2048;    // (4,1792,2048)
#pragma unroll
  for (int ci = 0; ci < 8; ++ci) {
    int cl = ly + 4 * ci;
    int cc = cc0 + cl;
    float vv = tile[lx][cl];
    out1[((size_t)b * 1792 + cc) * 2048 + n0 + lx] = vv;
    if (cc < 1280) out0[((size_t)b * 1280 + cc) * 2048 + n0 + lx] = vv;
  }
}

extern "C" void kernel_launch(void* const* d_in, const int* in_sizes, int n_in,
                              void* d_out, int out_size, void* d_ws, size_t ws_size,
                              hipStream_t stream) {
  (void)in_sizes; (void)n_in; (void)out_size; (void)ws_size;
  const float* vertices = (const float*)d_in[0];
  const float* rgb_f    = (const float*)d_in[1];
  const float* dir0     = (const float*)d_in[2];
  const float* w1 = (const float*)d_in[3],  *b1 = (const float*)d_in[4],  *d1 = (const float*)d_in[5];
  const float* w2 = (const float*)d_in[6],  *b2 = (const float*)d_in[7],  *d2 = (const float*)d_in[8];
  const float* w3 = (const float*)d_in[9],  *b3 = (const float*)d_in[10], *d3 = (const float*)d_in[11];
  const float* w4 = (const float*)d_in[12], *b4 = (const float*)d_in[13], *d4 = (const float*)d_in[14];
  const float* rgb_w = (const float*)d_in[15], *rgb_b = (const float*)d_in[16];
  const float* rbn_g = (const float*)d_in[17], *rbn_b = (const float*)d_in[18];
  const float* rbn_m = (const float*)d_in[19], *rbn_v = (const float*)d_in[20];
  const float* bn1_g = (const float*)d_in[21], *bn1_b = (const float*)d_in[22];
  const float* bn1_m = (const float*)d_in[23], *bn1_v = (const float*)d_in[24];
  const float* bn2_g = (const float*)d_in[25], *bn2_b = (const float*)d_in[26];
  const float* bn2_m = (const float*)d_in[27], *bn2_v = (const float*)d_in[28];
  const float* bn3_g = (const float*)d_in[29], *bn3_b = (const float*)d_in[30];
  const float* bn3_m = (const float*)d_in[31], *bn3_v = (const float*)d_in[32];
  float* out = (float*)d_out;

  char* ws = (char*)d_ws;
  size_t off = 0;
  auto alloc = [&](size_t bytes) -> void* {
    void* p = ws + off;
    off += (bytes + 255) & ~(size_t)255;
    return p;
  };
  int*   samp1 = (int*)alloc(512 * 4);
  int*   samp2 = (int*)alloc(128 * 4);
  int*   idx0  = (int*)alloc((size_t)4 * 2048 * NB * 4);
  int*   idx1  = (int*)alloc((size_t)4 * 512 * NB * 4);
  int*   idx2  = (int*)alloc((size_t)4 * 128 * NB * 4);
  float* fm0   = (float*)alloc((size_t)4 * 2048 * 128 * 4);
  float* fm1   = (float*)alloc((size_t)4 * 2048 * 128 * 4);
  float* fout  = (float*)alloc((size_t)4 * 2048 * 1024 * 4);   // fp32 fout (layer 4 only)
  __hip_bfloat16* foutb = (__hip_bfloat16*)alloc((size_t)4 * 2048 * 1024 * 2);  // bf16 fout (layers 1-3)
  float* v1    = (float*)alloc((size_t)4 * 512 * 3 * 4);
  float* fp1   = (float*)alloc((size_t)4 * 512 * 128 * 4);
  float* fm2   = (float*)alloc((size_t)4 * 512 * 256 * 4);
  float* fm3   = (float*)alloc((size_t)4 * 512 * 256 * 4);
  float* v2    = (float*)alloc((size_t)4 * 128 * 3 * 4);
  float* fp2   = (float*)alloc((size_t)4 * 128 * 256 * 4);
  float* fm4   = (float*)alloc((size_t)4 * 128 * 512 * 4);
  float* fg    = (float*)alloc((size_t)4 * 512 * 4);
  int*   ni1   = (int*)alloc((size_t)4 * 2048 * 4);
  int*   ni2   = (int*)alloc((size_t)4 * 2048 * 4);
  // bf16 matmul operands
  __hip_bfloat16* fm0b = (__hip_bfloat16*)alloc((size_t)4 * 2048 * 128 * 2);
  __hip_bfloat16* fp1b = (__hip_bfloat16*)alloc((size_t)4 * 512 * 128 * 2);
  __hip_bfloat16* fm2b = (__hip_bfloat16*)alloc((size_t)4 * 512 * 256 * 2);
  __hip_bfloat16* fp2b = (__hip_bfloat16*)alloc((size_t)4 * 128 * 256 * 2);
  __hip_bfloat16* wt1  = (__hip_bfloat16*)alloc((size_t)1024 * 128 * 2);
  __hip_bfloat16* wt2  = (__hip_bfloat16*)alloc((size_t)2048 * 128 * 2);
  __hip_bfloat16* wt3  = (__hip_bfloat16*)alloc((size_t)2048 * 256 * 2);
  __hip_bfloat16* wt4  = (__hip_bfloat16*)alloc((size_t)4096 * 256 * 2);
  // normalized directions
  float* d0n = (float*)alloc((size_t)3 * 448 * 4);
  float* d1n = (float*)alloc((size_t)3 * 896 * 4);
  float* d2n = (float*)alloc((size_t)3 * 1792 * 4);
  float* d3n = (float*)alloc((size_t)3 * 1792 * 4);
  float* d4n = (float*)alloc((size_t)3 * 3584 * 4);

  // one-shot prep + permutations
  prep_kernel<<<1954, 256, 0, stream>>>(w1, wt1, w2, wt2, w3, wt3, w4, wt4,
                                        dir0, d0n, d1, d1n, d2, d2n, d3, d3n, d4, d4n);
  perm2_kernel<<<2, 1024, 0, stream>>>(samp1, samp2);

  // level-0 kNN: 1024-thread blocks = 16 queries/block (staging amortized 4x)
  knn_wave_kernel<<<dim3(2048 / 16, 4), 1024, 0, stream>>>(vertices, 2048, idx0);

  // fm0 = [conv_surface(64ch) | bn(relu(rgb))(64ch)]  (fused)
  fm0_kernel<<<dim3(512, 4), 256, 0, stream>>>(vertices, idx0, d0n, rgb_f, rgb_w, rgb_b,
                                               rbn_g, rbn_b, rbn_m, rbn_v, fm0, fm0b);

  // layer 1 (fout bf16; combine v3: 1 ch/thread)
  mfma_gemm_kernel<<<dim3(1024 / 128, 8192 / 128), 256, 0, stream>>>(fm0b, wt1, b1, nullptr, foutb, 8192, 128, 1024);
  conv_combine3_kernel<__hip_bfloat16><<<dim3(2048 * 128 / 256, 4), 256, 0, stream>>>(idx0, vertices, foutb, d1n,
      bn1_g, bn1_b, bn1_m, bn1_v, 1, fm1, nullptr, 2048, 128);

  // pool 1 -> v1, fp1(+bf16) ; level-1 kNN
  pool_kernel<<<dim3(512, 4), 128, 0, stream>>>(vertices, fm1, idx0, samp1, v1, fp1, fp1b, 2048, 128);
  knn_wave_kernel<<<dim3(512 / 4, 4), 256, 0, stream>>>(v1, 512, idx1);

  // layer 2
  mfma_gemm_kernel<<<dim3(2048 / 128, 2048 / 128), 256, 0, stream>>>(fp1b, wt2, b2, nullptr, foutb, 2048, 128, 2048);
  conv_combine3_kernel<__hip_bfloat16><<<dim3(512 * 256 / 256, 4), 256, 0, stream>>>(idx1, v1, foutb, d2n,
      bn2_g, bn2_b, bn2_m, bn2_v, 1, fm2, fm2b, 512, 256);
  // layer 3
  mfma_gemm_kernel<<<dim3(2048 / 128, 2048 / 128), 256, 0, stream>>>(fm2b, wt3, b3, nullptr, foutb, 2048, 256, 2048);
  conv_combine3_kernel<__hip_bfloat16><<<dim3(512 * 256 / 256, 4), 256, 0, stream>>>(idx1, v1, foutb, d3n,
      bn3_g, bn3_b, bn3_m, bn3_v, 1, fm3, nullptr, 512, 256);

  // pool 2 -> v2, fp2(+bf16) ; level-2 kNN
  pool_kernel<<<dim3(128, 4), 256, 0, stream>>>(v1, fm3, idx1, samp2, v2, fp2, fp2b, 512, 256);
  knn_wave_kernel<<<dim3(128 / 4, 4), 256, 0, stream>>>(v2, 128, idx2);

  // layer 4 (fout fp32 — final layer feeds fm4 directly, keep precision)
  mfma_gemm_kernel<<<dim3(4096 / 128, 512 / 128), 256, 0, stream>>>(fp2b, wt4, b4, fout, nullptr, 512, 256, 4096);
  conv_combine3_kernel<float><<<dim3(128 * 512 / 256, 4), 256, 0, stream>>>(idx2, v2, fout, d4n,
      nullptr, nullptr, nullptr, nullptr, 0, fm4, nullptr, 128, 512);

  // upsample indices (wave-per-target) + global max (z=2)
  nearest3_kernel<<<dim3(512, 4, 3), 256, 0, stream>>>(vertices, v1, v2, fm4, ni1, ni2, fg);

  // outputs (LDS-tiled transpose)
  output2_kernel<<<dim3(32, 56, 4), 256, 0, stream>>>(fm0, fm1, fm2, fm3, fm4, fg, ni1, ni2, out);
}

// Round 9
// 245.322 us; speedup vs baseline: 5.8137x; 1.2110x over previous
//
#include <hip/hip_runtime.h>
#include <hip/hip_bf16.h>
#include <math.h>

#define NB 10
#define KNN_K 11

typedef __attribute__((ext_vector_type(8))) short bf16x8;
typedef __attribute__((ext_vector_type(4))) float f32x4;

__device__ __forceinline__ float toF(float x) { return x; }
__device__ __forceinline__ float toF(__hip_bfloat16 x) { return __bfloat162float(x); }

// ---------------- Threefry-2x32-20 (JAX) ----------------
__device__ __forceinline__ void tf2x32(unsigned k0, unsigned k1, unsigned& x0, unsigned& x1) {
  unsigned ks0 = k0, ks1 = k1, ks2 = k0 ^ k1 ^ 0x1BD11BDAu;
  x0 += ks0; x1 += ks1;
#define TF_R(r) { x0 += x1; x1 = (x1 << (r)) | (x1 >> (32 - (r))); x1 ^= x0; }
  TF_R(13) TF_R(15) TF_R(26) TF_R(6)  x0 += ks1; x1 += ks2 + 1u;
  TF_R(17) TF_R(29) TF_R(16) TF_R(24) x0 += ks2; x1 += ks0 + 2u;
  TF_R(13) TF_R(15) TF_R(26) TF_R(6)  x0 += ks0; x1 += ks1 + 3u;
  TF_R(17) TF_R(29) TF_R(16) TF_R(24) x0 += ks1; x1 += ks2 + 4u;
  TF_R(13) TF_R(15) TF_R(26) TF_R(6)  x0 += ks2; x1 += ks0 + 5u;
#undef TF_R
}

__device__ __forceinline__ unsigned long long shfl_xor_u64(unsigned long long v, int m) {
  unsigned lo = (unsigned)v, hi = (unsigned)(v >> 32);
  lo = (unsigned)__shfl_xor((int)lo, m);
  hi = (unsigned)__shfl_xor((int)hi, m);
  return ((unsigned long long)hi << 32) | lo;
}

// ---------------- setup mega-kernel ----------------
// blocks 0..479    : weight transpose+convert (4 x 32x32 tiles per block)
// blocks 480..488  : direction normalization
// blocks 489..490  : jax.random.permutation replication (n=2048 / n=512)
// blocks 491..1002 : level-0 kNN (512 blocks: b = i>>7, x = i&127, 16 queries/block)
__global__ __launch_bounds__(1024) void setup_kernel(
    const float* __restrict__ w1, __hip_bfloat16* __restrict__ o1,
    const float* __restrict__ w2, __hip_bfloat16* __restrict__ o2,
    const float* __restrict__ w3, __hip_bfloat16* __restrict__ o3,
    const float* __restrict__ w4, __hip_bfloat16* __restrict__ o4,
    const float* __restrict__ s0, float* __restrict__ n0,
    const float* __restrict__ s1, float* __restrict__ n1,
    const float* __restrict__ s2, float* __restrict__ n2,
    const float* __restrict__ s3, float* __restrict__ n3,
    const float* __restrict__ s4, float* __restrict__ n4,
    int* __restrict__ samp1, int* __restrict__ samp2,
    const float* __restrict__ v, int* __restrict__ idx0) {
  __shared__ __align__(16) char smem[49152];
  int bid = blockIdx.x;
  if (bid < 480) {
    // ---- weight transpose: W[K][N] fp32 -> WT[N][K] bf16, 4 tiles/block ----
    int sub = threadIdx.x >> 8, t = threadIdx.x & 255;
    int wtile = bid * 4 + sub;
    float (*tbuf)[33] = (float(*)[33])(smem + sub * (32 * 33 * 4));
    const float* W; __hip_bfloat16* O; int K, N;
    if (wtile < 128)      { W = w1; O = o1; K = 128; N = 1024; }
    else if (wtile < 384) { wtile -= 128; W = w2; O = o2; K = 128; N = 2048; }
    else if (wtile < 896) { wtile -= 384; W = w3; O = o3; K = 256; N = 2048; }
    else                  { wtile -= 896; W = w4; O = o4; K = 256; N = 4096; }
    int tpr = N / 32;
    int tk = wtile / tpr, tn = wtile % tpr;
    int tx = t & 31, ty = t >> 5;  // (32, 8)
#pragma unroll
    for (int i = 0; i < 4; ++i)
      tbuf[ty + 8 * i][tx] = W[(size_t)(tk * 32 + ty + 8 * i) * N + tn * 32 + tx];
    __syncthreads();
#pragma unroll
    for (int i = 0; i < 4; ++i)
      O[(size_t)(tn * 32 + ty + 8 * i) * K + tk * 32 + tx] = __float2bfloat16(tbuf[tx][ty + 8 * i]);
    return;
  }
  if (bid < 489) {
    // ---- dirnorm ----
    int e = (bid - 480) * 1024 + threadIdx.x;
    const float* S; float* D; int W;
    if (e < 448)                          { S = s0; D = n0; W = 448; }
    else if (e < 448 + 896)               { e -= 448; S = s1; D = n1; W = 896; }
    else if (e < 448 + 896 + 1792)        { e -= 448 + 896; S = s2; D = n2; W = 1792; }
    else if (e < 448 + 896 + 3584)        { e -= 448 + 896 + 1792; S = s3; D = n3; W = 1792; }
    else if (e < 448 + 896 + 3584 + 3584) { e -= 448 + 896 + 3584; S = s4; D = n4; W = 3584; }
    else return;
    float a = S[e], b = S[W + e], c = S[2 * W + e];
    float nr = fmaxf(sqrtf(a * a + b * b + c * c), 1e-12f);
    D[e] = a / nr; D[W + e] = b / nr; D[2 * W + e] = c / nr;
    return;
  }
  if (bid < 491) {
    // ---- permutation (register-resident bitonic, identical network to verified version) ----
    unsigned long long (*buf)[2048] = (unsigned long long(*)[2048])smem;
    unsigned (*perm)[2048] = (unsigned(*)[2048])(smem + 32768);
    int which = bid - 489;
    int n = (which == 0) ? 2048 : 512;
    int m = (which == 0) ? 512 : 128;
    int R = (which == 0) ? 2 : 1;
    unsigned k0 = 0u, k1 = (which == 0) ? 1u : 2u;
    int* out = (which == 0) ? samp1 : samp2;
    int T = n >> 1;
    int t = threadIdx.x;
    bool act = (t < T);
    int pb = 0;
    unsigned valA = 0, valB = 0;
    int lb = 0;
    for (int r = 0; r < R; ++r) {
      unsigned a0 = 0u, a1 = 0u, ss0 = 0u, ss1 = 1u;
      tf2x32(k0, k1, a0, a1);
      tf2x32(k0, k1, ss0, ss1);
      unsigned long long kA = 0, kB = 0;
      if (act) {
        unsigned y0 = 0u, y1 = (unsigned)t;
        tf2x32(ss0, ss1, y0, y1);
        kA = ((unsigned long long)(y0 ^ y1) << 32) | (unsigned)t;
        y0 = 0u; y1 = (unsigned)(t + T);
        tf2x32(ss0, ss1, y0, y1);
        kB = ((unsigned long long)(y0 ^ y1) << 32) | (unsigned)(t + T);
      }
      for (int kk = 2; kk <= n; kk <<= 1) {
        for (int j = kk >> 1; j > 0; j >>= 1) {
          if (j == T) {
            if (act) {
              unsigned long long lo = (kA < kB) ? kA : kB;
              unsigned long long hi = (kA < kB) ? kB : kA;
              kA = lo; kB = hi;
            }
          } else if (j >= 64) {
            if (act) { buf[lb][t] = kA; buf[lb][t + T] = kB; }
            __syncthreads();
            if (act) {
              unsigned long long okA = buf[lb][t ^ j];
              unsigned long long okB = buf[lb][(t ^ j) + T];
              bool lower = ((t & j) == 0);
              bool upA = ((t & kk) == 0);
              bool upB = (((t + T) & kk) == 0);
              kA = (upA == lower) ? (kA < okA ? kA : okA) : (kA < okA ? okA : kA);
              kB = (upB == lower) ? (kB < okB ? kB : okB) : (kB < okB ? okB : kB);
            }
            lb ^= 1;
          } else {
            unsigned long long okA = shfl_xor_u64(kA, j);
            unsigned long long okB = shfl_xor_u64(kB, j);
            if (act) {
              bool lower = ((t & j) == 0);
              bool upA = ((t & kk) == 0);
              bool upB = (((t + T) & kk) == 0);
              kA = (upA == lower) ? (kA < okA ? kA : okA) : (kA < okA ? okA : kA);
              kB = (upB == lower) ? (kB < okB ? kB : okB) : (kB < okB ? okB : kB);
            }
          }
        }
      }
      if (act) {
        unsigned posA = (unsigned)(kA & 0xffffffffu);
        unsigned posB = (unsigned)(kB & 0xffffffffu);
        if (r == 0) { valA = posA; valB = posB; }
        else        { valA = perm[pb][posA]; valB = perm[pb][posB]; }
      }
      if (r + 1 < R) {
        __syncthreads();
        if (act) { perm[pb ^ 1][t] = valA; perm[pb ^ 1][t + T] = valB; }
        pb ^= 1;
        __syncthreads();
      }
      k0 = a0; k1 = a1;
    }
    if (t < m) out[t] = (int)valA;
    return;
  }
  // ---- level-0 kNN: wave-per-query top-11, drop slot 0 ----
  {
    float4* pts = (float4*)smem;
    int i = bid - 491;
    int b = i >> 7, x = i & 127;
    const int N = 2048;
    const float* vb = v + (size_t)b * N * 3;
    for (int i2 = threadIdx.x; i2 < N; i2 += 1024) {
      float xx = vb[i2 * 3], yy = vb[i2 * 3 + 1], zz = vb[i2 * 3 + 2];
      pts[i2] = make_float4(xx, yy, zz, xx * xx + yy * yy + zz * zz);
    }
    __syncthreads();
    int wave = threadIdx.x >> 6;
    int lane = threadIdx.x & 63;
    int qi = x * 16 + wave;
    float4 p = pts[qi];
    float bd[KNN_K]; int bi[KNN_K];
#pragma unroll
    for (int t = 0; t < KNN_K; ++t) { bd[t] = 3.4e38f; bi[t] = 0x7fffffff; }
    for (int j = lane; j < N; j += 64) {
      float4 q = pts[j];
      float dot = p.x * q.x + p.y * q.y + p.z * q.z;
      float d = p.w + q.w - 2.0f * dot;
      if (d < bd[KNN_K - 1]) {
        float cd = d; int ci = j;
#pragma unroll
        for (int t = 0; t < KNN_K; ++t) {
          bool sw = cd < bd[t];
          float td = bd[t]; int ti = bi[t];
          bd[t] = sw ? cd : td; bi[t] = sw ? ci : ti;
          cd = sw ? td : cd;   ci = sw ? ti : ci;
        }
      }
    }
    int ptr = 0;
    int* o = idx0 + ((size_t)b * N + qi) * NB;
#pragma unroll 1
    for (int t = 0; t < KNN_K; ++t) {
      float d = (ptr < KNN_K) ? bd[ptr] : 3.4e38f;
      int idx = (ptr < KNN_K) ? bi[ptr] : 0x7fffffff;
      float rd = d; int ridx = idx;
#pragma unroll
      for (int s = 32; s > 0; s >>= 1) {
        float od = __shfl_xor(rd, s);
        int oi = __shfl_xor(ridx, s);
        if (od < rd || (od == rd && oi < ridx)) { rd = od; ridx = oi; }
      }
      if (d == rd && idx == ridx) ptr++;
      if (t >= 1 && lane == 0) o[t - 1] = ridx;
    }
  }
}

// ---------------- kNN (standalone, for levels 1/2) ----------------
__global__ __launch_bounds__(1024) void knn_wave_kernel(const float* __restrict__ v, int N,
                                                        int* __restrict__ out) {
  __shared__ float4 pts[2048];
  int b = blockIdx.y;
  const float* vb = v + (size_t)b * N * 3;
  for (int i = threadIdx.x; i < N; i += blockDim.x) {
    float x = vb[i * 3], y = vb[i * 3 + 1], z = vb[i * 3 + 2];
    pts[i] = make_float4(x, y, z, x * x + y * y + z * z);
  }
  __syncthreads();
  int qpb = blockDim.x >> 6;
  int wave = threadIdx.x >> 6;
  int lane = threadIdx.x & 63;
  int qi = blockIdx.x * qpb + wave;
  float4 p = pts[qi];
  float bd[KNN_K]; int bi[KNN_K];
#pragma unroll
  for (int t = 0; t < KNN_K; ++t) { bd[t] = 3.4e38f; bi[t] = 0x7fffffff; }
  for (int j = lane; j < N; j += 64) {
    float4 q = pts[j];
    float dot = p.x * q.x + p.y * q.y + p.z * q.z;
    float d = p.w + q.w - 2.0f * dot;
    if (d < bd[KNN_K - 1]) {
      float cd = d; int ci = j;
#pragma unroll
      for (int t = 0; t < KNN_K; ++t) {
        bool sw = cd < bd[t];
        float td = bd[t]; int ti = bi[t];
        bd[t] = sw ? cd : td; bi[t] = sw ? ci : ti;
        cd = sw ? td : cd;   ci = sw ? ti : ci;
      }
    }
  }
  int ptr = 0;
  int* o = out + ((size_t)b * N + qi) * NB;
#pragma unroll 1
  for (int t = 0; t < KNN_K; ++t) {
    float d = (ptr < KNN_K) ? bd[ptr] : 3.4e38f;
    int idx = (ptr < KNN_K) ? bi[ptr] : 0x7fffffff;
    float rd = d; int ridx = idx;
#pragma unroll
    for (int s = 32; s > 0; s >>= 1) {
      float od = __shfl_xor(rd, s);
      int oi = __shfl_xor(ridx, s);
      if (od < rd || (od == rd && oi < ridx)) { rd = od; ridx = oi; }
    }
    if (d == rd && idx == ridx) ptr++;
    if (t >= 1 && lane == 0) o[t - 1] = ridx;
  }
}

// ---------------- fm0 (z=0) + nearest argmin for levels 1/2 (z=1/2) ----------------
// v1[i] = vertices[samp1[i]], v2[i] = vertices[samp1[samp2[i]]] (pure copies) -> ni1/ni2
// depend only on samp*, so they run here, off the critical chain.
__global__ __launch_bounds__(256) void fm0n_kernel(const float* __restrict__ v, const int* __restrict__ idx,
                                                   const float* __restrict__ dir0n,
                                                   const float* __restrict__ rgb_f, const float* __restrict__ w,
                                                   const float* __restrict__ bias, const float* __restrict__ g,
                                                   const float* __restrict__ bb, const float* __restrict__ mm,
                                                   const float* __restrict__ vv,
                                                   const int* __restrict__ samp1, const int* __restrict__ samp2,
                                                   float* __restrict__ fm0, __hip_bfloat16* __restrict__ fm0b,
                                                   int* __restrict__ ni1, int* __restrict__ ni2) {
  int z = blockIdx.z;
  int b = blockIdx.y;
  int tid = threadIdx.x;
  if (z >= 1) {
    __shared__ float4 sp[512];
    int S = (z == 1) ? 512 : 128;
    int* outp = (z == 1) ? ni1 : ni2;
    for (int i = tid; i < S; i += blockDim.x) {
      int src = (z == 1) ? samp1[i] : samp1[samp2[i]];
      const float* q = v + ((size_t)b * 2048 + src) * 3;
      float x = q[0], y = q[1], zz = q[2];
      sp[i] = make_float4(x, y, zz, x * x + y * y + zz * zz);
    }
    __syncthreads();
    int wave = tid >> 6, lane = tid & 63;
    int n = blockIdx.x * 4 + wave;
    const float* t = v + ((size_t)b * 2048 + n) * 3;
    float x = t[0], y = t[1], zz = t[2];
    float sqt = x * x + y * y + zz * zz;
    float best = 3.4e38f; int bi = 0x7fffffff;
    for (int s = lane; s < S; s += 64) {
      float4 q = sp[s];
      float d = q.w + sqt - 2.f * (x * q.x + y * q.y + zz * q.z);
      if (d < best) { best = d; bi = s; }
    }
#pragma unroll
    for (int m = 32; m > 0; m >>= 1) {
      float od = __shfl_xor(best, m);
      int oi = __shfl_xor(bi, m);
      if (od < best || (od == best && oi < bi)) { best = od; bi = oi; }
    }
    if (lane == 0) outp[(size_t)b * 2048 + n] = bi;
    return;
  }
  __shared__ float dn[4][NB][3];
  int n0 = blockIdx.x * 4;
  if (tid < 4 * NB) {
    int p = tid / NB, k = tid % NB;
    size_t row = (size_t)b * 2048 + (n0 + p);
    const float* c = v + row * 3;
    int nb = idx[row * NB + k];
    const float* q = v + ((size_t)b * 2048 + nb) * 3;
    float dx = q[0] - c[0], dy = q[1] - c[1], dz = q[2] - c[2];
    float nr = fmaxf(sqrtf(dx * dx + dy * dy + dz * dz), 1e-12f);
    dn[p][k][0] = dx / nr; dn[p][k][1] = dy / nr; dn[p][k][2] = dz / nr;
  }
  __syncthreads();
  int p = tid >> 6, c = tid & 63;
  int n = n0 + p;
  float acc = 0.f;
  for (int s = 0; s < 7; ++s) {
    int e = s * 64 + c;
    float d0 = dir0n[e], d1 = dir0n[448 + e], d2 = dir0n[896 + e];
    float mx = 0.f;
#pragma unroll
    for (int k = 0; k < NB; ++k) {
      float t = dn[p][k][0] * d0 + dn[p][k][1] * d1 + dn[p][k][2] * d2;
      mx = fmaxf(mx, fmaxf(t, 0.f));
    }
    acc += mx;
  }
  acc = fmaxf(acc, 0.f);
  const float* f = rgb_f + (size_t)b * 32 * 2048;
  float a2 = bias[c];
  for (int cc = 0; cc < 32; ++cc) a2 += w[c * 32 + cc] * f[cc * 2048 + n];
  a2 = fmaxf(a2, 0.f);
  a2 = (a2 - mm[c]) / sqrtf(vv[c] + 1e-5f) * g[c] + bb[c];
  size_t o = ((size_t)b * 2048 + n) * 128;
  fm0[o + c] = acc;
  fm0[o + 64 + c] = a2;
  fm0b[o + c] = __float2bfloat16(acc);
  fm0b[o + 64 + c] = __float2bfloat16(a2);
}

// ---------------- bf16 MFMA GEMM: C = A @ BT^T + bias; writes fp32 C and/or bf16 Cb ----------------
__global__ __launch_bounds__(256) void mfma_gemm_kernel(const __hip_bfloat16* __restrict__ A,
                                                        const __hip_bfloat16* __restrict__ BT,
                                                        const float* __restrict__ bias,
                                                        float* __restrict__ C,
                                                        __hip_bfloat16* __restrict__ Cb,
                                                        int M, int K, int N) {
  __shared__ __hip_bfloat16 Al[128 * 32];
  __shared__ __hip_bfloat16 Bl[128 * 32];
  int t = threadIdx.x;
  int l = t & 63;
  int w = t >> 6;
  int wm = w >> 1, wn = w & 1;
  int m0 = blockIdx.y * 128, n0 = blockIdx.x * 128;
  f32x4 zero = {0.f, 0.f, 0.f, 0.f};
  f32x4 acc[4][4];
#pragma unroll
  for (int i = 0; i < 4; ++i)
#pragma unroll
    for (int j = 0; j < 4; ++j) acc[i][j] = zero;

  for (int kt = 0; kt < K; kt += 32) {
#pragma unroll
    for (int j = 0; j < 2; ++j) {
      int c = t + 256 * j;
      int r = c >> 2, o = c & 3;
      *(uint4*)&Al[r * 32 + o * 8] = *(const uint4*)&A[(size_t)(m0 + r) * K + kt + o * 8];
      *(uint4*)&Bl[r * 32 + o * 8] = *(const uint4*)&BT[(size_t)(n0 + r) * K + kt + o * 8];
    }
    __syncthreads();
    bf16x8 af[4], bfv[4];
#pragma unroll
    for (int f = 0; f < 4; ++f) {
      af[f]  = *(const bf16x8*)&Al[(wm * 64 + f * 16 + (l & 15)) * 32 + (l >> 4) * 8];
      bfv[f] = *(const bf16x8*)&Bl[(wn * 64 + f * 16 + (l & 15)) * 32 + (l >> 4) * 8];
    }
#pragma unroll
    for (int i = 0; i < 4; ++i)
#pragma unroll
      for (int j = 0; j < 4; ++j)
        acc[i][j] = __builtin_amdgcn_mfma_f32_16x16x32_bf16(af[i], bfv[j], acc[i][j], 0, 0, 0);
    __syncthreads();
  }
  int col_l = l & 15, rbase = (l >> 4) * 4;
#pragma unroll
  for (int i = 0; i < 4; ++i) {
#pragma unroll
    for (int j = 0; j < 4; ++j) {
      int col = n0 + wn * 64 + j * 16 + col_l;
      float bv = bias[col];
#pragma unroll
      for (int r = 0; r < 4; ++r) {
        int m = m0 + wm * 64 + i * 16 + rbase + r;
        float val = acc[i][j][r] + bv;
        if (C)  C[(size_t)m * N + col] = val;
        if (Cb) Cb[(size_t)m * N + col] = __float2bfloat16(val);
      }
    }
  }
}

// ---------------- conv_layer combine v3: thread = (point, channel) ----------------
template <typename T>
__global__ __launch_bounds__(256) void conv_combine3_kernel(
    const int* __restrict__ idx, const float* __restrict__ v,
    const T* __restrict__ fout, const float* __restrict__ dirn,
    const float* __restrict__ g, const float* __restrict__ bb,
    const float* __restrict__ mm, const float* __restrict__ vv,
    int use_bn_relu, float* __restrict__ outf, __hip_bfloat16* __restrict__ outb,
    int Np, int Cout) {
  __shared__ float dnS[2][NB][3];
  __shared__ int nbS[2][NB];
  int b = blockIdx.y;
  int tid = threadIdx.x;
  int base = blockIdx.x * 256;
  int p0 = base / Cout;
  int nPts = (Cout < 256) ? 2 : 1;
  if (tid < nPts * NB) {
    int p = tid / NB, k = tid - p * NB;
    size_t prow = (size_t)b * Np + p0 + p;
    int nb = idx[prow * NB + k];
    const float* cpt = v + prow * 3;
    const float* q = v + ((size_t)b * Np + nb) * 3;
    float dx = q[0] - cpt[0], dy = q[1] - cpt[1], dz = q[2] - cpt[2];
    float nr = fmaxf(sqrtf(dx * dx + dy * dy + dz * dz), 1e-12f);
    dnS[p][k][0] = dx / nr; dnS[p][k][1] = dy / nr; dnS[p][k][2] = dz / nr;
    nbS[p][k] = b * Np + nb;
  }
  __syncthreads();
  int gid = base + tid;
  int n = gid / Cout, c = gid - n * Cout;
  int lp = n - p0;
  size_t row = (size_t)b * Np + n;
  float dn0[NB], dn1[NB], dn2[NB]; int nbr[NB];
#pragma unroll
  for (int k = 0; k < NB; ++k) {
    dn0[k] = dnS[lp][k][0]; dn1[k] = dnS[lp][k][1]; dn2[k] = dnS[lp][k][2];
    nbr[k] = nbS[lp][k];
  }
  int F = 8 * Cout, W7 = 7 * Cout;
  float acc = toF(fout[row * (size_t)F + c]);  // center
  for (int s = 0; s < 7; ++s) {
    int e = s * Cout + c;
    float d0 = dirn[e], d1 = dirn[W7 + e], d2 = dirn[2 * W7 + e];
    float mx = -3.4e38f;
#pragma unroll
    for (int k = 0; k < NB; ++k) {
      float t = fmaxf(dn0[k] * d0 + dn1[k] * d1 + dn2[k] * d2, 0.f);
      float sv = toF(fout[(size_t)nbr[k] * F + Cout + e]);
      mx = fmaxf(mx, t * sv);
    }
    acc += mx;
  }
  if (use_bn_relu) {
    acc = (acc - mm[c]) / sqrtf(vv[c] + 1e-5f) * g[c] + bb[c];
    acc = fmaxf(acc, 0.f);
  }
  outf[row * (size_t)Cout + c] = acc;
  if (outb) outb[row * (size_t)Cout + c] = __float2bfloat16(acc);
}

// ---------------- pool: max over first-4 neighbors at sampled rows ----------------
__global__ void pool_kernel(const float* __restrict__ v, const float* __restrict__ fm,
                            const int* __restrict__ idx10, const int* __restrict__ samp,
                            float* __restrict__ v_out, float* __restrict__ f_out,
                            __hip_bfloat16* __restrict__ f_out_b, int Nin, int C) {
  int b = blockIdx.y, mi = blockIdx.x, c = threadIdx.x;
  int n = samp[mi];
  size_t row = (size_t)b * Nin + n;
  float mx = -3.4e38f;
#pragma unroll
  for (int j = 0; j < 4; ++j) {
    int nb = idx10[row * NB + j];
    mx = fmaxf(mx, fm[((size_t)b * Nin + nb) * C + c]);
  }
  int Mout = gridDim.x;
  f_out[((size_t)b * Mout + mi) * C + c] = mx;
  f_out_b[((size_t)b * Mout + mi) * C + c] = __float2bfloat16(mx);
  if (c < 3) v_out[((size_t)b * Mout + mi) * 3 + c] = v[row * 3 + c];
}

// ---------------- output v3: LDS-tiled transpose; fg (global max of fm4) computed inline ----------------
__global__ __launch_bounds__(256) void output3_kernel(
    const float* __restrict__ fm0, const float* __restrict__ fm1,
    const float* __restrict__ fm2, const float* __restrict__ fm3,
    const float* __restrict__ fm4,
    const int* __restrict__ ni1, const int* __restrict__ ni2,
    float* __restrict__ out) {
  __shared__ float tile[64][33];
  __shared__ int srow[64];
  int b = blockIdx.z;
  int cc0 = blockIdx.y * 32;
  int n0 = blockIdx.x * 64;
  int tid = threadIdx.x;
  float* out0 = out;                              // (4,1280,2048)
  float* out1 = out + (size_t)4 * 1280 * 2048;    // (4,1792,2048)
  if (cc0 >= 1280) {
    // fg region: compute max over 128 points of fm4 for these 32 channels, broadcast over n
    __shared__ float red[8][32];
    __shared__ float fgv[32];
    int coff = cc0 - 1280;
    int tx = tid & 31, ty = tid >> 5;
    float pm = -3.4e38f;
    for (int p = ty; p < 128; p += 8)
      pm = fmaxf(pm, fm4[((size_t)b * 128 + p) * 512 + coff + tx]);
    red[ty][tx] = pm;
    __syncthreads();
    if (tid < 32) {
      float m = red[0][tid];
#pragma unroll
      for (int r = 1; r < 8; ++r) m = fmaxf(m, red[r][tid]);
      fgv[tid] = m;
    }
    __syncthreads();
    int lx = tid & 63, ly = tid >> 6;
#pragma unroll
    for (int ci = 0; ci < 8; ++ci) {
      int cl = ly + 4 * ci;
      out1[((size_t)b * 1792 + cc0 + cl) * 2048 + n0 + lx] = fgv[cl];
    }
    return;
  }
  const float* P; int Cs, coff, mode;
  if (cc0 < 128)       { P = fm0; Cs = 128; coff = cc0;        mode = 0; }
  else if (cc0 < 256)  { P = fm1; Cs = 128; coff = cc0 - 128;  mode = 0; }
  else if (cc0 < 512)  { P = fm2; Cs = 256; coff = cc0 - 256;  mode = 1; }
  else if (cc0 < 768)  { P = fm3; Cs = 256; coff = cc0 - 512;  mode = 1; }
  else                 { P = fm4; Cs = 512; coff = cc0 - 768;  mode = 2; }
  if (tid < 64) {
    int n = n0 + tid;
    size_t r2 = (size_t)b * 2048 + n;
    int sr;
    if (mode == 0)      sr = b * 2048 + n;
    else if (mode == 1) sr = b * 512 + ni1[r2];
    else                sr = b * 128 + ni2[r2];
    srow[tid] = sr;
  }
  __syncthreads();
  int tx = tid & 31, ty = tid >> 5;  // 32 x 8
#pragma unroll
  for (int r = 0; r < 8; ++r) {
    int nl = ty + 8 * r;
    tile[nl][tx] = P[(size_t)srow[nl] * Cs + coff + tx];
  }
  __syncthreads();
  int lx = tid & 63, ly = tid >> 6;  // 64 x 4
#pragma unroll
  for (int ci = 0; ci < 8; ++ci) {
    int cl = ly + 4 * ci;
    int cc = cc0 + cl;
    float vv = tile[lx][cl];
    out1[((size_t)b * 1792 + cc) * 2048 + n0 + lx] = vv;
    out0[((size_t)b * 1280 + cc) * 2048 + n0 + lx] = vv;
  }
}

extern "C" void kernel_launch(void* const* d_in, const int* in_sizes, int n_in,
                              void* d_out, int out_size, void* d_ws, size_t ws_size,
                              hipStream_t stream) {
  (void)in_sizes; (void)n_in; (void)out_size; (void)ws_size;
  const float* vertices = (const float*)d_in[0];
  const float* rgb_f    = (const float*)d_in[1];
  const float* dir0     = (const float*)d_in[2];
  const float* w1 = (const float*)d_in[3],  *b1 = (const float*)d_in[4],  *d1 = (const float*)d_in[5];
  const float* w2 = (const float*)d_in[6],  *b2 = (const float*)d_in[7],  *d2 = (const float*)d_in[8];
  const float* w3 = (const float*)d_in[9],  *b3 = (const float*)d_in[10], *d3 = (const float*)d_in[11];
  const float* w4 = (const float*)d_in[12], *b4 = (const float*)d_in[13], *d4 = (const float*)d_in[14];
  const float* rgb_w = (const float*)d_in[15], *rgb_b = (const float*)d_in[16];
  const float* rbn_g = (const float*)d_in[17], *rbn_b = (const float*)d_in[18];
  const float* rbn_m = (const float*)d_in[19], *rbn_v = (const float*)d_in[20];
  const float* bn1_g = (const float*)d_in[21], *bn1_b = (const float*)d_in[22];
  const float* bn1_m = (const float*)d_in[23], *bn1_v = (const float*)d_in[24];
  const float* bn2_g = (const float*)d_in[25], *bn2_b = (const float*)d_in[26];
  const float* bn2_m = (const float*)d_in[27], *bn2_v = (const float*)d_in[28];
  const float* bn3_g = (const float*)d_in[29], *bn3_b = (const float*)d_in[30];
  const float* bn3_m = (const float*)d_in[31], *bn3_v = (const float*)d_in[32];
  float* out = (float*)d_out;

  char* ws = (char*)d_ws;
  size_t off = 0;
  auto alloc = [&](size_t bytes) -> void* {
    void* p = ws + off;
    off += (bytes + 255) & ~(size_t)255;
    return p;
  };
  int*   samp1 = (int*)alloc(512 * 4);
  int*   samp2 = (int*)alloc(128 * 4);
  int*   idx0  = (int*)alloc((size_t)4 * 2048 * NB * 4);
  int*   idx1  = (int*)alloc((size_t)4 * 512 * NB * 4);
  int*   idx2  = (int*)alloc((size_t)4 * 128 * NB * 4);
  float* fm0   = (float*)alloc((size_t)4 * 2048 * 128 * 4);
  float* fm1   = (float*)alloc((size_t)4 * 2048 * 128 * 4);
  float* fout  = (float*)alloc((size_t)4 * 2048 * 1024 * 4);   // fp32 fout (layer 4 only)
  __hip_bfloat16* foutb = (__hip_bfloat16*)alloc((size_t)4 * 2048 * 1024 * 2);  // bf16 fout (layers 1-3)
  float* v1    = (float*)alloc((size_t)4 * 512 * 3 * 4);
  float* fp1   = (float*)alloc((size_t)4 * 512 * 128 * 4);
  float* fm2   = (float*)alloc((size_t)4 * 512 * 256 * 4);
  float* fm3   = (float*)alloc((size_t)4 * 512 * 256 * 4);
  float* v2    = (float*)alloc((size_t)4 * 128 * 3 * 4);
  float* fp2   = (float*)alloc((size_t)4 * 128 * 256 * 4);
  float* fm4   = (float*)alloc((size_t)4 * 128 * 512 * 4);
  int*   ni1   = (int*)alloc((size_t)4 * 2048 * 4);
  int*   ni2   = (int*)alloc((size_t)4 * 2048 * 4);
  // bf16 matmul operands
  __hip_bfloat16* fm0b = (__hip_bfloat16*)alloc((size_t)4 * 2048 * 128 * 2);
  __hip_bfloat16* fp1b = (__hip_bfloat16*)alloc((size_t)4 * 512 * 128 * 2);
  __hip_bfloat16* fm2b = (__hip_bfloat16*)alloc((size_t)4 * 512 * 256 * 2);
  __hip_bfloat16* fp2b = (__hip_bfloat16*)alloc((size_t)4 * 128 * 256 * 2);
  __hip_bfloat16* wt1  = (__hip_bfloat16*)alloc((size_t)1024 * 128 * 2);
  __hip_bfloat16* wt2  = (__hip_bfloat16*)alloc((size_t)2048 * 128 * 2);
  __hip_bfloat16* wt3  = (__hip_bfloat16*)alloc((size_t)2048 * 256 * 2);
  __hip_bfloat16* wt4  = (__hip_bfloat16*)alloc((size_t)4096 * 256 * 2);
  // normalized directions
  float* d0n = (float*)alloc((size_t)3 * 448 * 4);
  float* d1n = (float*)alloc((size_t)3 * 896 * 4);
  float* d2n = (float*)alloc((size_t)3 * 1792 * 4);
  float* d3n = (float*)alloc((size_t)3 * 1792 * 4);
  float* d4n = (float*)alloc((size_t)3 * 3584 * 4);

  // launch 1: weights + dirnorm + permutations + level-0 kNN, all concurrent
  setup_kernel<<<1003, 1024, 0, stream>>>(w1, wt1, w2, wt2, w3, wt3, w4, wt4,
                                          dir0, d0n, d1, d1n, d2, d2n, d3, d3n, d4, d4n,
                                          samp1, samp2, vertices, idx0);

  // launch 2: fm0 (z=0) + nearest ni1 (z=1) + nearest ni2 (z=2)
  fm0n_kernel<<<dim3(512, 4, 3), 256, 0, stream>>>(vertices, idx0, d0n, rgb_f, rgb_w, rgb_b,
                                                   rbn_g, rbn_b, rbn_m, rbn_v, samp1, samp2,
                                                   fm0, fm0b, ni1, ni2);

  // layer 1
  mfma_gemm_kernel<<<dim3(1024 / 128, 8192 / 128), 256, 0, stream>>>(fm0b, wt1, b1, nullptr, foutb, 8192, 128, 1024);
  conv_combine3_kernel<__hip_bfloat16><<<dim3(2048 * 128 / 256, 4), 256, 0, stream>>>(idx0, vertices, foutb, d1n,
      bn1_g, bn1_b, bn1_m, bn1_v, 1, fm1, nullptr, 2048, 128);

  // pool 1 -> v1, fp1(+bf16) ; level-1 kNN
  pool_kernel<<<dim3(512, 4), 128, 0, stream>>>(vertices, fm1, idx0, samp1, v1, fp1, fp1b, 2048, 128);
  knn_wave_kernel<<<dim3(512 / 4, 4), 256, 0, stream>>>(v1, 512, idx1);

  // layer 2
  mfma_gemm_kernel<<<dim3(2048 / 128, 2048 / 128), 256, 0, stream>>>(fp1b, wt2, b2, nullptr, foutb, 2048, 128, 2048);
  conv_combine3_kernel<__hip_bfloat16><<<dim3(512 * 256 / 256, 4), 256, 0, stream>>>(idx1, v1, foutb, d2n,
      bn2_g, bn2_b, bn2_m, bn2_v, 1, fm2, fm2b, 512, 256);
  // layer 3
  mfma_gemm_kernel<<<dim3(2048 / 128, 2048 / 128), 256, 0, stream>>>(fm2b, wt3, b3, nullptr, foutb, 2048, 256, 2048);
  conv_combine3_kernel<__hip_bfloat16><<<dim3(512 * 256 / 256, 4), 256, 0, stream>>>(idx1, v1, foutb, d3n,
      bn3_g, bn3_b, bn3_m, bn3_v, 1, fm3, nullptr, 512, 256);

  // pool 2 -> v2, fp2(+bf16) ; level-2 kNN
  pool_kernel<<<dim3(128, 4), 256, 0, stream>>>(v1, fm3, idx1, samp2, v2, fp2, fp2b, 512, 256);
  knn_wave_kernel<<<dim3(128 / 4, 4), 256, 0, stream>>>(v2, 128, idx2);

  // layer 4 (fout fp32 — final layer feeds fm4 directly, keep precision)
  mfma_gemm_kernel<<<dim3(4096 / 128, 512 / 128), 256, 0, stream>>>(fp2b, wt4, b4, fout, nullptr, 512, 256, 4096);
  conv_combine3_kernel<float><<<dim3(128 * 512 / 256, 4), 256, 0, stream>>>(idx2, v2, fout, d4n,
      nullptr, nullptr, nullptr, nullptr, 0, fm4, nullptr, 128, 512);

  // outputs (LDS-tiled transpose; fg computed inline in the 1280.. region)
  output3_kernel<<<dim3(32, 56, 4), 256, 0, stream>>>(fm0, fm1, fm2, fm3, fm4, ni1, ni2, out);
}